// Round 8
// baseline (2021.556 us; speedup 1.0000x reference)
//
#include <hip/hip_runtime.h>
#include <math.h>

#define S_LEN 2048
#define DMODEL 2048
#define NHEAD 16
#define KVHEAD 2
#define DHEAD 128
#define NLAYER 4
#define VOCAB 10000
#define INNER_DIM 8192
#define LN_EPS 1e-5f
#define VOCAB_PAD 10240  // 40*256
#define QKVN 2560        // 2048 q + 256 k + 256 v

typedef __attribute__((ext_vector_type(4))) float f32x4;
typedef __attribute__((ext_vector_type(2))) float f32x2;
typedef __attribute__((ext_vector_type(8))) short s16x8;
typedef __attribute__((ext_vector_type(4))) short s16x4;

__device__ __forceinline__ short f2bf(float f) {
  union { float f; unsigned u; } v; v.f = f;
  unsigned r = v.u + 0x7FFFu + ((v.u >> 16) & 1u);  // RNE
  return (short)(r >> 16);
}

__device__ __forceinline__ float gelu_tanh(float x) {
  // tanh-approx GELU via fast exp (stable for all x)
  float z = 0.7978845608028654f * (x + 0.044715f * x * x * x);
  float t = __expf(-2.0f * fabsf(z));
  float th = (1.0f - t) / (1.0f + t);
  th = copysignf(th, z);
  return 0.5f * x * (1.0f + th);
}

__device__ __forceinline__ void glds16(const void* g, void* l) {
  __builtin_amdgcn_global_load_lds(
      (const __attribute__((address_space(1))) unsigned int*)g,
      (__attribute__((address_space(3))) unsigned int*)l, 16, 0, 0);
}

// ---------------- weight transpose 64x64 tiles: W[K][N] -> WT[NP][K] bf16 --
__global__ __launch_bounds__(256)
void wtrans64(const float* __restrict__ W, short* __restrict__ WT,
              int K, int N, int NP) {
  __shared__ float ld[64][65];
  const int n0 = blockIdx.x * 64, k0 = blockIdx.y * 64;
  const int tid = threadIdx.x;
  const int rbase = tid >> 4;
  const int c4 = (tid & 15) * 4;
#pragma unroll
  for (int q = 0; q < 4; ++q) {
    int kk = rbase + q * 16;
    const float* wp = W + (size_t)(k0 + kk) * N + n0 + c4;
    float v0, v1, v2, v3;
    if (n0 + c4 + 3 < N) {
      f32x4 v = *(const f32x4*)wp;
      v0 = v[0]; v1 = v[1]; v2 = v[2]; v3 = v[3];
    } else {
      v0 = (n0 + c4 + 0 < N) ? wp[0] : 0.f;
      v1 = (n0 + c4 + 1 < N) ? wp[1] : 0.f;
      v2 = (n0 + c4 + 2 < N) ? wp[2] : 0.f;
      v3 = (n0 + c4 + 3 < N) ? wp[3] : 0.f;
    }
    ld[kk][c4 + 0] = v0; ld[kk][c4 + 1] = v1;
    ld[kk][c4 + 2] = v2; ld[kk][c4 + 3] = v3;
  }
  __syncthreads();
#pragma unroll
  for (int s = 0; s < 2; ++s) {
    int lin = tid + s * 256;
    int nn = lin >> 3;
    int ks = lin & 7;
    int n = n0 + nn;
    if (n < NP) {
      s16x8 o;
#pragma unroll
      for (int j = 0; j < 8; ++j)
        o[j] = (n < N) ? f2bf(ld[ks * 8 + j][nn]) : (short)0;
      *(s16x8*)&WT[(size_t)n * K + k0 + ks * 8] = o;
    }
  }
}

// ---------------- V transpose: qkvf v-slice [S][256] (stride QKVN) -> vt[256][S]
__global__ __launch_bounds__(256)
void vtrans(const float* __restrict__ qkvf, short* __restrict__ vt) {
  __shared__ float ld[64][65];
  const int n0 = blockIdx.x * 64, k0 = blockIdx.y * 64;
  const int tid = threadIdx.x;
  const int rbase = tid >> 4;
  const int c4 = (tid & 15) * 4;
#pragma unroll
  for (int q = 0; q < 4; ++q) {
    int kk = rbase + q * 16;
    f32x4 v = *(const f32x4*)(qkvf + (size_t)(k0 + kk) * QKVN + 2304 + n0 + c4);
    ld[kk][c4 + 0] = v[0]; ld[kk][c4 + 1] = v[1];
    ld[kk][c4 + 2] = v[2]; ld[kk][c4 + 3] = v[3];
  }
  __syncthreads();
#pragma unroll
  for (int s = 0; s < 2; ++s) {
    int lin = tid + s * 256;
    int nn = lin >> 3;
    int ks = lin & 7;
    s16x8 o;
#pragma unroll
    for (int j = 0; j < 8; ++j) o[j] = f2bf(ld[ks * 8 + j][nn]);
    *(s16x8*)&vt[(size_t)(n0 + nn) * S_LEN + k0 + ks * 8] = o;
  }
}

// ---------------- embedding gather ----------------
__global__ __launch_bounds__(256)
void embed_gather(const int* __restrict__ text, const float* __restrict__ ew,
                  float* __restrict__ out) {
  const int row = blockIdx.x;
  const int tok = text[row];
  const float* src = ew + (size_t)tok * DMODEL;
  float* dst = out + (size_t)row * DMODEL;
#pragma unroll
  for (int i = 0; i < 2; ++i) {
    int idx = (threadIdx.x + i * 256) * 4;
    *(f32x4*)(dst + idx) = *(const f32x4*)(src + idx);
  }
}

// ---------------- triple LayerNorm: model -> block -> attn ----------------
__global__ __launch_bounds__(256)
void ln_triple(const float* __restrict__ in,
               const float* __restrict__ mg, const float* __restrict__ mb,
               const float* __restrict__ bg, const float* __restrict__ bb,
               const float* __restrict__ ag, const float* __restrict__ ab,
               float* __restrict__ hb, short* __restrict__ hn16) {
  const int row = blockIdx.x;
  const int tid = threadIdx.x;
  const int wave = tid >> 6;
  __shared__ float rs[3][4], rs2[3][4];
  float v[8];
  const float* x = in + (size_t)row * DMODEL;
#pragma unroll
  for (int i = 0; i < 8; ++i) v[i] = x[tid + i * 256];
#pragma unroll
  for (int rnd = 0; rnd < 3; ++rnd) {
    float s = 0.f, s2 = 0.f;
#pragma unroll
    for (int i = 0; i < 8; ++i) { s += v[i]; s2 += v[i] * v[i]; }
#pragma unroll
    for (int off = 1; off < 64; off <<= 1) {
      s += __shfl_xor(s, off); s2 += __shfl_xor(s2, off);
    }
    if ((tid & 63) == 0) { rs[rnd][wave] = s; rs2[rnd][wave] = s2; }
    __syncthreads();
    s = rs[rnd][0] + rs[rnd][1] + rs[rnd][2] + rs[rnd][3];
    s2 = rs2[rnd][0] + rs2[rnd][1] + rs2[rnd][2] + rs2[rnd][3];
    const float mean = s * (1.f / DMODEL);
    const float var = s2 * (1.f / DMODEL) - mean * mean;
    const float rstd = rsqrtf(var + LN_EPS);
    const float* gg = (rnd == 0) ? mg : (rnd == 1) ? bg : ag;
    const float* bbv = (rnd == 0) ? mb : (rnd == 1) ? bb : ab;
#pragma unroll
    for (int i = 0; i < 8; ++i) {
      int idx = tid + i * 256;
      v[i] = (v[i] - mean) * rstd * gg[idx] + bbv[idx];
    }
    if (rnd == 1) {
      float* o = hb + (size_t)row * DMODEL;
#pragma unroll
      for (int i = 0; i < 8; ++i) o[tid + i * 256] = v[i];
    }
  }
  short* o = hn16 + (size_t)row * DMODEL;
#pragma unroll
  for (int i = 0; i < 8; ++i) o[tid + i * 256] = f2bf(v[i]);
}

// ---------------- dual LN (model -> head), bf16 out ----------------
__global__ __launch_bounds__(256)
void ln_dual(const float* __restrict__ in,
             const float* __restrict__ mg, const float* __restrict__ mb,
             const float* __restrict__ hg, const float* __restrict__ hbv,
             short* __restrict__ out16) {
  const int row = blockIdx.x;
  const int tid = threadIdx.x;
  const int wave = tid >> 6;
  __shared__ float rs[2][4], rs2[2][4];
  float v[8];
  const float* x = in + (size_t)row * DMODEL;
#pragma unroll
  for (int i = 0; i < 8; ++i) v[i] = x[tid + i * 256];
#pragma unroll
  for (int rnd = 0; rnd < 2; ++rnd) {
    float s = 0.f, s2 = 0.f;
#pragma unroll
    for (int i = 0; i < 8; ++i) { s += v[i]; s2 += v[i] * v[i]; }
#pragma unroll
    for (int off = 1; off < 64; off <<= 1) {
      s += __shfl_xor(s, off); s2 += __shfl_xor(s2, off);
    }
    if ((tid & 63) == 0) { rs[rnd][wave] = s; rs2[rnd][wave] = s2; }
    __syncthreads();
    s = rs[rnd][0] + rs[rnd][1] + rs[rnd][2] + rs[rnd][3];
    s2 = rs2[rnd][0] + rs2[rnd][1] + rs2[rnd][2] + rs2[rnd][3];
    const float mean = s * (1.f / DMODEL);
    const float var = s2 * (1.f / DMODEL) - mean * mean;
    const float rstd = rsqrtf(var + LN_EPS);
    const float* gg = (rnd == 0) ? mg : hg;
    const float* bbv = (rnd == 0) ? mb : hbv;
#pragma unroll
    for (int i = 0; i < 8; ++i) {
      int idx = tid + i * 256;
      v[i] = (v[i] - mean) * rstd * gg[idx] + bbv[idx];
    }
  }
  short* o = out16 + (size_t)row * DMODEL;
#pragma unroll
  for (int i = 0; i < 8; ++i) o[tid + i * 256] = f2bf(v[i]);
}

// ---------------- fused q+k head-norm ----------------
__global__ __launch_bounds__(256)
void normqk(const float* __restrict__ qkvf,
            const float* __restrict__ qg, const float* __restrict__ kg,
            short* __restrict__ qb16, short* __restrict__ kb16) {
  const int rowjob = blockIdx.x * 4 + (threadIdx.x >> 6);
  const int lane = threadIdx.x & 63;
  const int s = rowjob / 18, sub = rowjob - s * 18;
  const float* p; short* o; const float* g;
  if (sub < 16) {
    p = qkvf + (size_t)s * QKVN + sub * DHEAD;
    o = qb16 + ((size_t)s * 16 + sub) * DHEAD;
    g = qg;
  } else {
    p = qkvf + (size_t)s * QKVN + 2048 + (sub - 16) * DHEAD;
    o = kb16 + ((size_t)s * 2 + (sub - 16)) * DHEAD;
    g = kg;
  }
  f32x2 t = *(const f32x2*)(p + lane * 2);
  float sm = t[0] + t[1];
  float s2 = t[0] * t[0] + t[1] * t[1];
#pragma unroll
  for (int off = 1; off < 64; off <<= 1) {
    sm += __shfl_xor(sm, off); s2 += __shfl_xor(s2, off);
  }
  const float mean = sm * (1.f / DHEAD);
  const float var = s2 * (1.f / DHEAD) - mean * mean;
  const float rstd = rsqrtf(var + LN_EPS);
  o[lane * 2] = f2bf((t[0] - mean) * rstd * g[lane * 2]);
  o[lane * 2 + 1] = f2bf((t[1] - mean) * rstd * g[lane * 2 + 1]);
}

// ---------------- split-K reduce: xres = sum(partials) + b2 + h2 ----------
__global__ __launch_bounds__(256)
void w2red(const float* __restrict__ p, const float* __restrict__ b2,
           const float* __restrict__ h2, float* __restrict__ out) {
  const int row = blockIdx.x;
  const size_t SD = (size_t)S_LEN * DMODEL;
#pragma unroll
  for (int i = 0; i < 2; ++i) {
    int c = (threadIdx.x + i * 256) * 4;
    size_t idx = (size_t)row * DMODEL + c;
    f32x4 a = *(const f32x4*)(p + idx);
    f32x4 b = *(const f32x4*)(p + SD + idx);
    f32x4 cc = *(const f32x4*)(p + 2 * SD + idx);
    f32x4 d = *(const f32x4*)(p + 3 * SD + idx);
    f32x4 hv = *(const f32x4*)(h2 + idx);
    f32x4 bv = *(const f32x4*)(b2 + c);
    f32x4 r;
#pragma unroll
    for (int j = 0; j < 4; ++j) r[j] = ((a[j] + b[j]) + (cc[j] + d[j])) + bv[j] + hv[j];
    *(f32x4*)(out + idx) = r;
  }
}

// ---------------- 2-phase double-buffered bf16 GEMM (flexible shapes) -----
// C = act(A[M,K'] @ BT[N,K']^T + bias)(+res); LDA/LDB row strides; blockIdx.z
// selects a K-chunk (split-K): A/BT column offset z*K, Cf offset z*M*N.
template<int BM, int BN, int BK, int WM, int WN, int ACT, bool BIAS, bool RES,
         bool WF, bool WB>
__global__ __launch_bounds__(WM * WN * 64)
void gemm_db(const short* __restrict__ A, const short* __restrict__ BT,
             const float* __restrict__ bias, const float* __restrict__ res,
             float* __restrict__ Cf, short* __restrict__ Cb,
             int M, int N, int K, int LDA, int LDB) {
  constexpr int THREADS = WM * WN * 64;
  constexpr int MR = BM / WM / 16;
  constexpr int NR = BN / WN / 16;
  constexpr int KH = BK / 32;
  constexpr int SLOTS = BK / 8;
  constexpr int SMASK = SLOTS - 1;
  constexpr int RSH = (SLOTS == 8) ? 0 : 1;
  constexpr int CSH = (SLOTS == 8) ? 3 : 2;
  constexpr int NIA = (BM * BK) / (THREADS * 8);
  constexpr int NIB = (BN * BK) / (THREADS * 8);
  __shared__ short As[2][BM * BK];
  __shared__ short Bs[2][BN * BK];
  const int tid = threadIdx.x;
  const int wave = tid >> 6, lane = tid & 63;
  const int g = lane >> 4, r = lane & 15;
  const int wm = wave / WN, wn = wave % WN;
  const int zoff = blockIdx.z * K;
  if (WF) Cf += (size_t)blockIdx.z * M * N;

  const int GY = gridDim.y;
  int lin = blockIdx.x + blockIdx.y * gridDim.x;
  int nwg = gridDim.x * GY;
  int sw = ((nwg & 7) == 0) ? ((lin & 7) * (nwg >> 3) + (lin >> 3)) : lin;
  const int bm = (sw % GY) * BM;
  const int bn = (sw / GY) * BN;

  const short* gsrc[NIA + NIB];
  short* ldst[2][NIA + NIB];
#pragma unroll
  for (int i = 0; i < NIA; ++i) {
    int c = i * THREADS + tid;
    int row = c >> CSH;
    int slot = c & SMASK;
    int col = ((slot ^ ((row >> RSH) & SMASK)) << 3);
    gsrc[i] = A + (size_t)(bm + row) * LDA + zoff + col;
    int base = (i * THREADS + (wave << 6)) << 3;
    ldst[0][i] = &As[0][base];
    ldst[1][i] = &As[1][base];
  }
#pragma unroll
  for (int i = 0; i < NIB; ++i) {
    int c = i * THREADS + tid;
    int row = c >> CSH;
    int slot = c & SMASK;
    int col = ((slot ^ ((row >> RSH) & SMASK)) << 3);
    gsrc[NIA + i] = BT + (size_t)(bn + row) * LDB + zoff + col;
    int base = (i * THREADS + (wave << 6)) << 3;
    ldst[0][NIA + i] = &Bs[0][base];
    ldst[1][NIA + i] = &Bs[1][base];
  }

  f32x4 acc[MR][NR] = {};
  const int NT = K / BK;

#pragma unroll
  for (int i = 0; i < NIA + NIB; ++i) glds16(gsrc[i], ldst[0][i]);
  asm volatile("s_waitcnt vmcnt(0)" ::: "memory");
  __syncthreads();

  for (int t = 0; t < NT; ++t) {
    const int cur = t & 1;
    const short* as = As[cur];
    const short* bs = Bs[cur];
    s16x8 bfr[NR][KH], af[MR / 2][KH];
#pragma unroll
    for (int n = 0; n < NR; ++n) {
      int rr = wn * (NR * 16) + n * 16 + r;
#pragma unroll
      for (int kk = 0; kk < KH; ++kk) {
        int lg = kk * 4 + g;
        bfr[n][kk] = *(const s16x8*)&bs[rr * BK + ((lg ^ ((rr >> RSH) & SMASK)) << 3)];
      }
    }
#pragma unroll
    for (int mm = 0; mm < MR / 2; ++mm) {
      int rr = wm * (MR * 16) + mm * 16 + r;
#pragma unroll
      for (int kk = 0; kk < KH; ++kk) {
        int lg = kk * 4 + g;
        af[mm][kk] = *(const s16x8*)&as[rr * BK + ((lg ^ ((rr >> RSH) & SMASK)) << 3)];
      }
    }
    if (t + 1 < NT) {
#pragma unroll
      for (int i = 0; i < NIA + NIB; ++i) glds16(gsrc[i] + (t + 1) * BK, ldst[cur ^ 1][i]);
    }
    asm volatile("s_waitcnt lgkmcnt(0)" ::: "memory");
    __builtin_amdgcn_sched_barrier(0);
    __builtin_amdgcn_s_setprio(1);
#pragma unroll
    for (int mm = 0; mm < MR / 2; ++mm)
#pragma unroll
      for (int n = 0; n < NR; ++n)
#pragma unroll
        for (int kk = 0; kk < KH; ++kk)
          acc[mm][n] = __builtin_amdgcn_mfma_f32_16x16x32_bf16(af[mm][kk], bfr[n][kk], acc[mm][n], 0, 0, 0);
    __builtin_amdgcn_s_setprio(0);
    __builtin_amdgcn_s_barrier();
#pragma unroll
    for (int mm = 0; mm < MR / 2; ++mm) {
      int rr = wm * (MR * 16) + (MR / 2 + mm) * 16 + r;
#pragma unroll
      for (int kk = 0; kk < KH; ++kk) {
        int lg = kk * 4 + g;
        af[mm][kk] = *(const s16x8*)&as[rr * BK + ((lg ^ ((rr >> RSH) & SMASK)) << 3)];
      }
    }
    asm volatile("s_waitcnt lgkmcnt(0)" ::: "memory");
    __builtin_amdgcn_sched_barrier(0);
    __builtin_amdgcn_s_setprio(1);
#pragma unroll
    for (int mm = 0; mm < MR / 2; ++mm)
#pragma unroll
      for (int n = 0; n < NR; ++n)
#pragma unroll
        for (int kk = 0; kk < KH; ++kk)
          acc[MR / 2 + mm][n] = __builtin_amdgcn_mfma_f32_16x16x32_bf16(af[mm][kk], bfr[n][kk], acc[MR / 2 + mm][n], 0, 0, 0);
    __builtin_amdgcn_s_setprio(0);
    __syncthreads();
  }

#pragma unroll
  for (int m = 0; m < MR; ++m) {
    int row = bm + wm * (MR * 16) + m * 16 + g * 4;
#pragma unroll
    for (int n = 0; n < NR; ++n) {
      int col = bn + wn * (NR * 16) + n * 16 + r;
      if (col < N) {
#pragma unroll
        for (int j = 0; j < 4; ++j) {
          float v = acc[m][n][j];
          if (BIAS) v += bias[col];
          if (ACT) v = gelu_tanh(v);
          if (RES) v += res[(size_t)(row + j) * N + col];
          if (WF) Cf[(size_t)(row + j) * N + col] = v;
          if (WB) Cb[(size_t)(row + j) * N + col] = f2bf(v);
        }
      }
    }
  }
}

// ---------------- Flash attention v2 (R6, proven) ------------------------
__global__ __launch_bounds__(256)
void attn_fwd2(const short* __restrict__ qbuf, const short* __restrict__ kbuf,
               const short* __restrict__ vtb, short* __restrict__ obuf) {
  __shared__ short Qs[64 * 128];
  __shared__ short Ks[64 * 128];
  __shared__ short Vt[128 * 64];
  __shared__ short Ps[4][16][88];
  const int tid = threadIdx.x;
  int lin = blockIdx.x + blockIdx.y * gridDim.x;
  int sw = (lin & 7) * 32 + (lin >> 3);
  const int pair = sw & 15;
  const int h = sw >> 4;
  const int kh = h >> 3;
  const int wave = tid >> 6, lane = tid & 63;
  const int g = lane >> 4, r = lane & 15;
  const float scale = 0.08838834764831845f;

#pragma unroll
  for (int half = 0; half < 2; ++half) {
    const int qt = half ? (31 - pair) : pair;
    const int qbase = qt * 64;
    __builtin_amdgcn_s_barrier();
#pragma unroll
    for (int i = 0; i < 4; ++i) {
      int c = i * 256 + tid;
      int row = c >> 4;
      int scol = (((c & 15) ^ (row & 7)) << 3);
      glds16(qbuf + (size_t)(qbase + row) * DMODEL + h * DHEAD + scol,
             &Qs[(i * 256 + (wave << 6)) << 3]);
    }
    f32x4 O[8] = {};
    float mst[4], lst[4];
#pragma unroll
    for (int j = 0; j < 4; ++j) { mst[j] = -1e30f; lst[j] = 0.f; }
    s16x8 aq[4];

    for (int jt = 0; jt <= qt; ++jt) {
      const int jb = jt * 64;
      if (jt) __builtin_amdgcn_s_barrier();
#pragma unroll
      for (int i = 0; i < 4; ++i) {
        int c = i * 256 + tid;
        int row = c >> 4;
        int scol = (((c & 15) ^ (row & 7)) << 3);
        glds16(kbuf + (size_t)(jb + row) * 256 + kh * DHEAD + scol,
               &Ks[(i * 256 + (wave << 6)) << 3]);
      }
#pragma unroll
      for (int i = 0; i < 4; ++i) {
        int c = i * 256 + tid;
        int row = c >> 3;
        int scol = (((c & 7) ^ (row & 7)) << 3);
        glds16(vtb + (size_t)(kh * 128 + row) * S_LEN + jb + scol,
               &Vt[(i * 256 + (wave << 6)) << 3]);
      }
      asm volatile("s_waitcnt vmcnt(0)" ::: "memory");
      __builtin_amdgcn_s_barrier();
      if (jt == 0) {
#pragma unroll
        for (int kc = 0; kc < 4; ++kc) {
          int rr = wave * 16 + r;
          aq[kc] = *(const s16x8*)&Qs[rr * 128 + ((((kc << 2) | g) ^ (rr & 7)) << 3)];
        }
      }
      f32x4 sc[4] = {};
      __builtin_amdgcn_s_setprio(1);
#pragma unroll
      for (int n = 0; n < 4; ++n) {
        int rr = n * 16 + r;
#pragma unroll
        for (int kc = 0; kc < 4; ++kc) {
          s16x8 bk = *(const s16x8*)&Ks[rr * 128 + ((((kc << 2) | g) ^ (rr & 7)) << 3)];
          sc[n] = __builtin_amdgcn_mfma_f32_16x16x32_bf16(aq[kc], bk, sc[n], 0, 0, 0);
        }
      }
      __builtin_amdgcn_s_setprio(0);
      if (jt == qt) {
#pragma unroll
        for (int j = 0; j < 4; ++j) {
          int irow = qbase + wave * 16 + g * 4 + j;
#pragma unroll
          for (int n = 0; n < 4; ++n) {
            int jcol = jb + n * 16 + r;
            sc[n][j] = (jcol <= irow) ? sc[n][j] * scale : -1e30f;
          }
        }
      } else {
#pragma unroll
        for (int j = 0; j < 4; ++j)
#pragma unroll
          for (int n = 0; n < 4; ++n) sc[n][j] *= scale;
      }
      float pmax[4], alpha[4], rsum[4];
#pragma unroll
      for (int j = 0; j < 4; ++j)
        pmax[j] = fmaxf(fmaxf(sc[0][j], sc[1][j]), fmaxf(sc[2][j], sc[3][j]));
#pragma unroll
      for (int off = 1; off < 16; off <<= 1)
#pragma unroll
        for (int j = 0; j < 4; ++j) pmax[j] = fmaxf(pmax[j], __shfl_xor(pmax[j], off));
#pragma unroll
      for (int j = 0; j < 4; ++j) {
        float mnew = fmaxf(mst[j], pmax[j]);
        alpha[j] = __expf(mst[j] - mnew);
        mst[j] = mnew;
#pragma unroll
        for (int n = 0; n < 4; ++n) sc[n][j] = __expf(sc[n][j] - mnew);
        rsum[j] = (sc[0][j] + sc[1][j]) + (sc[2][j] + sc[3][j]);
      }
#pragma unroll
      for (int off = 1; off < 16; off <<= 1)
#pragma unroll
        for (int j = 0; j < 4; ++j) rsum[j] += __shfl_xor(rsum[j], off);
#pragma unroll
      for (int j = 0; j < 4; ++j) lst[j] = lst[j] * alpha[j] + rsum[j];
#pragma unroll
      for (int d = 0; d < 8; ++d)
#pragma unroll
        for (int j = 0; j < 4; ++j) O[d][j] *= alpha[j];
#pragma unroll
      for (int j = 0; j < 4; ++j)
#pragma unroll
        for (int n = 0; n < 4; ++n)
          Ps[wave][g * 4 + j][n * 16 + r] = f2bf(sc[n][j]);
      s16x8 pa0 = *(const s16x8*)&Ps[wave][r][g * 8];
      s16x8 pa1 = *(const s16x8*)&Ps[wave][r][32 + g * 8];
      __builtin_amdgcn_s_setprio(1);
#pragma unroll
      for (int d = 0; d < 8; ++d) {
        int dd = d * 16 + r;
        s16x8 b0 = *(const s16x8*)&Vt[dd * 64 + ((g ^ (dd & 7)) << 3)];
        s16x8 b1 = *(const s16x8*)&Vt[dd * 64 + (((4 + g) ^ (dd & 7)) << 3)];
        O[d] = __builtin_amdgcn_mfma_f32_16x16x32_bf16(pa0, b0, O[d], 0, 0, 0);
        O[d] = __builtin_amdgcn_mfma_f32_16x16x32_bf16(pa1, b1, O[d], 0, 0, 0);
      }
      __builtin_amdgcn_s_setprio(0);
    }
    float linv[4];
#pragma unroll
    for (int j = 0; j < 4; ++j) linv[j] = 1.f / lst[j];
#pragma unroll
    for (int d = 0; d < 8; ++d)
#pragma unroll
      for (int j = 0; j < 4; ++j)
        obuf[(size_t)(qbase + wave * 16 + g * 4 + j) * DMODEL + h * DHEAD + d * 16 + r] =
            f2bf(O[d][j] * linv[j]);
  }
}

// ---------------- host side ----------------
extern "C" void kernel_launch(void* const* d_in, const int* in_sizes, int n_in,
                              void* d_out, int out_size, void* d_ws, size_t ws_size,
                              hipStream_t stream) {
  const int* text = (const int*)d_in[0];
  const float* embed_w = (const float*)d_in[1];
  const float* model_g = (const float*)d_in[2];
  const float* model_b = (const float*)d_in[3];
  const float* blk_g = (const float*)d_in[4];
  const float* blk_b = (const float*)d_in[5];
  const float* attn_g = (const float*)d_in[6];
  const float* attn_b = (const float*)d_in[7];
  const float* wq = (const float*)d_in[8];
  const float* wk = (const float*)d_in[9];
  const float* wv = (const float*)d_in[10];
  const float* wo = (const float*)d_in[11];
  const float* qn_g = (const float*)d_in[12];
  const float* kn_g = (const float*)d_in[13];
  const float* w1 = (const float*)d_in[14];
  const float* b1 = (const float*)d_in[15];
  const float* w2 = (const float*)d_in[16];
  const float* b2 = (const float*)d_in[17];
  const float* head_g = (const float*)d_in[18];
  const float* head_b = (const float*)d_in[19];
  const float* head_w = (const float*)d_in[20];
  const float* head_bias = (const float*)d_in[21];
  float* out = (float*)d_out;

  const size_t SD = (size_t)S_LEN * DMODEL;
  const size_t SKV = (size_t)S_LEN * KVHEAD * DHEAD;
  const size_t SI = (size_t)S_LEN * INNER_DIM;
  const size_t WD = (size_t)DMODEL * DMODEL;
  const size_t WKV = (size_t)DMODEL * KVHEAD * DHEAD;
  const size_t WI = (size_t)DMODEL * INNER_DIM;

  char* p = (char*)d_ws;
  float* xres  = (float*)p; p += SD * 4;
  float* hb    = (float*)p; p += SD * 4;
  float* h2    = (float*)p; p += SD * 4;
  float* qkvf  = (float*)p; p += (size_t)S_LEN * QKVN * 4;
  float* wpart = (float*)p; p += SD * 4 * 4;     // 4 split-K partials
  short* hn16  = (short*)p; p += SD * 2;
  short* h216  = (short*)p; p += SD * 2;
  short* ao16  = (short*)p; p += SD * 2;
  short* ffi16 = (short*)p; p += SI * 2;
  short* qb16  = (short*)p; p += SD * 2;
  short* kb16  = (short*)p; p += SKV * 2;
  short* vt16  = (short*)p; p += SKV * 2;
  short* wqkvT = (short*)p; p += (size_t)QKVN * DMODEL * 2;
  short* woT   = (short*)p; p += WD * 2;
  short* w1T   = (short*)p; p += WI * 2;
  short* w2T   = (short*)p; p += WI * 2;
  short* headT = w1T;

  dim3 blk(256);
  embed_gather<<<S_LEN, blk, 0, stream>>>(text, embed_w, xres);

  for (int i = 0; i < NLAYER; ++i) {
    const float* wq_i = wq + (size_t)i * WD;
    const float* wk_i = wk + (size_t)i * WKV;
    const float* wv_i = wv + (size_t)i * WKV;
    const float* wo_i = wo + (size_t)i * WD;
    const float* w1_i = w1 + (size_t)i * WI;
    const float* b1_i = b1 + (size_t)i * INNER_DIM;
    const float* w2_i = w2 + (size_t)i * WI;
    const float* b2_i = b2 + (size_t)i * DMODEL;

    wtrans64<<<dim3(32, 32), blk, 0, stream>>>(wq_i, wqkvT, DMODEL, DMODEL, DMODEL);
    wtrans64<<<dim3(4, 32), blk, 0, stream>>>(wk_i, wqkvT + (size_t)2048 * DMODEL, DMODEL, 256, 256);
    wtrans64<<<dim3(4, 32), blk, 0, stream>>>(wv_i, wqkvT + (size_t)2304 * DMODEL, DMODEL, 256, 256);
    wtrans64<<<dim3(32, 32), blk, 0, stream>>>(wo_i, woT, DMODEL, DMODEL, DMODEL);
    wtrans64<<<dim3(128, 32), blk, 0, stream>>>(w1_i, w1T, DMODEL, INNER_DIM, INNER_DIM);
    wtrans64<<<dim3(32, 128), blk, 0, stream>>>(w2_i, w2T, INNER_DIM, DMODEL, DMODEL);

    ln_triple<<<S_LEN, blk, 0, stream>>>(xres, model_g, model_b,
                                         blk_g + i * DMODEL, blk_b + i * DMODEL,
                                         attn_g + i * DMODEL, attn_b + i * DMODEL,
                                         hb, hn16);

    // qkv: 256x128 tiles, 160 blocks
    gemm_db<256, 128, 32, 4, 2, 0, false, false, true, false>
        <<<dim3(QKVN / 128, S_LEN / 256), dim3(512), 0, stream>>>(
        hn16, wqkvT, nullptr, nullptr, qkvf, nullptr,
        S_LEN, QKVN, DMODEL, DMODEL, DMODEL);

    normqk<<<(S_LEN * 18) / 4, blk, 0, stream>>>(qkvf, qn_g + i * DHEAD, kn_g + i * DHEAD, qb16, kb16);
    vtrans<<<dim3(4, 32), blk, 0, stream>>>(qkvf, vt16);

    attn_fwd2<<<dim3(16, 16), blk, 0, stream>>>(qb16, kb16, vt16, ao16);

    // wo: 256x128 tiles, 128 blocks (res=hb, write f32+bf16)
    gemm_db<256, 128, 32, 4, 2, 0, false, true, true, true>
        <<<dim3(DMODEL / 128, S_LEN / 256), dim3(512), 0, stream>>>(
        ao16, woT, nullptr, hb, h2, h216,
        S_LEN, DMODEL, DMODEL, DMODEL, DMODEL);

    // w1: 256x256 tiles, 256 blocks (gelu+bias, bf16 out)
    gemm_db<256, 256, 32, 2, 4, 1, true, false, false, true>
        <<<dim3(INNER_DIM / 256, S_LEN / 256), dim3(512), 0, stream>>>(
        h216, w1T, b1_i, nullptr, nullptr, ffi16,
        S_LEN, INNER_DIM, DMODEL, DMODEL, DMODEL);

    // w2: split-K x4, 256x256 tiles, grid (8,8,4)=256 blocks -> partials
    gemm_db<256, 256, 32, 2, 4, 0, false, false, true, false>
        <<<dim3(DMODEL / 256, S_LEN / 256, 4), dim3(512), 0, stream>>>(
        ffi16, w2T, nullptr, nullptr, wpart, nullptr,
        S_LEN, DMODEL, INNER_DIM / 4, INNER_DIM, INNER_DIM);
    // xres = sum partials + b2 + h2
    w2red<<<S_LEN, blk, 0, stream>>>(wpart, b2_i, h2, xres);
  }

  wtrans64<<<dim3(VOCAB_PAD / 64, 32), blk, 0, stream>>>(head_w, headT, DMODEL, VOCAB, VOCAB_PAD);
  ln_dual<<<S_LEN, blk, 0, stream>>>(xres, model_g, model_b, head_g, head_b, hn16);
  // head: 256x256 tiles, 320 blocks
  gemm_db<256, 256, 32, 2, 4, 0, true, false, true, false>
      <<<dim3(VOCAB_PAD / 256, S_LEN / 256), dim3(512), 0, stream>>>(
      hn16, headT, head_bias, nullptr, out, nullptr,
      S_LEN, VOCAB, DMODEL, DMODEL, DMODEL);
}

// Round 9
// 1708.911 us; speedup vs baseline: 1.1829x; 1.1829x over previous
//
#include <hip/hip_runtime.h>
#include <math.h>

#define S_LEN 2048
#define DMODEL 2048
#define NHEAD 16
#define KVHEAD 2
#define DHEAD 128
#define NLAYER 4
#define VOCAB 10000
#define INNER_DIM 8192
#define LN_EPS 1e-5f
#define VOCAB_PAD 10240  // 40*256
#define QKVN 2560        // 2048 q + 256 k + 256 v

typedef __attribute__((ext_vector_type(4))) float f32x4;
typedef __attribute__((ext_vector_type(2))) float f32x2;
typedef __attribute__((ext_vector_type(8))) short s16x8;
typedef __attribute__((ext_vector_type(4))) short s16x4;

__device__ __forceinline__ short f2bf(float f) {
  union { float f; unsigned u; } v; v.f = f;
  unsigned r = v.u + 0x7FFFu + ((v.u >> 16) & 1u);  // RNE
  return (short)(r >> 16);
}

__device__ __forceinline__ float gelu_tanh(float x) {
  float z = 0.7978845608028654f * (x + 0.044715f * x * x * x);
  float t = __expf(-2.0f * fabsf(z));
  float th = (1.0f - t) / (1.0f + t);
  th = copysignf(th, z);
  return 0.5f * x * (1.0f + th);
}

__device__ __forceinline__ void glds16(const void* g, void* l) {
  __builtin_amdgcn_global_load_lds(
      (const __attribute__((address_space(1))) unsigned int*)g,
      (__attribute__((address_space(3))) unsigned int*)l, 16, 0, 0);
}

// ---------------- ALL per-layer weight transposes in one launch ----------
// 10496 tile-jobs: wq 1024 | wk 128 | wv 128 | wo 1024 | w1 4096 | w2 4096.
// All dims %64 == 0 -> no edge handling.
__global__ __launch_bounds__(256)
void wtrans_all(const float* __restrict__ wq, const float* __restrict__ wk,
                const float* __restrict__ wv, const float* __restrict__ wo,
                const float* __restrict__ w1, const float* __restrict__ w2,
                short* __restrict__ wqkvT, short* __restrict__ woT,
                short* __restrict__ w1T, short* __restrict__ w2T) {
  __shared__ float ld[64][65];
  int b = blockIdx.x;
  const float* W; short* WT; int gx, K;
  if (b < 1024)      { W = wq; WT = wqkvT; gx = 32; K = 2048; }
  else if (b < 1152) { b -= 1024; W = wk; WT = wqkvT + (size_t)2048 * 2048; gx = 4; K = 2048; }
  else if (b < 1280) { b -= 1152; W = wv; WT = wqkvT + (size_t)2304 * 2048; gx = 4; K = 2048; }
  else if (b < 2304) { b -= 1280; W = wo; WT = woT; gx = 32; K = 2048; }
  else if (b < 6400) { b -= 2304; W = w1; WT = w1T; gx = 128; K = 2048; }
  else               { b -= 6400; W = w2; WT = w2T; gx = 32; K = 8192; }
  const int N = gx * 64;
  const int n0 = (b % gx) * 64, k0 = (b / gx) * 64;
  const int tid = threadIdx.x;
  const int rbase = tid >> 4;
  const int c4 = (tid & 15) * 4;
#pragma unroll
  for (int q = 0; q < 4; ++q) {
    int kk = rbase + q * 16;
    f32x4 v = *(const f32x4*)(W + (size_t)(k0 + kk) * N + n0 + c4);
    ld[kk][c4 + 0] = v[0]; ld[kk][c4 + 1] = v[1];
    ld[kk][c4 + 2] = v[2]; ld[kk][c4 + 3] = v[3];
  }
  __syncthreads();
#pragma unroll
  for (int s = 0; s < 2; ++s) {
    int lin = tid + s * 256;
    int nn = lin >> 3;
    int ks = lin & 7;
    s16x8 o;
#pragma unroll
    for (int j = 0; j < 8; ++j) o[j] = f2bf(ld[ks * 8 + j][nn]);
    *(s16x8*)&WT[(size_t)(n0 + nn) * K + k0 + ks * 8] = o;
  }
}

// ---------------- head weight transpose (edge at N=10000) ----------------
__global__ __launch_bounds__(256)
void wtrans64(const float* __restrict__ W, short* __restrict__ WT,
              int K, int N, int NP) {
  __shared__ float ld[64][65];
  const int n0 = blockIdx.x * 64, k0 = blockIdx.y * 64;
  const int tid = threadIdx.x;
  const int rbase = tid >> 4;
  const int c4 = (tid & 15) * 4;
#pragma unroll
  for (int q = 0; q < 4; ++q) {
    int kk = rbase + q * 16;
    const float* wp = W + (size_t)(k0 + kk) * N + n0 + c4;
    float v0, v1, v2, v3;
    if (n0 + c4 + 3 < N) {
      f32x4 v = *(const f32x4*)wp;
      v0 = v[0]; v1 = v[1]; v2 = v[2]; v3 = v[3];
    } else {
      v0 = (n0 + c4 + 0 < N) ? wp[0] : 0.f;
      v1 = (n0 + c4 + 1 < N) ? wp[1] : 0.f;
      v2 = (n0 + c4 + 2 < N) ? wp[2] : 0.f;
      v3 = (n0 + c4 + 3 < N) ? wp[3] : 0.f;
    }
    ld[kk][c4 + 0] = v0; ld[kk][c4 + 1] = v1;
    ld[kk][c4 + 2] = v2; ld[kk][c4 + 3] = v3;
  }
  __syncthreads();
#pragma unroll
  for (int s = 0; s < 2; ++s) {
    int lin = tid + s * 256;
    int nn = lin >> 3;
    int ks = lin & 7;
    int n = n0 + nn;
    if (n < NP) {
      s16x8 o;
#pragma unroll
      for (int j = 0; j < 8; ++j)
        o[j] = (n < N) ? f2bf(ld[ks * 8 + j][nn]) : (short)0;
      *(s16x8*)&WT[(size_t)n * K + k0 + ks * 8] = o;
    }
  }
}

// ---------------- LN core: 3 rounds (model -> block -> attn) -------------
__device__ __forceinline__ void ln3_core(
    float (&v)[8], int tid, int wave,
    const float* __restrict__ mg, const float* __restrict__ mb,
    const float* __restrict__ bg, const float* __restrict__ bb,
    const float* __restrict__ ag, const float* __restrict__ ab,
    float* __restrict__ hbrow, short* __restrict__ hnrow,
    float rs[3][4], float rs2[3][4]) {
#pragma unroll
  for (int rnd = 0; rnd < 3; ++rnd) {
    float s = 0.f, s2 = 0.f;
#pragma unroll
    for (int i = 0; i < 8; ++i) { s += v[i]; s2 += v[i] * v[i]; }
#pragma unroll
    for (int off = 1; off < 64; off <<= 1) {
      s += __shfl_xor(s, off); s2 += __shfl_xor(s2, off);
    }
    if ((tid & 63) == 0) { rs[rnd][wave] = s; rs2[rnd][wave] = s2; }
    __syncthreads();
    s = rs[rnd][0] + rs[rnd][1] + rs[rnd][2] + rs[rnd][3];
    s2 = rs2[rnd][0] + rs2[rnd][1] + rs2[rnd][2] + rs2[rnd][3];
    const float mean = s * (1.f / DMODEL);
    const float var = s2 * (1.f / DMODEL) - mean * mean;
    const float rstd = rsqrtf(var + LN_EPS);
    const float* gg = (rnd == 0) ? mg : (rnd == 1) ? bg : ag;
    const float* bbv = (rnd == 0) ? mb : (rnd == 1) ? bb : ab;
#pragma unroll
    for (int i = 0; i < 8; ++i) {
      int idx = tid + i * 256;
      v[i] = (v[i] - mean) * rstd * gg[idx] + bbv[idx];
    }
    if (rnd == 1) {
#pragma unroll
      for (int i = 0; i < 8; ++i) hbrow[tid + i * 256] = v[i];
    }
  }
#pragma unroll
  for (int i = 0; i < 8; ++i) hnrow[tid + i * 256] = f2bf(v[i]);
}

// ---------------- triple LN from f32 buffer ----------------
__global__ __launch_bounds__(256)
void ln_triple(const float* __restrict__ in,
               const float* __restrict__ mg, const float* __restrict__ mb,
               const float* __restrict__ bg, const float* __restrict__ bb,
               const float* __restrict__ ag, const float* __restrict__ ab,
               float* __restrict__ hb, short* __restrict__ hn16) {
  const int row = blockIdx.x;
  const int tid = threadIdx.x;
  const int wave = tid >> 6;
  __shared__ float rs[3][4], rs2[3][4];
  float v[8];
  const float* x = in + (size_t)row * DMODEL;
#pragma unroll
  for (int i = 0; i < 8; ++i) v[i] = x[tid + i * 256];
  ln3_core(v, tid, wave, mg, mb, bg, bb, ag, ab,
           hb + (size_t)row * DMODEL, hn16 + (size_t)row * DMODEL, rs, rs2);
}

// ---------------- embed gather + triple LN ----------------
__global__ __launch_bounds__(256)
void embed_ln3(const int* __restrict__ text, const float* __restrict__ ew,
               const float* __restrict__ mg, const float* __restrict__ mb,
               const float* __restrict__ bg, const float* __restrict__ bb,
               const float* __restrict__ ag, const float* __restrict__ ab,
               float* __restrict__ hb, short* __restrict__ hn16) {
  const int row = blockIdx.x;
  const int tid = threadIdx.x;
  const int wave = tid >> 6;
  __shared__ float rs[3][4], rs2[3][4];
  float v[8];
  const float* x = ew + (size_t)text[row] * DMODEL;
#pragma unroll
  for (int i = 0; i < 8; ++i) v[i] = x[tid + i * 256];
  ln3_core(v, tid, wave, mg, mb, bg, bb, ag, ab,
           hb + (size_t)row * DMODEL, hn16 + (size_t)row * DMODEL, rs, rs2);
}

// ---------------- dual LN (model -> head), bf16 out ----------------
__global__ __launch_bounds__(256)
void ln_dual(const float* __restrict__ in,
             const float* __restrict__ mg, const float* __restrict__ mb,
             const float* __restrict__ hg, const float* __restrict__ hbv,
             short* __restrict__ out16) {
  const int row = blockIdx.x;
  const int tid = threadIdx.x;
  const int wave = tid >> 6;
  __shared__ float rs[2][4], rs2[2][4];
  float v[8];
  const float* x = in + (size_t)row * DMODEL;
#pragma unroll
  for (int i = 0; i < 8; ++i) v[i] = x[tid + i * 256];
#pragma unroll
  for (int rnd = 0; rnd < 2; ++rnd) {
    float s = 0.f, s2 = 0.f;
#pragma unroll
    for (int i = 0; i < 8; ++i) { s += v[i]; s2 += v[i] * v[i]; }
#pragma unroll
    for (int off = 1; off < 64; off <<= 1) {
      s += __shfl_xor(s, off); s2 += __shfl_xor(s2, off);
    }
    if ((tid & 63) == 0) { rs[rnd][wave] = s; rs2[rnd][wave] = s2; }
    __syncthreads();
    s = rs[rnd][0] + rs[rnd][1] + rs[rnd][2] + rs[rnd][3];
    s2 = rs2[rnd][0] + rs2[rnd][1] + rs2[rnd][2] + rs2[rnd][3];
    const float mean = s * (1.f / DMODEL);
    const float var = s2 * (1.f / DMODEL) - mean * mean;
    const float rstd = rsqrtf(var + LN_EPS);
    const float* gg = (rnd == 0) ? mg : hg;
    const float* bbv = (rnd == 0) ? mb : hbv;
#pragma unroll
    for (int i = 0; i < 8; ++i) {
      int idx = tid + i * 256;
      v[i] = (v[i] - mean) * rstd * gg[idx] + bbv[idx];
    }
  }
  short* o = out16 + (size_t)row * DMODEL;
#pragma unroll
  for (int i = 0; i < 8; ++i) o[tid + i * 256] = f2bf(v[i]);
}

// ---------------- fused q+k head-norm AND v-transpose, one launch --------
// blocks [0,9216): qk-norm rowjobs; [9216,9344): v transpose 64x64 tiles.
__global__ __launch_bounds__(256)
void normqk_vtrans(const float* __restrict__ qkvf,
                   const float* __restrict__ qg, const float* __restrict__ kg,
                   short* __restrict__ qb16, short* __restrict__ kb16,
                   short* __restrict__ vt) {
  __shared__ float ld[64][65];
  if (blockIdx.x < 9216) {
    const int rowjob = blockIdx.x * 4 + (threadIdx.x >> 6);
    const int lane = threadIdx.x & 63;
    const int s = rowjob / 18, sub = rowjob - s * 18;
    const float* p; short* o; const float* g;
    if (sub < 16) {
      p = qkvf + (size_t)s * QKVN + sub * DHEAD;
      o = qb16 + ((size_t)s * 16 + sub) * DHEAD;
      g = qg;
    } else {
      p = qkvf + (size_t)s * QKVN + 2048 + (sub - 16) * DHEAD;
      o = kb16 + ((size_t)s * 2 + (sub - 16)) * DHEAD;
      g = kg;
    }
    f32x2 t = *(const f32x2*)(p + lane * 2);
    float sm = t[0] + t[1];
    float s2 = t[0] * t[0] + t[1] * t[1];
#pragma unroll
    for (int off = 1; off < 64; off <<= 1) {
      sm += __shfl_xor(sm, off); s2 += __shfl_xor(s2, off);
    }
    const float mean = sm * (1.f / DHEAD);
    const float var = s2 * (1.f / DHEAD) - mean * mean;
    const float rstd = rsqrtf(var + LN_EPS);
    o[lane * 2] = f2bf((t[0] - mean) * rstd * g[lane * 2]);
    o[lane * 2 + 1] = f2bf((t[1] - mean) * rstd * g[lane * 2 + 1]);
  } else {
    const int b = blockIdx.x - 9216;
    const int n0 = (b & 3) * 64, k0 = (b >> 2) * 64;
    const int tid = threadIdx.x;
    const int rbase = tid >> 4;
    const int c4 = (tid & 15) * 4;
#pragma unroll
    for (int q = 0; q < 4; ++q) {
      int kk = rbase + q * 16;
      f32x4 v = *(const f32x4*)(qkvf + (size_t)(k0 + kk) * QKVN + 2304 + n0 + c4);
      ld[kk][c4 + 0] = v[0]; ld[kk][c4 + 1] = v[1];
      ld[kk][c4 + 2] = v[2]; ld[kk][c4 + 3] = v[3];
    }
    __syncthreads();
#pragma unroll
    for (int s = 0; s < 2; ++s) {
      int lin = tid + s * 256;
      int nn = lin >> 3;
      int ks = lin & 7;
      s16x8 o;
#pragma unroll
      for (int j = 0; j < 8; ++j) o[j] = f2bf(ld[ks * 8 + j][nn]);
      *(s16x8*)&vt[(size_t)(n0 + nn) * S_LEN + k0 + ks * 8] = o;
    }
  }
}

// ---------------- 2-phase double-buffered bf16 GEMM (R3/R6, proven) ------
template<int BM, int BN, int BK, int WM, int WN, int ACT, bool BIAS, bool RES,
         bool WF, bool WB>
__global__ __launch_bounds__(WM * WN * 64)
void gemm_db(const short* __restrict__ A, const short* __restrict__ BT,
             const float* __restrict__ bias, const float* __restrict__ res,
             float* __restrict__ Cf, short* __restrict__ Cb,
             int M, int N, int K) {
  constexpr int THREADS = WM * WN * 64;
  constexpr int MR = BM / WM / 16;
  constexpr int NR = BN / WN / 16;
  constexpr int KH = BK / 32;
  constexpr int SLOTS = BK / 8;
  constexpr int SMASK = SLOTS - 1;
  constexpr int RSH = (SLOTS == 8) ? 0 : 1;
  constexpr int CSH = (SLOTS == 8) ? 3 : 2;
  constexpr int NI = (BM * BK) / (THREADS * 8);
  __shared__ short As[2][BM * BK];
  __shared__ short Bs[2][BN * BK];
  const int tid = threadIdx.x;
  const int wave = tid >> 6, lane = tid & 63;
  const int g = lane >> 4, r = lane & 15;
  const int wm = wave / WN, wn = wave % WN;

  const int GY = gridDim.y;
  int lin = blockIdx.x + blockIdx.y * gridDim.x;
  int nwg = gridDim.x * GY;
  int sw = ((nwg & 7) == 0) ? ((lin & 7) * (nwg >> 3) + (lin >> 3)) : lin;
  const int bm = (sw % GY) * BM;
  const int bn = (sw / GY) * BN;

  const short* gsrc[2 * NI];
  short* ldst[2][2 * NI];
#pragma unroll
  for (int i = 0; i < NI; ++i) {
    int c = i * THREADS + tid;
    int row = c >> CSH;
    int slot = c & SMASK;
    int col = ((slot ^ ((row >> RSH) & SMASK)) << 3);
    gsrc[i] = A + (size_t)(bm + row) * K + col;
    gsrc[NI + i] = BT + (size_t)(bn + row) * K + col;
    int base = (i * THREADS + (wave << 6)) << 3;
    ldst[0][i] = &As[0][base]; ldst[0][NI + i] = &Bs[0][base];
    ldst[1][i] = &As[1][base]; ldst[1][NI + i] = &Bs[1][base];
  }

  f32x4 acc[MR][NR] = {};
  const int NT = K / BK;

#pragma unroll
  for (int i = 0; i < 2 * NI; ++i) glds16(gsrc[i], ldst[0][i]);
  asm volatile("s_waitcnt vmcnt(0)" ::: "memory");
  __syncthreads();

  for (int t = 0; t < NT; ++t) {
    const int cur = t & 1;
    const short* as = As[cur];
    const short* bs = Bs[cur];
    s16x8 bfr[NR][KH], af[MR / 2][KH];
#pragma unroll
    for (int n = 0; n < NR; ++n) {
      int rr = wn * (NR * 16) + n * 16 + r;
#pragma unroll
      for (int kk = 0; kk < KH; ++kk) {
        int lg = kk * 4 + g;
        bfr[n][kk] = *(const s16x8*)&bs[rr * BK + ((lg ^ ((rr >> RSH) & SMASK)) << 3)];
      }
    }
#pragma unroll
    for (int mm = 0; mm < MR / 2; ++mm) {
      int rr = wm * (MR * 16) + mm * 16 + r;
#pragma unroll
      for (int kk = 0; kk < KH; ++kk) {
        int lg = kk * 4 + g;
        af[mm][kk] = *(const s16x8*)&as[rr * BK + ((lg ^ ((rr >> RSH) & SMASK)) << 3)];
      }
    }
    if (t + 1 < NT) {
#pragma unroll
      for (int i = 0; i < 2 * NI; ++i) glds16(gsrc[i] + (t + 1) * BK, ldst[cur ^ 1][i]);
    }
    asm volatile("s_waitcnt lgkmcnt(0)" ::: "memory");
    __builtin_amdgcn_sched_barrier(0);
    __builtin_amdgcn_s_setprio(1);
#pragma unroll
    for (int mm = 0; mm < MR / 2; ++mm)
#pragma unroll
      for (int n = 0; n < NR; ++n)
#pragma unroll
        for (int kk = 0; kk < KH; ++kk)
          acc[mm][n] = __builtin_amdgcn_mfma_f32_16x16x32_bf16(af[mm][kk], bfr[n][kk], acc[mm][n], 0, 0, 0);
    __builtin_amdgcn_s_setprio(0);
    __builtin_amdgcn_s_barrier();
#pragma unroll
    for (int mm = 0; mm < MR / 2; ++mm) {
      int rr = wm * (MR * 16) + (MR / 2 + mm) * 16 + r;
#pragma unroll
      for (int kk = 0; kk < KH; ++kk) {
        int lg = kk * 4 + g;
        af[mm][kk] = *(const s16x8*)&as[rr * BK + ((lg ^ ((rr >> RSH) & SMASK)) << 3)];
      }
    }
    asm volatile("s_waitcnt lgkmcnt(0)" ::: "memory");
    __builtin_amdgcn_sched_barrier(0);
    __builtin_amdgcn_s_setprio(1);
#pragma unroll
    for (int mm = 0; mm < MR / 2; ++mm)
#pragma unroll
      for (int n = 0; n < NR; ++n)
#pragma unroll
        for (int kk = 0; kk < KH; ++kk)
          acc[MR / 2 + mm][n] = __builtin_amdgcn_mfma_f32_16x16x32_bf16(af[mm][kk], bfr[n][kk], acc[MR / 2 + mm][n], 0, 0, 0);
    __builtin_amdgcn_s_setprio(0);
    __syncthreads();
  }

#pragma unroll
  for (int m = 0; m < MR; ++m) {
    int row = bm + wm * (MR * 16) + m * 16 + g * 4;
#pragma unroll
    for (int n = 0; n < NR; ++n) {
      int col = bn + wn * (NR * 16) + n * 16 + r;
      if (col < N) {
#pragma unroll
        for (int j = 0; j < 4; ++j) {
          float v = acc[m][n][j];
          if (BIAS) v += bias[col];
          if (ACT) v = gelu_tanh(v);
          if (RES) v += res[(size_t)(row + j) * N + col];
          if (WF) Cf[(size_t)(row + j) * N + col] = v;
          if (WB) Cb[(size_t)(row + j) * N + col] = f2bf(v);
        }
      }
    }
  }
}

// ---------------- 8-phase 256x256 bf16 GEMM (R6, proven-neutral-or-better)
template<int ACT, bool BIAS, bool WF, bool WB>
__global__ __launch_bounds__(512, 2)
void gemm_8ph(const short* __restrict__ A, const short* __restrict__ BT,
              const float* __restrict__ bias,
              float* __restrict__ Cf, short* __restrict__ Cb,
              int M, int N, int K) {
  __shared__ short As[2][2][128 * 64];
  __shared__ short Bs[2][2][128 * 64];
  const int tid = threadIdx.x;
  const int wave = tid >> 6, lane = tid & 63;
  const int g = lane >> 4, r = lane & 15;
  const int wm = wave >> 2, wn = wave & 3;

  const int GY = gridDim.y;
  int lin = blockIdx.x + blockIdx.y * gridDim.x;
  int nwg = gridDim.x * GY;
  int sw = (lin & 7) * (nwg >> 3) + (lin >> 3);
  const int bm = (sw % GY) * 256;
  const int bn = (sw / GY) * 256;

  int rl[2], csw[2], ldo[2];
#pragma unroll
  for (int i = 0; i < 2; ++i) {
    int c = i * 512 + tid;
    rl[i] = c >> 3;
    csw[i] = (((c & 7) ^ (rl[i] & 7)) << 3);
    ldo[i] = (i * 512 + (wave << 6)) << 3;
  }
  const int NT = K >> 6;

  auto stA = [&](int t, int h, int d) {
#pragma unroll
    for (int i = 0; i < 2; ++i)
      glds16(A + (size_t)(bm + h * 128 + rl[i]) * K + t * 64 + csw[i], &As[d][h][ldo[i]]);
  };
  auto stB = [&](int t, int h, int d) {
#pragma unroll
    for (int i = 0; i < 2; ++i)
      glds16(BT + (size_t)(bn + h * 128 + rl[i]) * K + t * 64 + csw[i], &Bs[d][h][ldo[i]]);
  };

  stA(0, 0, 0); stA(0, 1, 0); stB(0, 0, 0); stB(0, 1, 0);
  stA(1, 0, 1);
  asm volatile("s_waitcnt vmcnt(2)" ::: "memory");
  asm volatile("s_barrier" ::: "memory");

  f32x4 acc[8][4] = {};
  s16x8 af[4][2], bf0[2][2], bf1[2][2];
  const int brow = (wn & 1) * 64;
  const int U = NT >> 1;

  for (int u = 0; u < U; ++u) {
    const int t1 = 2 * u + 1;
    const int q0 = (2 * u + 2 < NT) ? 2 * u + 2 : 0;
    const int q1 = (2 * u + 3 < NT) ? 2 * u + 3 : 0;
#pragma unroll
    for (int d = 0; d < 2; ++d) {
      const short* as = As[d][wm];
      const short* bsl = Bs[d][wn >> 1];
#pragma unroll
      for (int m = 0; m < 4; ++m)
#pragma unroll
        for (int kk = 0; kk < 2; ++kk)
          af[m][kk] = *(const s16x8*)&as[(m * 16 + r) * 64 + (((kk * 4 + g) ^ (r & 7)) << 3)];
#pragma unroll
      for (int n = 0; n < 2; ++n)
#pragma unroll
        for (int kk = 0; kk < 2; ++kk)
          bf0[n][kk] = *(const s16x8*)&bsl[(brow + n * 16 + r) * 64 + (((kk * 4 + g) ^ (r & 7)) << 3)];
      if (d == 0) stA(t1, 1, 1); else stA(q0, 1, 0);
      asm volatile("s_waitcnt lgkmcnt(0)" ::: "memory");
      __builtin_amdgcn_sched_barrier(0);
      __builtin_amdgcn_s_setprio(1);
#pragma unroll
      for (int m = 0; m < 4; ++m)
#pragma unroll
        for (int n = 0; n < 2; ++n)
#pragma unroll
          for (int kk = 0; kk < 2; ++kk)
            acc[m][n] = __builtin_amdgcn_mfma_f32_16x16x32_bf16(af[m][kk], bf0[n][kk], acc[m][n], 0, 0, 0);
      __builtin_amdgcn_s_setprio(0);
      asm volatile("s_barrier" ::: "memory");
#pragma unroll
      for (int n = 0; n < 2; ++n)
#pragma unroll
        for (int kk = 0; kk < 2; ++kk)
          bf1[n][kk] = *(const s16x8*)&bsl[(brow + (n + 2) * 16 + r) * 64 + (((kk * 4 + g) ^ (r & 7)) << 3)];
      if (d == 0) stB(t1, 0, 1); else stB(q0, 0, 0);
      asm volatile("s_waitcnt lgkmcnt(0)" ::: "memory");
      __builtin_amdgcn_sched_barrier(0);
      __builtin_amdgcn_s_setprio(1);
#pragma unroll
      for (int m = 0; m < 4; ++m)
#pragma unroll
        for (int n = 0; n < 2; ++n)
#pragma unroll
          for (int kk = 0; kk < 2; ++kk)
            acc[m][n + 2] = __builtin_amdgcn_mfma_f32_16x16x32_bf16(af[m][kk], bf1[n][kk], acc[m][n + 2], 0, 0, 0);
      __builtin_amdgcn_s_setprio(0);
      asm volatile("s_barrier" ::: "memory");
#pragma unroll
      for (int m = 0; m < 4; ++m)
#pragma unroll
        for (int kk = 0; kk < 2; ++kk)
          af[m][kk] = *(const s16x8*)&as[((m + 4) * 16 + r) * 64 + (((kk * 4 + g) ^ (r & 7)) << 3)];
      if (d == 0) stB(t1, 1, 1); else stB(q0, 1, 0);
      asm volatile("s_waitcnt lgkmcnt(0)" ::: "memory");
      __builtin_amdgcn_sched_barrier(0);
      __builtin_amdgcn_s_setprio(1);
#pragma unroll
      for (int m = 0; m < 4; ++m)
#pragma unroll
        for (int n = 0; n < 2; ++n)
#pragma unroll
          for (int kk = 0; kk < 2; ++kk)
            acc[m + 4][n + 2] = __builtin_amdgcn_mfma_f32_16x16x32_bf16(af[m][kk], bf1[n][kk], acc[m + 4][n + 2], 0, 0, 0);
      __builtin_amdgcn_s_setprio(0);
      asm volatile("s_barrier" ::: "memory");
      if (d == 0) stA(q0, 0, 0); else stA(q1, 0, 1);
      __builtin_amdgcn_s_setprio(1);
#pragma unroll
      for (int m = 0; m < 4; ++m)
#pragma unroll
        for (int n = 0; n < 2; ++n)
#pragma unroll
          for (int kk = 0; kk < 2; ++kk)
            acc[m + 4][n] = __builtin_amdgcn_mfma_f32_16x16x32_bf16(af[m][kk], bf0[n][kk], acc[m + 4][n], 0, 0, 0);
      __builtin_amdgcn_s_setprio(0);
      asm volatile("s_waitcnt vmcnt(2)" ::: "memory");
      asm volatile("s_barrier" ::: "memory");
    }
  }
  asm volatile("s_waitcnt vmcnt(0)" ::: "memory");

#pragma unroll
  for (int m = 0; m < 8; ++m) {
    int row = bm + wm * 128 + m * 16 + g * 4;
#pragma unroll
    for (int n = 0; n < 4; ++n) {
      int col = bn + wn * 64 + n * 16 + r;
      if (col < N) {
#pragma unroll
        for (int j = 0; j < 4; ++j) {
          float v = acc[m][n][j];
          if (BIAS) v += bias[col];
          if (ACT) v = gelu_tanh(v);
          if (WF) Cf[(size_t)(row + j) * N + col] = v;
          if (WB) Cb[(size_t)(row + j) * N + col] = f2bf(v);
        }
      }
    }
  }
}

// ---------------- Flash attention v2 (R6, proven) ------------------------
__global__ __launch_bounds__(256)
void attn_fwd2(const short* __restrict__ qbuf, const short* __restrict__ kbuf,
               const short* __restrict__ vtb, short* __restrict__ obuf) {
  __shared__ short Qs[64 * 128];
  __shared__ short Ks[64 * 128];
  __shared__ short Vt[128 * 64];
  __shared__ short Ps[4][16][88];
  const int tid = threadIdx.x;
  int lin = blockIdx.x + blockIdx.y * gridDim.x;
  int sw = (lin & 7) * 32 + (lin >> 3);
  const int pair = sw & 15;
  const int h = sw >> 4;
  const int kh = h >> 3;
  const int wave = tid >> 6, lane = tid & 63;
  const int g = lane >> 4, r = lane & 15;
  const float scale = 0.08838834764831845f;

#pragma unroll
  for (int half = 0; half < 2; ++half) {
    const int qt = half ? (31 - pair) : pair;
    const int qbase = qt * 64;
    __builtin_amdgcn_s_barrier();
#pragma unroll
    for (int i = 0; i < 4; ++i) {
      int c = i * 256 + tid;
      int row = c >> 4;
      int scol = (((c & 15) ^ (row & 7)) << 3);
      glds16(qbuf + (size_t)(qbase + row) * DMODEL + h * DHEAD + scol,
             &Qs[(i * 256 + (wave << 6)) << 3]);
    }
    f32x4 O[8] = {};
    float mst[4], lst[4];
#pragma unroll
    for (int j = 0; j < 4; ++j) { mst[j] = -1e30f; lst[j] = 0.f; }
    s16x8 aq[4];

    for (int jt = 0; jt <= qt; ++jt) {
      const int jb = jt * 64;
      if (jt) __builtin_amdgcn_s_barrier();
#pragma unroll
      for (int i = 0; i < 4; ++i) {
        int c = i * 256 + tid;
        int row = c >> 4;
        int scol = (((c & 15) ^ (row & 7)) << 3);
        glds16(kbuf + (size_t)(jb + row) * 256 + kh * DHEAD + scol,
               &Ks[(i * 256 + (wave << 6)) << 3]);
      }
#pragma unroll
      for (int i = 0; i < 4; ++i) {
        int c = i * 256 + tid;
        int row = c >> 3;
        int scol = (((c & 7) ^ (row & 7)) << 3);
        glds16(vtb + (size_t)(kh * 128 + row) * S_LEN + jb + scol,
               &Vt[(i * 256 + (wave << 6)) << 3]);
      }
      asm volatile("s_waitcnt vmcnt(0)" ::: "memory");
      __builtin_amdgcn_s_barrier();
      if (jt == 0) {
#pragma unroll
        for (int kc = 0; kc < 4; ++kc) {
          int rr = wave * 16 + r;
          aq[kc] = *(const s16x8*)&Qs[rr * 128 + ((((kc << 2) | g) ^ (rr & 7)) << 3)];
        }
      }
      f32x4 sc[4] = {};
      __builtin_amdgcn_s_setprio(1);
#pragma unroll
      for (int n = 0; n < 4; ++n) {
        int rr = n * 16 + r;
#pragma unroll
        for (int kc = 0; kc < 4; ++kc) {
          s16x8 bk = *(const s16x8*)&Ks[rr * 128 + ((((kc << 2) | g) ^ (rr & 7)) << 3)];
          sc[n] = __builtin_amdgcn_mfma_f32_16x16x32_bf16(aq[kc], bk, sc[n], 0, 0, 0);
        }
      }
      __builtin_amdgcn_s_setprio(0);
      if (jt == qt) {
#pragma unroll
        for (int j = 0; j < 4; ++j) {
          int irow = qbase + wave * 16 + g * 4 + j;
#pragma unroll
          for (int n = 0; n < 4; ++n) {
            int jcol = jb + n * 16 + r;
            sc[n][j] = (jcol <= irow) ? sc[n][j] * scale : -1e30f;
          }
        }
      } else {
#pragma unroll
        for (int j = 0; j < 4; ++j)
#pragma unroll
          for (int n = 0; n < 4; ++n) sc[n][j] *= scale;
      }
      float pmax[4], alpha[4], rsum[4];
#pragma unroll
      for (int j = 0; j < 4; ++j)
        pmax[j] = fmaxf(fmaxf(sc[0][j], sc[1][j]), fmaxf(sc[2][j], sc[3][j]));
#pragma unroll
      for (int off = 1; off < 16; off <<= 1)
#pragma unroll
        for (int j = 0; j < 4; ++j) pmax[j] = fmaxf(pmax[j], __shfl_xor(pmax[j], off));
#pragma unroll
      for (int j = 0; j < 4; ++j) {
        float mnew = fmaxf(mst[j], pmax[j]);
        alpha[j] = __expf(mst[j] - mnew);
        mst[j] = mnew;
#pragma unroll
        for (int n = 0; n < 4; ++n) sc[n][j] = __expf(sc[n][j] - mnew);
        rsum[j] = (sc[0][j] + sc[1][j]) + (sc[2][j] + sc[3][j]);
      }
#pragma unroll
      for (int off = 1; off < 16; off <<= 1)
#pragma unroll
        for (int j = 0; j < 4; ++j) rsum[j] += __shfl_xor(rsum[j], off);
#pragma unroll
      for (int j = 0; j < 4; ++j) lst[j] = lst[j] * alpha[j] + rsum[j];
#pragma unroll
      for (int d = 0; d < 8; ++d)
#pragma unroll
        for (int j = 0; j < 4; ++j) O[d][j] *= alpha[j];
#pragma unroll
      for (int j = 0; j < 4; ++j)
#pragma unroll
        for (int n = 0; n < 4; ++n)
          Ps[wave][g * 4 + j][n * 16 + r] = f2bf(sc[n][j]);
      s16x8 pa0 = *(const s16x8*)&Ps[wave][r][g * 8];
      s16x8 pa1 = *(const s16x8*)&Ps[wave][r][32 + g * 8];
      __builtin_amdgcn_s_setprio(1);
#pragma unroll
      for (int d = 0; d < 8; ++d) {
        int dd = d * 16 + r;
        s16x8 b0 = *(const s16x8*)&Vt[dd * 64 + ((g ^ (dd & 7)) << 3)];
        s16x8 b1 = *(const s16x8*)&Vt[dd * 64 + (((4 + g) ^ (dd & 7)) << 3)];
        O[d] = __builtin_amdgcn_mfma_f32_16x16x32_bf16(pa0, b0, O[d], 0, 0, 0);
        O[d] = __builtin_amdgcn_mfma_f32_16x16x32_bf16(pa1, b1, O[d], 0, 0, 0);
      }
      __builtin_amdgcn_s_setprio(0);
    }
    float linv[4];
#pragma unroll
    for (int j = 0; j < 4; ++j) linv[j] = 1.f / lst[j];
#pragma unroll
    for (int d = 0; d < 8; ++d)
#pragma unroll
      for (int j = 0; j < 4; ++j)
        obuf[(size_t)(qbase + wave * 16 + g * 4 + j) * DMODEL + h * DHEAD + d * 16 + r] =
            f2bf(O[d][j] * linv[j]);
  }
}

// ---------------- host side ----------------
extern "C" void kernel_launch(void* const* d_in, const int* in_sizes, int n_in,
                              void* d_out, int out_size, void* d_ws, size_t ws_size,
                              hipStream_t stream) {
  const int* text = (const int*)d_in[0];
  const float* embed_w = (const float*)d_in[1];
  const float* model_g = (const float*)d_in[2];
  const float* model_b = (const float*)d_in[3];
  const float* blk_g = (const float*)d_in[4];
  const float* blk_b = (const float*)d_in[5];
  const float* attn_g = (const float*)d_in[6];
  const float* attn_b = (const float*)d_in[7];
  const float* wq = (const float*)d_in[8];
  const float* wk = (const float*)d_in[9];
  const float* wv = (const float*)d_in[10];
  const float* wo = (const float*)d_in[11];
  const float* qn_g = (const float*)d_in[12];
  const float* kn_g = (const float*)d_in[13];
  const float* w1 = (const float*)d_in[14];
  const float* b1 = (const float*)d_in[15];
  const float* w2 = (const float*)d_in[16];
  const float* b2 = (const float*)d_in[17];
  const float* head_g = (const float*)d_in[18];
  const float* head_b = (const float*)d_in[19];
  const float* head_w = (const float*)d_in[20];
  const float* head_bias = (const float*)d_in[21];
  float* out = (float*)d_out;

  const size_t SD = (size_t)S_LEN * DMODEL;
  const size_t SKV = (size_t)S_LEN * KVHEAD * DHEAD;
  const size_t SI = (size_t)S_LEN * INNER_DIM;
  const size_t WD = (size_t)DMODEL * DMODEL;
  const size_t WKV = (size_t)DMODEL * KVHEAD * DHEAD;
  const size_t WI = (size_t)DMODEL * INNER_DIM;

  char* p = (char*)d_ws;
  float* xres  = (float*)p; p += SD * 4;
  float* hb    = (float*)p; p += SD * 4;
  float* h2    = (float*)p; p += SD * 4;
  float* qkvf  = (float*)p; p += (size_t)S_LEN * QKVN * 4;
  short* hn16  = (short*)p; p += SD * 2;
  short* h216  = (short*)p; p += SD * 2;
  short* ao16  = (short*)p; p += SD * 2;
  short* ffi16 = (short*)p; p += SI * 2;
  short* qb16  = (short*)p; p += SD * 2;
  short* kb16  = (short*)p; p += SKV * 2;
  short* vt16  = (short*)p; p += SKV * 2;
  short* wqkvT = (short*)p; p += (size_t)QKVN * DMODEL * 2;
  short* woT   = (short*)p; p += WD * 2;
  short* w1T   = (short*)p; p += WI * 2;
  short* w2T   = (short*)p; p += WI * 2;
  short* headT = w1T;  // reused after layers (10240*2048*2 = 42MB < 64MB)

  dim3 blk(256);
  // layer-0 inputs: embed + model/block/attn LNs fused
  embed_ln3<<<S_LEN, blk, 0, stream>>>(text, embed_w, model_g, model_b,
                                       blk_g, blk_b, attn_g, attn_b, hb, hn16);

  for (int i = 0; i < NLAYER; ++i) {
    wtrans_all<<<10496, blk, 0, stream>>>(
        wq + (size_t)i * WD, wk + (size_t)i * WKV, wv + (size_t)i * WKV,
        wo + (size_t)i * WD, w1 + (size_t)i * WI, w2 + (size_t)i * WI,
        wqkvT, woT, w1T, w2T);

    gemm_db<128, 128, 64, 2, 2, 0, false, false, true, false>
        <<<dim3(QKVN / 128, S_LEN / 128), blk, 0, stream>>>(
        hn16, wqkvT, nullptr, nullptr, qkvf, nullptr, S_LEN, QKVN, DMODEL);

    normqk_vtrans<<<9344, blk, 0, stream>>>(
        qkvf, qn_g + i * DHEAD, kn_g + i * DHEAD, qb16, kb16, vt16);

    attn_fwd2<<<dim3(16, 16), blk, 0, stream>>>(qb16, kb16, vt16, ao16);

    gemm_db<128, 128, 64, 2, 2, 0, false, true, true, true>
        <<<dim3(DMODEL / 128, S_LEN / 128), blk, 0, stream>>>(
        ao16, woT, nullptr, hb, h2, h216, S_LEN, DMODEL, DMODEL);
    gemm_8ph<1, true, false, true>
        <<<dim3(INNER_DIM / 256, S_LEN / 256), dim3(512), 0, stream>>>(
        h216, w1T, b1 + (size_t)i * INNER_DIM, nullptr, ffi16, S_LEN, INNER_DIM, DMODEL);
    gemm_db<128, 128, 64, 2, 2, 0, true, true, true, false>
        <<<dim3(DMODEL / 128, S_LEN / 128), blk, 0, stream>>>(
        ffi16, w2T, b2 + (size_t)i * DMODEL, h2, xres, nullptr, S_LEN, DMODEL, INNER_DIM);

    if (i + 1 < NLAYER) {
      ln_triple<<<S_LEN, blk, 0, stream>>>(
          xres, model_g, model_b,
          blk_g + (i + 1) * DMODEL, blk_b + (i + 1) * DMODEL,
          attn_g + (i + 1) * DMODEL, attn_b + (i + 1) * DMODEL, hb, hn16);
    }
  }

  wtrans64<<<dim3(VOCAB_PAD / 64, 32), blk, 0, stream>>>(head_w, headT, DMODEL, VOCAB, VOCAB_PAD);
  ln_dual<<<S_LEN, blk, 0, stream>>>(xres, model_g, model_b, head_g, head_b, hn16);
  gemm_8ph<0, true, true, false>
      <<<dim3(VOCAB_PAD / 256, S_LEN / 256), dim3(512), 0, stream>>>(
      hn16, headT, head_bias, out, nullptr, S_LEN, VOCAB, DMODEL);
}

// Round 10
// 1657.621 us; speedup vs baseline: 1.2196x; 1.0309x over previous
//
#include <hip/hip_runtime.h>
#include <math.h>

#define S_LEN 2048
#define DMODEL 2048
#define NHEAD 16
#define KVHEAD 2
#define DHEAD 128
#define NLAYER 4
#define VOCAB 10000
#define INNER_DIM 8192
#define LN_EPS 1e-5f
#define VOCAB_PAD 10240  // 40*256
#define QKVN 2560        // 2048 q + 256 k + 256 v

typedef __attribute__((ext_vector_type(4))) float f32x4;
typedef __attribute__((ext_vector_type(2))) float f32x2;
typedef __attribute__((ext_vector_type(8))) short s16x8;
typedef __attribute__((ext_vector_type(4))) short s16x4;

__device__ __forceinline__ short f2bf(float f) {
  union { float f; unsigned u; } v; v.f = f;
  unsigned r = v.u + 0x7FFFu + ((v.u >> 16) & 1u);  // RNE
  return (short)(r >> 16);
}

__device__ __forceinline__ float gelu_tanh(float x) {
  float z = 0.7978845608028654f * (x + 0.044715f * x * x * x);
  float t = __expf(-2.0f * fabsf(z));
  float th = (1.0f - t) / (1.0f + t);
  th = copysignf(th, z);
  return 0.5f * x * (1.0f + th);
}

__device__ __forceinline__ void glds16(const void* g, void* l) {
  __builtin_amdgcn_global_load_lds(
      (const __attribute__((address_space(1))) unsigned int*)g,
      (__attribute__((address_space(3))) unsigned int*)l, 16, 0, 0);
}

// ---------------- ALL per-layer weight transposes in one launch ----------
__global__ __launch_bounds__(256)
void wtrans_all(const float* __restrict__ wq, const float* __restrict__ wk,
                const float* __restrict__ wv, const float* __restrict__ wo,
                const float* __restrict__ w1, const float* __restrict__ w2,
                short* __restrict__ wqkvT, short* __restrict__ woT,
                short* __restrict__ w1T, short* __restrict__ w2T) {
  __shared__ float ld[64][65];
  int b = blockIdx.x;
  const float* W; short* WT; int gx, K;
  if (b < 1024)      { W = wq; WT = wqkvT; gx = 32; K = 2048; }
  else if (b < 1152) { b -= 1024; W = wk; WT = wqkvT + (size_t)2048 * 2048; gx = 4; K = 2048; }
  else if (b < 1280) { b -= 1152; W = wv; WT = wqkvT + (size_t)2304 * 2048; gx = 4; K = 2048; }
  else if (b < 2304) { b -= 1280; W = wo; WT = woT; gx = 32; K = 2048; }
  else if (b < 6400) { b -= 2304; W = w1; WT = w1T; gx = 128; K = 2048; }
  else               { b -= 6400; W = w2; WT = w2T; gx = 32; K = 8192; }
  const int N = gx * 64;
  const int n0 = (b % gx) * 64, k0 = (b / gx) * 64;
  const int tid = threadIdx.x;
  const int rbase = tid >> 4;
  const int c4 = (tid & 15) * 4;
#pragma unroll
  for (int q = 0; q < 4; ++q) {
    int kk = rbase + q * 16;
    f32x4 v = *(const f32x4*)(W + (size_t)(k0 + kk) * N + n0 + c4);
    ld[kk][c4 + 0] = v[0]; ld[kk][c4 + 1] = v[1];
    ld[kk][c4 + 2] = v[2]; ld[kk][c4 + 3] = v[3];
  }
  __syncthreads();
#pragma unroll
  for (int s = 0; s < 2; ++s) {
    int lin = tid + s * 256;
    int nn = lin >> 3;
    int ks = lin & 7;
    s16x8 o;
#pragma unroll
    for (int j = 0; j < 8; ++j) o[j] = f2bf(ld[ks * 8 + j][nn]);
    *(s16x8*)&WT[(size_t)(n0 + nn) * K + k0 + ks * 8] = o;
  }
}

// ---------------- head weight transpose (edge at N=10000) ----------------
__global__ __launch_bounds__(256)
void wtrans64(const float* __restrict__ W, short* __restrict__ WT,
              int K, int N, int NP) {
  __shared__ float ld[64][65];
  const int n0 = blockIdx.x * 64, k0 = blockIdx.y * 64;
  const int tid = threadIdx.x;
  const int rbase = tid >> 4;
  const int c4 = (tid & 15) * 4;
#pragma unroll
  for (int q = 0; q < 4; ++q) {
    int kk = rbase + q * 16;
    const float* wp = W + (size_t)(k0 + kk) * N + n0 + c4;
    float v0, v1, v2, v3;
    if (n0 + c4 + 3 < N) {
      f32x4 v = *(const f32x4*)wp;
      v0 = v[0]; v1 = v[1]; v2 = v[2]; v3 = v[3];
    } else {
      v0 = (n0 + c4 + 0 < N) ? wp[0] : 0.f;
      v1 = (n0 + c4 + 1 < N) ? wp[1] : 0.f;
      v2 = (n0 + c4 + 2 < N) ? wp[2] : 0.f;
      v3 = (n0 + c4 + 3 < N) ? wp[3] : 0.f;
    }
    ld[kk][c4 + 0] = v0; ld[kk][c4 + 1] = v1;
    ld[kk][c4 + 2] = v2; ld[kk][c4 + 3] = v3;
  }
  __syncthreads();
#pragma unroll
  for (int s = 0; s < 2; ++s) {
    int lin = tid + s * 256;
    int nn = lin >> 3;
    int ks = lin & 7;
    int n = n0 + nn;
    if (n < NP) {
      s16x8 o;
#pragma unroll
      for (int j = 0; j < 8; ++j)
        o[j] = (n < N) ? f2bf(ld[ks * 8 + j][nn]) : (short)0;
      *(s16x8*)&WT[(size_t)n * K + k0 + ks * 8] = o;
    }
  }
}

// ---------------- LN core: 3 rounds ----------------
__device__ __forceinline__ void ln3_core(
    float (&v)[8], int tid, int wave,
    const float* __restrict__ mg, const float* __restrict__ mb,
    const float* __restrict__ bg, const float* __restrict__ bb,
    const float* __restrict__ ag, const float* __restrict__ ab,
    float* __restrict__ hbrow, short* __restrict__ hnrow,
    float rs[3][4], float rs2[3][4]) {
#pragma unroll
  for (int rnd = 0; rnd < 3; ++rnd) {
    float s = 0.f, s2 = 0.f;
#pragma unroll
    for (int i = 0; i < 8; ++i) { s += v[i]; s2 += v[i] * v[i]; }
#pragma unroll
    for (int off = 1; off < 64; off <<= 1) {
      s += __shfl_xor(s, off); s2 += __shfl_xor(s2, off);
    }
    if ((tid & 63) == 0) { rs[rnd][wave] = s; rs2[rnd][wave] = s2; }
    __syncthreads();
    s = rs[rnd][0] + rs[rnd][1] + rs[rnd][2] + rs[rnd][3];
    s2 = rs2[rnd][0] + rs2[rnd][1] + rs2[rnd][2] + rs2[rnd][3];
    const float mean = s * (1.f / DMODEL);
    const float var = s2 * (1.f / DMODEL) - mean * mean;
    const float rstd = rsqrtf(var + LN_EPS);
    const float* gg = (rnd == 0) ? mg : (rnd == 1) ? bg : ag;
    const float* bbv = (rnd == 0) ? mb : (rnd == 1) ? bb : ab;
#pragma unroll
    for (int i = 0; i < 8; ++i) {
      int idx = tid + i * 256;
      v[i] = (v[i] - mean) * rstd * gg[idx] + bbv[idx];
    }
    if (rnd == 1) {
#pragma unroll
      for (int i = 0; i < 8; ++i) hbrow[tid + i * 256] = v[i];
    }
  }
#pragma unroll
  for (int i = 0; i < 8; ++i) hnrow[tid + i * 256] = f2bf(v[i]);
}

__global__ __launch_bounds__(256)
void ln_triple(const float* __restrict__ in,
               const float* __restrict__ mg, const float* __restrict__ mb,
               const float* __restrict__ bg, const float* __restrict__ bb,
               const float* __restrict__ ag, const float* __restrict__ ab,
               float* __restrict__ hb, short* __restrict__ hn16) {
  const int row = blockIdx.x;
  const int tid = threadIdx.x;
  const int wave = tid >> 6;
  __shared__ float rs[3][4], rs2[3][4];
  float v[8];
  const float* x = in + (size_t)row * DMODEL;
#pragma unroll
  for (int i = 0; i < 8; ++i) v[i] = x[tid + i * 256];
  ln3_core(v, tid, wave, mg, mb, bg, bb, ag, ab,
           hb + (size_t)row * DMODEL, hn16 + (size_t)row * DMODEL, rs, rs2);
}

__global__ __launch_bounds__(256)
void embed_ln3(const int* __restrict__ text, const float* __restrict__ ew,
               const float* __restrict__ mg, const float* __restrict__ mb,
               const float* __restrict__ bg, const float* __restrict__ bb,
               const float* __restrict__ ag, const float* __restrict__ ab,
               float* __restrict__ hb, short* __restrict__ hn16) {
  const int row = blockIdx.x;
  const int tid = threadIdx.x;
  const int wave = tid >> 6;
  __shared__ float rs[3][4], rs2[3][4];
  float v[8];
  const float* x = ew + (size_t)text[row] * DMODEL;
#pragma unroll
  for (int i = 0; i < 8; ++i) v[i] = x[tid + i * 256];
  ln3_core(v, tid, wave, mg, mb, bg, bb, ag, ab,
           hb + (size_t)row * DMODEL, hn16 + (size_t)row * DMODEL, rs, rs2);
}

__global__ __launch_bounds__(256)
void ln_dual(const float* __restrict__ in,
             const float* __restrict__ mg, const float* __restrict__ mb,
             const float* __restrict__ hg, const float* __restrict__ hbv,
             short* __restrict__ out16) {
  const int row = blockIdx.x;
  const int tid = threadIdx.x;
  const int wave = tid >> 6;
  __shared__ float rs[2][4], rs2[2][4];
  float v[8];
  const float* x = in + (size_t)row * DMODEL;
#pragma unroll
  for (int i = 0; i < 8; ++i) v[i] = x[tid + i * 256];
#pragma unroll
  for (int rnd = 0; rnd < 2; ++rnd) {
    float s = 0.f, s2 = 0.f;
#pragma unroll
    for (int i = 0; i < 8; ++i) { s += v[i]; s2 += v[i] * v[i]; }
#pragma unroll
    for (int off = 1; off < 64; off <<= 1) {
      s += __shfl_xor(s, off); s2 += __shfl_xor(s2, off);
    }
    if ((tid & 63) == 0) { rs[rnd][wave] = s; rs2[rnd][wave] = s2; }
    __syncthreads();
    s = rs[rnd][0] + rs[rnd][1] + rs[rnd][2] + rs[rnd][3];
    s2 = rs2[rnd][0] + rs2[rnd][1] + rs2[rnd][2] + rs2[rnd][3];
    const float mean = s * (1.f / DMODEL);
    const float var = s2 * (1.f / DMODEL) - mean * mean;
    const float rstd = rsqrtf(var + LN_EPS);
    const float* gg = (rnd == 0) ? mg : hg;
    const float* bbv = (rnd == 0) ? mb : hbv;
#pragma unroll
    for (int i = 0; i < 8; ++i) {
      int idx = tid + i * 256;
      v[i] = (v[i] - mean) * rstd * gg[idx] + bbv[idx];
    }
  }
  short* o = out16 + (size_t)row * DMODEL;
#pragma unroll
  for (int i = 0; i < 8; ++i) o[tid + i * 256] = f2bf(v[i]);
}

// ---------------- V transpose bf16: vb[S][256] -> vt[256][S] --------------
__global__ __launch_bounds__(256)
void vtrans_b16(const short* __restrict__ vb, short* __restrict__ vt) {
  __shared__ short ld[64][72];  // 144B stride (16B-aligned rows)
  const int b = blockIdx.x;     // 128 blocks: 4 (d-tiles) x 32 (s-tiles)
  const int n0 = (b & 3) * 64, k0 = (b >> 2) * 64;
  const int tid = threadIdx.x;
  {
    int row = tid >> 2, s0 = (tid & 3) * 16;
    s16x8 a = *(const s16x8*)(vb + (size_t)(k0 + row) * 256 + n0 + s0);
    s16x8 c = *(const s16x8*)(vb + (size_t)(k0 + row) * 256 + n0 + s0 + 8);
    *(s16x8*)&ld[row][s0] = a;
    *(s16x8*)&ld[row][s0 + 8] = c;
  }
  __syncthreads();
  {
    int d = tid >> 2, seg = tid & 3;
    s16x8 o0, o1;
#pragma unroll
    for (int i = 0; i < 8; ++i) o0[i] = ld[seg * 16 + i][d];
#pragma unroll
    for (int i = 0; i < 8; ++i) o1[i] = ld[seg * 16 + 8 + i][d];
    *(s16x8*)&vt[(size_t)(n0 + d) * S_LEN + k0 + seg * 16] = o0;
    *(s16x8*)&vt[(size_t)(n0 + d) * S_LEN + k0 + seg * 16 + 8] = o1;
  }
}

// ---------------- 2-phase double-buffered bf16 GEMM (proven) -------------
template<int BM, int BN, int BK, int WM, int WN, int ACT, bool BIAS, bool RES,
         bool WF, bool WB>
__global__ __launch_bounds__(WM * WN * 64)
void gemm_db(const short* __restrict__ A, const short* __restrict__ BT,
             const float* __restrict__ bias, const float* __restrict__ res,
             float* __restrict__ Cf, short* __restrict__ Cb,
             int M, int N, int K) {
  constexpr int THREADS = WM * WN * 64;
  constexpr int MR = BM / WM / 16;
  constexpr int NR = BN / WN / 16;
  constexpr int KH = BK / 32;
  constexpr int SLOTS = BK / 8;
  constexpr int SMASK = SLOTS - 1;
  constexpr int RSH = (SLOTS == 8) ? 0 : 1;
  constexpr int CSH = (SLOTS == 8) ? 3 : 2;
  constexpr int NI = (BM * BK) / (THREADS * 8);
  __shared__ short As[2][BM * BK];
  __shared__ short Bs[2][BN * BK];
  const int tid = threadIdx.x;
  const int wave = tid >> 6, lane = tid & 63;
  const int g = lane >> 4, r = lane & 15;
  const int wm = wave / WN, wn = wave % WN;

  const int GY = gridDim.y;
  int lin = blockIdx.x + blockIdx.y * gridDim.x;
  int nwg = gridDim.x * GY;
  int sw = ((nwg & 7) == 0) ? ((lin & 7) * (nwg >> 3) + (lin >> 3)) : lin;
  const int bm = (sw % GY) * BM;
  const int bn = (sw / GY) * BN;

  const short* gsrc[2 * NI];
  short* ldst[2][2 * NI];
#pragma unroll
  for (int i = 0; i < NI; ++i) {
    int c = i * THREADS + tid;
    int row = c >> CSH;
    int slot = c & SMASK;
    int col = ((slot ^ ((row >> RSH) & SMASK)) << 3);
    gsrc[i] = A + (size_t)(bm + row) * K + col;
    gsrc[NI + i] = BT + (size_t)(bn + row) * K + col;
    int base = (i * THREADS + (wave << 6)) << 3;
    ldst[0][i] = &As[0][base]; ldst[0][NI + i] = &Bs[0][base];
    ldst[1][i] = &As[1][base]; ldst[1][NI + i] = &Bs[1][base];
  }

  f32x4 acc[MR][NR] = {};
  const int NT = K / BK;

#pragma unroll
  for (int i = 0; i < 2 * NI; ++i) glds16(gsrc[i], ldst[0][i]);
  asm volatile("s_waitcnt vmcnt(0)" ::: "memory");
  __syncthreads();

  for (int t = 0; t < NT; ++t) {
    const int cur = t & 1;
    const short* as = As[cur];
    const short* bs = Bs[cur];
    s16x8 bfr[NR][KH], af[MR / 2][KH];
#pragma unroll
    for (int n = 0; n < NR; ++n) {
      int rr = wn * (NR * 16) + n * 16 + r;
#pragma unroll
      for (int kk = 0; kk < KH; ++kk) {
        int lg = kk * 4 + g;
        bfr[n][kk] = *(const s16x8*)&bs[rr * BK + ((lg ^ ((rr >> RSH) & SMASK)) << 3)];
      }
    }
#pragma unroll
    for (int mm = 0; mm < MR / 2; ++mm) {
      int rr = wm * (MR * 16) + mm * 16 + r;
#pragma unroll
      for (int kk = 0; kk < KH; ++kk) {
        int lg = kk * 4 + g;
        af[mm][kk] = *(const s16x8*)&as[rr * BK + ((lg ^ ((rr >> RSH) & SMASK)) << 3)];
      }
    }
    if (t + 1 < NT) {
#pragma unroll
      for (int i = 0; i < 2 * NI; ++i) glds16(gsrc[i] + (t + 1) * BK, ldst[cur ^ 1][i]);
    }
    asm volatile("s_waitcnt lgkmcnt(0)" ::: "memory");
    __builtin_amdgcn_sched_barrier(0);
    __builtin_amdgcn_s_setprio(1);
#pragma unroll
    for (int mm = 0; mm < MR / 2; ++mm)
#pragma unroll
      for (int n = 0; n < NR; ++n)
#pragma unroll
        for (int kk = 0; kk < KH; ++kk)
          acc[mm][n] = __builtin_amdgcn_mfma_f32_16x16x32_bf16(af[mm][kk], bfr[n][kk], acc[mm][n], 0, 0, 0);
    __builtin_amdgcn_s_setprio(0);
    __builtin_amdgcn_s_barrier();
#pragma unroll
    for (int mm = 0; mm < MR / 2; ++mm) {
      int rr = wm * (MR * 16) + (MR / 2 + mm) * 16 + r;
#pragma unroll
      for (int kk = 0; kk < KH; ++kk) {
        int lg = kk * 4 + g;
        af[mm][kk] = *(const s16x8*)&as[rr * BK + ((lg ^ ((rr >> RSH) & SMASK)) << 3)];
      }
    }
    asm volatile("s_waitcnt lgkmcnt(0)" ::: "memory");
    __builtin_amdgcn_sched_barrier(0);
    __builtin_amdgcn_s_setprio(1);
#pragma unroll
    for (int mm = 0; mm < MR / 2; ++mm)
#pragma unroll
      for (int n = 0; n < NR; ++n)
#pragma unroll
        for (int kk = 0; kk < KH; ++kk)
          acc[MR / 2 + mm][n] = __builtin_amdgcn_mfma_f32_16x16x32_bf16(af[mm][kk], bfr[n][kk], acc[MR / 2 + mm][n], 0, 0, 0);
    __builtin_amdgcn_s_setprio(0);
    __syncthreads();
  }

#pragma unroll
  for (int m = 0; m < MR; ++m) {
    int row = bm + wm * (MR * 16) + m * 16 + g * 4;
#pragma unroll
    for (int n = 0; n < NR; ++n) {
      int col = bn + wn * (NR * 16) + n * 16 + r;
      if (col < N) {
#pragma unroll
        for (int j = 0; j < 4; ++j) {
          float v = acc[m][n][j];
          if (BIAS) v += bias[col];
          if (ACT) v = gelu_tanh(v);
          if (RES) v += res[(size_t)(row + j) * N + col];
          if (WF) Cf[(size_t)(row + j) * N + col] = v;
          if (WB) Cb[(size_t)(row + j) * N + col] = f2bf(v);
        }
      }
    }
  }
}

// ---------------- qkv GEMM with fused qk-norm epilogue -------------------
// BM=128,BN=128(=DHEAD!),BK=64, 2x2 waves. Each col-tile is exactly one head:
// bn<2048 -> q head, norm+scale -> qb16; 2048<=bn<2304 -> k head -> kb16;
// bn>=2304 -> v slice -> vb16 (no norm). Row stats: shfl over 16 r-lanes +
// LDS combine across the 2 wn-waves, computed on f32 accumulators.
__global__ __launch_bounds__(256)
void gemm_qkv(const short* __restrict__ A, const short* __restrict__ BT,
              const float* __restrict__ qg, const float* __restrict__ kg,
              short* __restrict__ qb, short* __restrict__ kb,
              short* __restrict__ vb, int M, int K) {
  __shared__ short As[2][128 * 64];
  __shared__ short Bs[2][128 * 64];
  __shared__ float rsm[2][128], rs2m[2][128];
  const int tid = threadIdx.x;
  const int wave = tid >> 6, lane = tid & 63;
  const int g = lane >> 4, r = lane & 15;
  const int wm = wave >> 1, wn = wave & 1;

  const int GY = gridDim.y;
  int lin = blockIdx.x + blockIdx.y * gridDim.x;
  int nwg = gridDim.x * GY;
  int sw = (lin & 7) * (nwg >> 3) + (lin >> 3);  // 320 % 8 == 0
  const int bm = (sw % GY) * 128;
  const int bn = (sw / GY) * 128;

  const short* gsrc[8];
  short* ldst[2][8];
#pragma unroll
  for (int i = 0; i < 4; ++i) {
    int c = i * 256 + tid;
    int row = c >> 3;
    int slot = c & 7;
    int col = ((slot ^ (row & 7)) << 3);
    gsrc[i] = A + (size_t)(bm + row) * K + col;
    gsrc[4 + i] = BT + (size_t)(bn + row) * K + col;
    int base = (i * 256 + (wave << 6)) << 3;
    ldst[0][i] = &As[0][base]; ldst[0][4 + i] = &Bs[0][base];
    ldst[1][i] = &As[1][base]; ldst[1][4 + i] = &Bs[1][base];
  }

  f32x4 acc[4][4] = {};
  const int NT = K >> 6;

#pragma unroll
  for (int i = 0; i < 8; ++i) glds16(gsrc[i], ldst[0][i]);
  asm volatile("s_waitcnt vmcnt(0)" ::: "memory");
  __syncthreads();

  for (int t = 0; t < NT; ++t) {
    const int cur = t & 1;
    const short* as = As[cur];
    const short* bs = Bs[cur];
    s16x8 bfr[4][2], af[2][2];
#pragma unroll
    for (int n = 0; n < 4; ++n) {
      int rr = wn * 64 + n * 16 + r;
#pragma unroll
      for (int kk = 0; kk < 2; ++kk) {
        int lg = kk * 4 + g;
        bfr[n][kk] = *(const s16x8*)&bs[rr * 64 + ((lg ^ (rr & 7)) << 3)];
      }
    }
#pragma unroll
    for (int mm = 0; mm < 2; ++mm) {
      int rr = wm * 64 + mm * 16 + r;
#pragma unroll
      for (int kk = 0; kk < 2; ++kk) {
        int lg = kk * 4 + g;
        af[mm][kk] = *(const s16x8*)&as[rr * 64 + ((lg ^ (rr & 7)) << 3)];
      }
    }
    if (t + 1 < NT) {
#pragma unroll
      for (int i = 0; i < 8; ++i) glds16(gsrc[i] + (t + 1) * 64, ldst[cur ^ 1][i]);
    }
    asm volatile("s_waitcnt lgkmcnt(0)" ::: "memory");
    __builtin_amdgcn_sched_barrier(0);
    __builtin_amdgcn_s_setprio(1);
#pragma unroll
    for (int mm = 0; mm < 2; ++mm)
#pragma unroll
      for (int n = 0; n < 4; ++n)
#pragma unroll
        for (int kk = 0; kk < 2; ++kk)
          acc[mm][n] = __builtin_amdgcn_mfma_f32_16x16x32_bf16(af[mm][kk], bfr[n][kk], acc[mm][n], 0, 0, 0);
    __builtin_amdgcn_s_setprio(0);
    __builtin_amdgcn_s_barrier();
#pragma unroll
    for (int mm = 0; mm < 2; ++mm) {
      int rr = wm * 64 + (2 + mm) * 16 + r;
#pragma unroll
      for (int kk = 0; kk < 2; ++kk) {
        int lg = kk * 4 + g;
        af[mm][kk] = *(const s16x8*)&as[rr * 64 + ((lg ^ (rr & 7)) << 3)];
      }
    }
    asm volatile("s_waitcnt lgkmcnt(0)" ::: "memory");
    __builtin_amdgcn_sched_barrier(0);
    __builtin_amdgcn_s_setprio(1);
#pragma unroll
    for (int mm = 0; mm < 2; ++mm)
#pragma unroll
      for (int n = 0; n < 4; ++n)
#pragma unroll
        for (int kk = 0; kk < 2; ++kk)
          acc[2 + mm][n] = __builtin_amdgcn_mfma_f32_16x16x32_bf16(af[mm][kk], bfr[n][kk], acc[2 + mm][n], 0, 0, 0);
    __builtin_amdgcn_s_setprio(0);
    __syncthreads();
  }

  if (bn >= 2304) {
    // v slice: plain bf16 write, compact layout [s][256]
#pragma unroll
    for (int m = 0; m < 4; ++m) {
      int row = bm + wm * 64 + m * 16 + g * 4;
#pragma unroll
      for (int n = 0; n < 4; ++n) {
        int cl = wn * 64 + n * 16 + r;
#pragma unroll
        for (int j = 0; j < 4; ++j)
          vb[(size_t)(row + j) * 256 + (bn - 2304) + cl] = f2bf(acc[m][n][j]);
      }
    }
  } else {
    // qk-norm over the 128 cols of this head
    float ms[4][4], m2[4][4];
#pragma unroll
    for (int m = 0; m < 4; ++m)
#pragma unroll
      for (int j = 0; j < 4; ++j) {
        float s = 0.f, s2 = 0.f;
#pragma unroll
        for (int n = 0; n < 4; ++n) { float v = acc[m][n][j]; s += v; s2 += v * v; }
#pragma unroll
        for (int off = 1; off < 16; off <<= 1) {
          s += __shfl_xor(s, off); s2 += __shfl_xor(s2, off);
        }
        ms[m][j] = s; m2[m][j] = s2;
      }
    if (r == 0) {
#pragma unroll
      for (int m = 0; m < 4; ++m)
#pragma unroll
        for (int j = 0; j < 4; ++j) {
          int rl = wm * 64 + m * 16 + g * 4 + j;
          rsm[wn][rl] = ms[m][j]; rs2m[wn][rl] = m2[m][j];
        }
    }
    __syncthreads();
    const float* gv = (bn < 2048) ? qg : kg;
#pragma unroll
    for (int m = 0; m < 4; ++m)
#pragma unroll
      for (int j = 0; j < 4; ++j) {
        int rl = wm * 64 + m * 16 + g * 4 + j;
        float s = rsm[0][rl] + rsm[1][rl];
        float s2 = rs2m[0][rl] + rs2m[1][rl];
        float mean = s * (1.f / 128.f);
        float var = s2 * (1.f / 128.f) - mean * mean;
        float rstd = rsqrtf(var + LN_EPS);
        int srow = bm + rl;
#pragma unroll
        for (int n = 0; n < 4; ++n) {
          int cl = wn * 64 + n * 16 + r;
          float v = (acc[m][n][j] - mean) * rstd * gv[cl];
          if (bn < 2048) qb[(size_t)srow * 2048 + bn + cl] = f2bf(v);
          else kb[(size_t)srow * 256 + (bn - 2048) + cl] = f2bf(v);
        }
      }
  }
}

// ---------------- 8-phase 256x256 bf16 GEMM (R6, proven) -----------------
template<int ACT, bool BIAS, bool WF, bool WB>
__global__ __launch_bounds__(512, 2)
void gemm_8ph(const short* __restrict__ A, const short* __restrict__ BT,
              const float* __restrict__ bias,
              float* __restrict__ Cf, short* __restrict__ Cb,
              int M, int N, int K) {
  __shared__ short As[2][2][128 * 64];
  __shared__ short Bs[2][2][128 * 64];
  const int tid = threadIdx.x;
  const int wave = tid >> 6, lane = tid & 63;
  const int g = lane >> 4, r = lane & 15;
  const int wm = wave >> 2, wn = wave & 3;

  const int GY = gridDim.y;
  int lin = blockIdx.x + blockIdx.y * gridDim.x;
  int nwg = gridDim.x * GY;
  int sw = (lin & 7) * (nwg >> 3) + (lin >> 3);
  const int bm = (sw % GY) * 256;
  const int bn = (sw / GY) * 256;

  int rl[2], csw[2], ldo[2];
#pragma unroll
  for (int i = 0; i < 2; ++i) {
    int c = i * 512 + tid;
    rl[i] = c >> 3;
    csw[i] = (((c & 7) ^ (rl[i] & 7)) << 3);
    ldo[i] = (i * 512 + (wave << 6)) << 3;
  }
  const int NT = K >> 6;

  auto stA = [&](int t, int h, int d) {
#pragma unroll
    for (int i = 0; i < 2; ++i)
      glds16(A + (size_t)(bm + h * 128 + rl[i]) * K + t * 64 + csw[i], &As[d][h][ldo[i]]);
  };
  auto stB = [&](int t, int h, int d) {
#pragma unroll
    for (int i = 0; i < 2; ++i)
      glds16(BT + (size_t)(bn + h * 128 + rl[i]) * K + t * 64 + csw[i], &Bs[d][h][ldo[i]]);
  };

  stA(0, 0, 0); stA(0, 1, 0); stB(0, 0, 0); stB(0, 1, 0);
  stA(1, 0, 1);
  asm volatile("s_waitcnt vmcnt(2)" ::: "memory");
  asm volatile("s_barrier" ::: "memory");

  f32x4 acc[8][4] = {};
  s16x8 af[4][2], bf0[2][2], bf1[2][2];
  const int brow = (wn & 1) * 64;
  const int U = NT >> 1;

  for (int u = 0; u < U; ++u) {
    const int t1 = 2 * u + 1;
    const int q0 = (2 * u + 2 < NT) ? 2 * u + 2 : 0;
    const int q1 = (2 * u + 3 < NT) ? 2 * u + 3 : 0;
#pragma unroll
    for (int d = 0; d < 2; ++d) {
      const short* as = As[d][wm];
      const short* bsl = Bs[d][wn >> 1];
#pragma unroll
      for (int m = 0; m < 4; ++m)
#pragma unroll
        for (int kk = 0; kk < 2; ++kk)
          af[m][kk] = *(const s16x8*)&as[(m * 16 + r) * 64 + (((kk * 4 + g) ^ (r & 7)) << 3)];
#pragma unroll
      for (int n = 0; n < 2; ++n)
#pragma unroll
        for (int kk = 0; kk < 2; ++kk)
          bf0[n][kk] = *(const s16x8*)&bsl[(brow + n * 16 + r) * 64 + (((kk * 4 + g) ^ (r & 7)) << 3)];
      if (d == 0) stA(t1, 1, 1); else stA(q0, 1, 0);
      asm volatile("s_waitcnt lgkmcnt(0)" ::: "memory");
      __builtin_amdgcn_sched_barrier(0);
      __builtin_amdgcn_s_setprio(1);
#pragma unroll
      for (int m = 0; m < 4; ++m)
#pragma unroll
        for (int n = 0; n < 2; ++n)
#pragma unroll
          for (int kk = 0; kk < 2; ++kk)
            acc[m][n] = __builtin_amdgcn_mfma_f32_16x16x32_bf16(af[m][kk], bf0[n][kk], acc[m][n], 0, 0, 0);
      __builtin_amdgcn_s_setprio(0);
      asm volatile("s_barrier" ::: "memory");
#pragma unroll
      for (int n = 0; n < 2; ++n)
#pragma unroll
        for (int kk = 0; kk < 2; ++kk)
          bf1[n][kk] = *(const s16x8*)&bsl[(brow + (n + 2) * 16 + r) * 64 + (((kk * 4 + g) ^ (r & 7)) << 3)];
      if (d == 0) stB(t1, 0, 1); else stB(q0, 0, 0);
      asm volatile("s_waitcnt lgkmcnt(0)" ::: "memory");
      __builtin_amdgcn_sched_barrier(0);
      __builtin_amdgcn_s_setprio(1);
#pragma unroll
      for (int m = 0; m < 4; ++m)
#pragma unroll
        for (int n = 0; n < 2; ++n)
#pragma unroll
          for (int kk = 0; kk < 2; ++kk)
            acc[m][n + 2] = __builtin_amdgcn_mfma_f32_16x16x32_bf16(af[m][kk], bf1[n][kk], acc[m][n + 2], 0, 0, 0);
      __builtin_amdgcn_s_setprio(0);
      asm volatile("s_barrier" ::: "memory");
#pragma unroll
      for (int m = 0; m < 4; ++m)
#pragma unroll
        for (int kk = 0; kk < 2; ++kk)
          af[m][kk] = *(const s16x8*)&as[((m + 4) * 16 + r) * 64 + (((kk * 4 + g) ^ (r & 7)) << 3)];
      if (d == 0) stB(t1, 1, 1); else stB(q0, 1, 0);
      asm volatile("s_waitcnt lgkmcnt(0)" ::: "memory");
      __builtin_amdgcn_sched_barrier(0);
      __builtin_amdgcn_s_setprio(1);
#pragma unroll
      for (int m = 0; m < 4; ++m)
#pragma unroll
        for (int n = 0; n < 2; ++n)
#pragma unroll
          for (int kk = 0; kk < 2; ++kk)
            acc[m + 4][n + 2] = __builtin_amdgcn_mfma_f32_16x16x32_bf16(af[m][kk], bf1[n][kk], acc[m + 4][n + 2], 0, 0, 0);
      __builtin_amdgcn_s_setprio(0);
      asm volatile("s_barrier" ::: "memory");
      if (d == 0) stA(q0, 0, 0); else stA(q1, 0, 1);
      __builtin_amdgcn_s_setprio(1);
#pragma unroll
      for (int m = 0; m < 4; ++m)
#pragma unroll
        for (int n = 0; n < 2; ++n)
#pragma unroll
          for (int kk = 0; kk < 2; ++kk)
            acc[m + 4][n] = __builtin_amdgcn_mfma_f32_16x16x32_bf16(af[m][kk], bf0[n][kk], acc[m + 4][n], 0, 0, 0);
      __builtin_amdgcn_s_setprio(0);
      asm volatile("s_waitcnt vmcnt(2)" ::: "memory");
      asm volatile("s_barrier" ::: "memory");
    }
  }
  asm volatile("s_waitcnt vmcnt(0)" ::: "memory");

#pragma unroll
  for (int m = 0; m < 8; ++m) {
    int row = bm + wm * 128 + m * 16 + g * 4;
#pragma unroll
    for (int n = 0; n < 4; ++n) {
      int col = bn + wn * 64 + n * 16 + r;
      if (col < N) {
#pragma unroll
        for (int j = 0; j < 4; ++j) {
          float v = acc[m][n][j];
          if (BIAS) v += bias[col];
          if (ACT) v = gelu_tanh(v);
          if (WF) Cf[(size_t)(row + j) * N + col] = v;
          if (WB) Cb[(size_t)(row + j) * N + col] = f2bf(v);
        }
      }
    }
  }
}

// ---------------- Flash attention v3: split K/V waits --------------------
// V-landing hidden under QK^T+softmax (issue-early, drain-late).
__global__ __launch_bounds__(256)
void attn_fwd3(const short* __restrict__ qbuf, const short* __restrict__ kbuf,
               const short* __restrict__ vtb, short* __restrict__ obuf) {
  __shared__ short Qs[64 * 128];
  __shared__ short Ks[64 * 128];
  __shared__ short Vt[128 * 64];
  __shared__ short Ps[4][16][88];
  const int tid = threadIdx.x;
  int lin = blockIdx.x + blockIdx.y * gridDim.x;
  int sw = (lin & 7) * 32 + (lin >> 3);
  const int pair = sw & 15;
  const int h = sw >> 4;
  const int kh = h >> 3;
  const int wave = tid >> 6, lane = tid & 63;
  const int g = lane >> 4, r = lane & 15;
  const float scale = 0.08838834764831845f;

#pragma unroll
  for (int half = 0; half < 2; ++half) {
    const int qt = half ? (31 - pair) : pair;
    const int qbase = qt * 64;
    __builtin_amdgcn_s_barrier();
#pragma unroll
    for (int i = 0; i < 4; ++i) {
      int c = i * 256 + tid;
      int row = c >> 4;
      int scol = (((c & 15) ^ (row & 7)) << 3);
      glds16(qbuf + (size_t)(qbase + row) * DMODEL + h * DHEAD + scol,
             &Qs[(i * 256 + (wave << 6)) << 3]);
    }
    f32x4 O[8] = {};
    float mst[4], lst[4];
#pragma unroll
    for (int j = 0; j < 4; ++j) { mst[j] = -1e30f; lst[j] = 0.f; }
    s16x8 aq[4];

    for (int jt = 0; jt <= qt; ++jt) {
      const int jb = jt * 64;
      if (jt) __builtin_amdgcn_s_barrier();  // all waves' prior QK^T/PV reads done
      // issue K loads then V loads
#pragma unroll
      for (int i = 0; i < 4; ++i) {
        int c = i * 256 + tid;
        int row = c >> 4;
        int scol = (((c & 15) ^ (row & 7)) << 3);
        glds16(kbuf + (size_t)(jb + row) * 256 + kh * DHEAD + scol,
               &Ks[(i * 256 + (wave << 6)) << 3]);
      }
#pragma unroll
      for (int i = 0; i < 4; ++i) {
        int c = i * 256 + tid;
        int row = c >> 3;
        int scol = (((c & 7) ^ (row & 7)) << 3);
        glds16(vtb + (size_t)(kh * 128 + row) * S_LEN + jb + scol,
               &Vt[(i * 256 + (wave << 6)) << 3]);
      }
      // wait Q(first iter)+K only; V (4 loads) stays in flight
      asm volatile("s_waitcnt vmcnt(4)" ::: "memory");
      __builtin_amdgcn_s_barrier();
      if (jt == 0) {
#pragma unroll
        for (int kc = 0; kc < 4; ++kc) {
          int rr = wave * 16 + r;
          aq[kc] = *(const s16x8*)&Qs[rr * 128 + ((((kc << 2) | g) ^ (rr & 7)) << 3)];
        }
      }
      f32x4 sc[4] = {};
      __builtin_amdgcn_s_setprio(1);
#pragma unroll
      for (int n = 0; n < 4; ++n) {
        int rr = n * 16 + r;
#pragma unroll
        for (int kc = 0; kc < 4; ++kc) {
          s16x8 bk = *(const s16x8*)&Ks[rr * 128 + ((((kc << 2) | g) ^ (rr & 7)) << 3)];
          sc[n] = __builtin_amdgcn_mfma_f32_16x16x32_bf16(aq[kc], bk, sc[n], 0, 0, 0);
        }
      }
      __builtin_amdgcn_s_setprio(0);
      if (jt == qt) {
#pragma unroll
        for (int j = 0; j < 4; ++j) {
          int irow = qbase + wave * 16 + g * 4 + j;
#pragma unroll
          for (int n = 0; n < 4; ++n) {
            int jcol = jb + n * 16 + r;
            sc[n][j] = (jcol <= irow) ? sc[n][j] * scale : -1e30f;
          }
        }
      } else {
#pragma unroll
        for (int j = 0; j < 4; ++j)
#pragma unroll
          for (int n = 0; n < 4; ++n) sc[n][j] *= scale;
      }
      float pmax[4], alpha[4], rsum[4];
#pragma unroll
      for (int j = 0; j < 4; ++j)
        pmax[j] = fmaxf(fmaxf(sc[0][j], sc[1][j]), fmaxf(sc[2][j], sc[3][j]));
#pragma unroll
      for (int off = 1; off < 16; off <<= 1)
#pragma unroll
        for (int j = 0; j < 4; ++j) pmax[j] = fmaxf(pmax[j], __shfl_xor(pmax[j], off));
#pragma unroll
      for (int j = 0; j < 4; ++j) {
        float mnew = fmaxf(mst[j], pmax[j]);
        alpha[j] = __expf(mst[j] - mnew);
        mst[j] = mnew;
#pragma unroll
        for (int n = 0; n < 4; ++n) sc[n][j] = __expf(sc[n][j] - mnew);
        rsum[j] = (sc[0][j] + sc[1][j]) + (sc[2][j] + sc[3][j]);
      }
#pragma unroll
      for (int off = 1; off < 16; off <<= 1)
#pragma unroll
        for (int j = 0; j < 4; ++j) rsum[j] += __shfl_xor(rsum[j], off);
#pragma unroll
      for (int j = 0; j < 4; ++j) lst[j] = lst[j] * alpha[j] + rsum[j];
#pragma unroll
      for (int d = 0; d < 8; ++d)
#pragma unroll
        for (int j = 0; j < 4; ++j) O[d][j] *= alpha[j];
      // drain V + publish across waves, then PV
      asm volatile("s_waitcnt vmcnt(0)" ::: "memory");
      __builtin_amdgcn_s_barrier();
#pragma unroll
      for (int j = 0; j < 4; ++j)
#pragma unroll
        for (int n = 0; n < 4; ++n)
          Ps[wave][g * 4 + j][n * 16 + r] = f2bf(sc[n][j]);
      s16x8 pa0 = *(const s16x8*)&Ps[wave][r][g * 8];
      s16x8 pa1 = *(const s16x8*)&Ps[wave][r][32 + g * 8];
      __builtin_amdgcn_s_setprio(1);
#pragma unroll
      for (int d = 0; d < 8; ++d) {
        int dd = d * 16 + r;
        s16x8 b0 = *(const s16x8*)&Vt[dd * 64 + ((g ^ (dd & 7)) << 3)];
        s16x8 b1 = *(const s16x8*)&Vt[dd * 64 + (((4 + g) ^ (dd & 7)) << 3)];
        O[d] = __builtin_amdgcn_mfma_f32_16x16x32_bf16(pa0, b0, O[d], 0, 0, 0);
        O[d] = __builtin_amdgcn_mfma_f32_16x16x32_bf16(pa1, b1, O[d], 0, 0, 0);
      }
      __builtin_amdgcn_s_setprio(0);
    }
    float linv[4];
#pragma unroll
    for (int j = 0; j < 4; ++j) linv[j] = 1.f / lst[j];
#pragma unroll
    for (int d = 0; d < 8; ++d)
#pragma unroll
      for (int j = 0; j < 4; ++j)
        obuf[(size_t)(qbase + wave * 16 + g * 4 + j) * DMODEL + h * DHEAD + d * 16 + r] =
            f2bf(O[d][j] * linv[j]);
  }
}

// ---------------- host side ----------------
extern "C" void kernel_launch(void* const* d_in, const int* in_sizes, int n_in,
                              void* d_out, int out_size, void* d_ws, size_t ws_size,
                              hipStream_t stream) {
  const int* text = (const int*)d_in[0];
  const float* embed_w = (const float*)d_in[1];
  const float* model_g = (const float*)d_in[2];
  const float* model_b = (const float*)d_in[3];
  const float* blk_g = (const float*)d_in[4];
  const float* blk_b = (const float*)d_in[5];
  const float* attn_g = (const float*)d_in[6];
  const float* attn_b = (const float*)d_in[7];
  const float* wq = (const float*)d_in[8];
  const float* wk = (const float*)d_in[9];
  const float* wv = (const float*)d_in[10];
  const float* wo = (const float*)d_in[11];
  const float* qn_g = (const float*)d_in[12];
  const float* kn_g = (const float*)d_in[13];
  const float* w1 = (const float*)d_in[14];
  const float* b1 = (const float*)d_in[15];
  const float* w2 = (const float*)d_in[16];
  const float* b2 = (const float*)d_in[17];
  const float* head_g = (const float*)d_in[18];
  const float* head_b = (const float*)d_in[19];
  const float* head_w = (const float*)d_in[20];
  const float* head_bias = (const float*)d_in[21];
  float* out = (float*)d_out;

  const size_t SD = (size_t)S_LEN * DMODEL;
  const size_t SKV = (size_t)S_LEN * KVHEAD * DHEAD;
  const size_t SI = (size_t)S_LEN * INNER_DIM;
  const size_t WD = (size_t)DMODEL * DMODEL;
  const size_t WKV = (size_t)DMODEL * KVHEAD * DHEAD;
  const size_t WI = (size_t)DMODEL * INNER_DIM;

  char* p = (char*)d_ws;
  float* xres  = (float*)p; p += SD * 4;
  float* hb    = (float*)p; p += SD * 4;
  float* h2    = (float*)p; p += SD * 4;
  short* hn16  = (short*)p; p += SD * 2;
  short* h216  = (short*)p; p += SD * 2;
  short* ao16  = (short*)p; p += SD * 2;
  short* ffi16 = (short*)p; p += SI * 2;
  short* qb16  = (short*)p; p += SD * 2;
  short* kb16  = (short*)p; p += SKV * 2;
  short* vb16  = (short*)p; p += SKV * 2;
  short* vt16  = (short*)p; p += SKV * 2;
  short* wqkvT = (short*)p; p += (size_t)QKVN * DMODEL * 2;
  short* woT   = (short*)p; p += WD * 2;
  short* w1T   = (short*)p; p += WI * 2;
  short* w2T   = (short*)p; p += WI * 2;
  short* headT = w1T;  // reused after layers (10240*2048*2 = 42MB < 64MB)

  dim3 blk(256);
  embed_ln3<<<S_LEN, blk, 0, stream>>>(text, embed_w, model_g, model_b,
                                       blk_g, blk_b, attn_g, attn_b, hb, hn16);

  for (int i = 0; i < NLAYER; ++i) {
    wtrans_all<<<10496, blk, 0, stream>>>(
        wq + (size_t)i * WD, wk + (size_t)i * WKV, wv + (size_t)i * WKV,
        wo + (size_t)i * WD, w1 + (size_t)i * WI, w2 + (size_t)i * WI,
        wqkvT, woT, w1T, w2T);

    // qkv GEMM with fused qk-norm epilogue (320 blocks)
    gemm_qkv<<<dim3(QKVN / 128, S_LEN / 128), blk, 0, stream>>>(
        hn16, wqkvT, qn_g + i * DHEAD, kn_g + i * DHEAD,
        qb16, kb16, vb16, S_LEN, DMODEL);

    vtrans_b16<<<128, blk, 0, stream>>>(vb16, vt16);

    attn_fwd3<<<dim3(16, 16), blk, 0, stream>>>(qb16, kb16, vt16, ao16);

    gemm_db<128, 128, 64, 2, 2, 0, false, true, true, true>
        <<<dim3(DMODEL / 128, S_LEN / 128), blk, 0, stream>>>(
        ao16, woT, nullptr, hb, h2, h216, S_LEN, DMODEL, DMODEL);
    gemm_8ph<1, true, false, true>
        <<<dim3(INNER_DIM / 256, S_LEN / 256), dim3(512), 0, stream>>>(
        h216, w1T, b1 + (size_t)i * INNER_DIM, nullptr, ffi16, S_LEN, INNER_DIM, DMODEL);
    gemm_db<128, 128, 64, 2, 2, 0, true, true, true, false>
        <<<dim3(DMODEL / 128, S_LEN / 128), blk, 0, stream>>>(
        ffi16, w2T, b2 + (size_t)i * DMODEL, h2, xres, nullptr, S_LEN, DMODEL, INNER_DIM);

    if (i + 1 < NLAYER) {
      ln_triple<<<S_LEN, blk, 0, stream>>>(
          xres, model_g, model_b,
          blk_g + (i + 1) * DMODEL, blk_b + (i + 1) * DMODEL,
          attn_g + (i + 1) * DMODEL, attn_b + (i + 1) * DMODEL, hb, hn16);
    }
  }

  wtrans64<<<dim3(VOCAB_PAD / 64, 32), blk, 0, stream>>>(head_w, headT, DMODEL, VOCAB, VOCAB_PAD);
  ln_dual<<<S_LEN, blk, 0, stream>>>(xres, model_g, model_b, head_g, head_b, hn16);
  gemm_8ph<0, true, true, false>
      <<<dim3(VOCAB_PAD / 256, S_LEN / 256), dim3(512), 0, stream>>>(
      hn16, headT, head_bias, out, nullptr, S_LEN, VOCAB, DMODEL);
}

// Round 11
// 1641.370 us; speedup vs baseline: 1.2316x; 1.0099x over previous
//
#include <hip/hip_runtime.h>
#include <math.h>

#define S_LEN 2048
#define DMODEL 2048
#define NHEAD 16
#define KVHEAD 2
#define DHEAD 128
#define NLAYER 4
#define VOCAB 10000
#define INNER_DIM 8192
#define LN_EPS 1e-5f
#define VOCAB_PAD 10240  // 40*256
#define QKVN 2560        // 2048 q + 256 k + 256 v

typedef __attribute__((ext_vector_type(4))) float f32x4;
typedef __attribute__((ext_vector_type(2))) float f32x2;
typedef __attribute__((ext_vector_type(8))) short s16x8;
typedef __attribute__((ext_vector_type(4))) short s16x4;

__device__ __forceinline__ short f2bf(float f) {
  union { float f; unsigned u; } v; v.f = f;
  unsigned r = v.u + 0x7FFFu + ((v.u >> 16) & 1u);  // RNE
  return (short)(r >> 16);
}

__device__ __forceinline__ float gelu_tanh(float x) {
  float z = 0.7978845608028654f * (x + 0.044715f * x * x * x);
  float t = __expf(-2.0f * fabsf(z));
  float th = (1.0f - t) / (1.0f + t);
  th = copysignf(th, z);
  return 0.5f * x * (1.0f + th);
}

__device__ __forceinline__ void glds16(const void* g, void* l) {
  __builtin_amdgcn_global_load_lds(
      (const __attribute__((address_space(1))) unsigned int*)g,
      (__attribute__((address_space(3))) unsigned int*)l, 16, 0, 0);
}

// ---------------- ALL per-layer weight transposes in one launch ----------
__global__ __launch_bounds__(256)
void wtrans_all(const float* __restrict__ wq, const float* __restrict__ wk,
                const float* __restrict__ wv, const float* __restrict__ wo,
                const float* __restrict__ w1, const float* __restrict__ w2,
                short* __restrict__ wqkvT, short* __restrict__ woT,
                short* __restrict__ w1T, short* __restrict__ w2T) {
  __shared__ float ld[64][65];
  int b = blockIdx.x;
  const float* W; short* WT; int gx, K;
  if (b < 1024)      { W = wq; WT = wqkvT; gx = 32; K = 2048; }
  else if (b < 1152) { b -= 1024; W = wk; WT = wqkvT + (size_t)2048 * 2048; gx = 4; K = 2048; }
  else if (b < 1280) { b -= 1152; W = wv; WT = wqkvT + (size_t)2304 * 2048; gx = 4; K = 2048; }
  else if (b < 2304) { b -= 1280; W = wo; WT = woT; gx = 32; K = 2048; }
  else if (b < 6400) { b -= 2304; W = w1; WT = w1T; gx = 128; K = 2048; }
  else               { b -= 6400; W = w2; WT = w2T; gx = 32; K = 8192; }
  const int N = gx * 64;
  const int n0 = (b % gx) * 64, k0 = (b / gx) * 64;
  const int tid = threadIdx.x;
  const int rbase = tid >> 4;
  const int c4 = (tid & 15) * 4;
#pragma unroll
  for (int q = 0; q < 4; ++q) {
    int kk = rbase + q * 16;
    f32x4 v = *(const f32x4*)(W + (size_t)(k0 + kk) * N + n0 + c4);
    ld[kk][c4 + 0] = v[0]; ld[kk][c4 + 1] = v[1];
    ld[kk][c4 + 2] = v[2]; ld[kk][c4 + 3] = v[3];
  }
  __syncthreads();
#pragma unroll
  for (int s = 0; s < 2; ++s) {
    int lin = tid + s * 256;
    int nn = lin >> 3;
    int ks = lin & 7;
    s16x8 o;
#pragma unroll
    for (int j = 0; j < 8; ++j) o[j] = f2bf(ld[ks * 8 + j][nn]);
    *(s16x8*)&WT[(size_t)(n0 + nn) * K + k0 + ks * 8] = o;
  }
}

// ---------------- head weight transpose (edge at N=10000) ----------------
__global__ __launch_bounds__(256)
void wtrans64(const float* __restrict__ W, short* __restrict__ WT,
              int K, int N, int NP) {
  __shared__ float ld[64][65];
  const int n0 = blockIdx.x * 64, k0 = blockIdx.y * 64;
  const int tid = threadIdx.x;
  const int rbase = tid >> 4;
  const int c4 = (tid & 15) * 4;
#pragma unroll
  for (int q = 0; q < 4; ++q) {
    int kk = rbase + q * 16;
    const float* wp = W + (size_t)(k0 + kk) * N + n0 + c4;
    float v0, v1, v2, v3;
    if (n0 + c4 + 3 < N) {
      f32x4 v = *(const f32x4*)wp;
      v0 = v[0]; v1 = v[1]; v2 = v[2]; v3 = v[3];
    } else {
      v0 = (n0 + c4 + 0 < N) ? wp[0] : 0.f;
      v1 = (n0 + c4 + 1 < N) ? wp[1] : 0.f;
      v2 = (n0 + c4 + 2 < N) ? wp[2] : 0.f;
      v3 = (n0 + c4 + 3 < N) ? wp[3] : 0.f;
    }
    ld[kk][c4 + 0] = v0; ld[kk][c4 + 1] = v1;
    ld[kk][c4 + 2] = v2; ld[kk][c4 + 3] = v3;
  }
  __syncthreads();
#pragma unroll
  for (int s = 0; s < 2; ++s) {
    int lin = tid + s * 256;
    int nn = lin >> 3;
    int ks = lin & 7;
    int n = n0 + nn;
    if (n < NP) {
      s16x8 o;
#pragma unroll
      for (int j = 0; j < 8; ++j)
        o[j] = (n < N) ? f2bf(ld[ks * 8 + j][nn]) : (short)0;
      *(s16x8*)&WT[(size_t)n * K + k0 + ks * 8] = o;
    }
  }
}

// ---------------- LN core: 3 rounds ----------------
__device__ __forceinline__ void ln3_core(
    float (&v)[8], int tid, int wave,
    const float* __restrict__ mg, const float* __restrict__ mb,
    const float* __restrict__ bg, const float* __restrict__ bb,
    const float* __restrict__ ag, const float* __restrict__ ab,
    float* __restrict__ hbrow, short* __restrict__ hnrow,
    float rs[3][4], float rs2[3][4]) {
#pragma unroll
  for (int rnd = 0; rnd < 3; ++rnd) {
    float s = 0.f, s2 = 0.f;
#pragma unroll
    for (int i = 0; i < 8; ++i) { s += v[i]; s2 += v[i] * v[i]; }
#pragma unroll
    for (int off = 1; off < 64; off <<= 1) {
      s += __shfl_xor(s, off); s2 += __shfl_xor(s2, off);
    }
    if ((tid & 63) == 0) { rs[rnd][wave] = s; rs2[rnd][wave] = s2; }
    __syncthreads();
    s = rs[rnd][0] + rs[rnd][1] + rs[rnd][2] + rs[rnd][3];
    s2 = rs2[rnd][0] + rs2[rnd][1] + rs2[rnd][2] + rs2[rnd][3];
    const float mean = s * (1.f / DMODEL);
    const float var = s2 * (1.f / DMODEL) - mean * mean;
    const float rstd = rsqrtf(var + LN_EPS);
    const float* gg = (rnd == 0) ? mg : (rnd == 1) ? bg : ag;
    const float* bbv = (rnd == 0) ? mb : (rnd == 1) ? bb : ab;
#pragma unroll
    for (int i = 0; i < 8; ++i) {
      int idx = tid + i * 256;
      v[i] = (v[i] - mean) * rstd * gg[idx] + bbv[idx];
    }
    if (rnd == 1) {
#pragma unroll
      for (int i = 0; i < 8; ++i) hbrow[tid + i * 256] = v[i];
    }
  }
#pragma unroll
  for (int i = 0; i < 8; ++i) hnrow[tid + i * 256] = f2bf(v[i]);
}

__global__ __launch_bounds__(256)
void ln_triple(const float* __restrict__ in,
               const float* __restrict__ mg, const float* __restrict__ mb,
               const float* __restrict__ bg, const float* __restrict__ bb,
               const float* __restrict__ ag, const float* __restrict__ ab,
               float* __restrict__ hb, short* __restrict__ hn16) {
  const int row = blockIdx.x;
  const int tid = threadIdx.x;
  const int wave = tid >> 6;
  __shared__ float rs[3][4], rs2[3][4];
  float v[8];
  const float* x = in + (size_t)row * DMODEL;
#pragma unroll
  for (int i = 0; i < 8; ++i) v[i] = x[tid + i * 256];
  ln3_core(v, tid, wave, mg, mb, bg, bb, ag, ab,
           hb + (size_t)row * DMODEL, hn16 + (size_t)row * DMODEL, rs, rs2);
}

__global__ __launch_bounds__(256)
void embed_ln3(const int* __restrict__ text, const float* __restrict__ ew,
               const float* __restrict__ mg, const float* __restrict__ mb,
               const float* __restrict__ bg, const float* __restrict__ bb,
               const float* __restrict__ ag, const float* __restrict__ ab,
               float* __restrict__ hb, short* __restrict__ hn16) {
  const int row = blockIdx.x;
  const int tid = threadIdx.x;
  const int wave = tid >> 6;
  __shared__ float rs[3][4], rs2[3][4];
  float v[8];
  const float* x = ew + (size_t)text[row] * DMODEL;
#pragma unroll
  for (int i = 0; i < 8; ++i) v[i] = x[tid + i * 256];
  ln3_core(v, tid, wave, mg, mb, bg, bb, ag, ab,
           hb + (size_t)row * DMODEL, hn16 + (size_t)row * DMODEL, rs, rs2);
}

__global__ __launch_bounds__(256)
void ln_dual(const float* __restrict__ in,
             const float* __restrict__ mg, const float* __restrict__ mb,
             const float* __restrict__ hg, const float* __restrict__ hbv,
             short* __restrict__ out16) {
  const int row = blockIdx.x;
  const int tid = threadIdx.x;
  const int wave = tid >> 6;
  __shared__ float rs[2][4], rs2[2][4];
  float v[8];
  const float* x = in + (size_t)row * DMODEL;
#pragma unroll
  for (int i = 0; i < 8; ++i) v[i] = x[tid + i * 256];
#pragma unroll
  for (int rnd = 0; rnd < 2; ++rnd) {
    float s = 0.f, s2 = 0.f;
#pragma unroll
    for (int i = 0; i < 8; ++i) { s += v[i]; s2 += v[i] * v[i]; }
#pragma unroll
    for (int off = 1; off < 64; off <<= 1) {
      s += __shfl_xor(s, off); s2 += __shfl_xor(s2, off);
    }
    if ((tid & 63) == 0) { rs[rnd][wave] = s; rs2[rnd][wave] = s2; }
    __syncthreads();
    s = rs[rnd][0] + rs[rnd][1] + rs[rnd][2] + rs[rnd][3];
    s2 = rs2[rnd][0] + rs2[rnd][1] + rs2[rnd][2] + rs2[rnd][3];
    const float mean = s * (1.f / DMODEL);
    const float var = s2 * (1.f / DMODEL) - mean * mean;
    const float rstd = rsqrtf(var + LN_EPS);
    const float* gg = (rnd == 0) ? mg : hg;
    const float* bbv = (rnd == 0) ? mb : hbv;
#pragma unroll
    for (int i = 0; i < 8; ++i) {
      int idx = tid + i * 256;
      v[i] = (v[i] - mean) * rstd * gg[idx] + bbv[idx];
    }
  }
  short* o = out16 + (size_t)row * DMODEL;
#pragma unroll
  for (int i = 0; i < 8; ++i) o[tid + i * 256] = f2bf(v[i]);
}

// ---------------- 2-phase double-buffered bf16 GEMM (proven) -------------
template<int BM, int BN, int BK, int WM, int WN, int ACT, bool BIAS, bool RES,
         bool WF, bool WB>
__global__ __launch_bounds__(WM * WN * 64)
void gemm_db(const short* __restrict__ A, const short* __restrict__ BT,
             const float* __restrict__ bias, const float* __restrict__ res,
             float* __restrict__ Cf, short* __restrict__ Cb,
             int M, int N, int K) {
  constexpr int THREADS = WM * WN * 64;
  constexpr int MR = BM / WM / 16;
  constexpr int NR = BN / WN / 16;
  constexpr int KH = BK / 32;
  constexpr int SLOTS = BK / 8;
  constexpr int SMASK = SLOTS - 1;
  constexpr int RSH = (SLOTS == 8) ? 0 : 1;
  constexpr int CSH = (SLOTS == 8) ? 3 : 2;
  constexpr int NI = (BM * BK) / (THREADS * 8);
  __shared__ short As[2][BM * BK];
  __shared__ short Bs[2][BN * BK];
  const int tid = threadIdx.x;
  const int wave = tid >> 6, lane = tid & 63;
  const int g = lane >> 4, r = lane & 15;
  const int wm = wave / WN, wn = wave % WN;

  const int GY = gridDim.y;
  int lin = blockIdx.x + blockIdx.y * gridDim.x;
  int nwg = gridDim.x * GY;
  int sw = ((nwg & 7) == 0) ? ((lin & 7) * (nwg >> 3) + (lin >> 3)) : lin;
  const int bm = (sw % GY) * BM;
  const int bn = (sw / GY) * BN;

  const short* gsrc[2 * NI];
  short* ldst[2][2 * NI];
#pragma unroll
  for (int i = 0; i < NI; ++i) {
    int c = i * THREADS + tid;
    int row = c >> CSH;
    int slot = c & SMASK;
    int col = ((slot ^ ((row >> RSH) & SMASK)) << 3);
    gsrc[i] = A + (size_t)(bm + row) * K + col;
    gsrc[NI + i] = BT + (size_t)(bn + row) * K + col;
    int base = (i * THREADS + (wave << 6)) << 3;
    ldst[0][i] = &As[0][base]; ldst[0][NI + i] = &Bs[0][base];
    ldst[1][i] = &As[1][base]; ldst[1][NI + i] = &Bs[1][base];
  }

  f32x4 acc[MR][NR] = {};
  const int NT = K / BK;

#pragma unroll
  for (int i = 0; i < 2 * NI; ++i) glds16(gsrc[i], ldst[0][i]);
  asm volatile("s_waitcnt vmcnt(0)" ::: "memory");
  __syncthreads();

  for (int t = 0; t < NT; ++t) {
    const int cur = t & 1;
    const short* as = As[cur];
    const short* bs = Bs[cur];
    s16x8 bfr[NR][KH], af[MR / 2][KH];
#pragma unroll
    for (int n = 0; n < NR; ++n) {
      int rr = wn * (NR * 16) + n * 16 + r;
#pragma unroll
      for (int kk = 0; kk < KH; ++kk) {
        int lg = kk * 4 + g;
        bfr[n][kk] = *(const s16x8*)&bs[rr * BK + ((lg ^ ((rr >> RSH) & SMASK)) << 3)];
      }
    }
#pragma unroll
    for (int mm = 0; mm < MR / 2; ++mm) {
      int rr = wm * (MR * 16) + mm * 16 + r;
#pragma unroll
      for (int kk = 0; kk < KH; ++kk) {
        int lg = kk * 4 + g;
        af[mm][kk] = *(const s16x8*)&as[rr * BK + ((lg ^ ((rr >> RSH) & SMASK)) << 3)];
      }
    }
    if (t + 1 < NT) {
#pragma unroll
      for (int i = 0; i < 2 * NI; ++i) glds16(gsrc[i] + (t + 1) * BK, ldst[cur ^ 1][i]);
    }
    asm volatile("s_waitcnt lgkmcnt(0)" ::: "memory");
    __builtin_amdgcn_sched_barrier(0);
    __builtin_amdgcn_s_setprio(1);
#pragma unroll
    for (int mm = 0; mm < MR / 2; ++mm)
#pragma unroll
      for (int n = 0; n < NR; ++n)
#pragma unroll
        for (int kk = 0; kk < KH; ++kk)
          acc[mm][n] = __builtin_amdgcn_mfma_f32_16x16x32_bf16(af[mm][kk], bfr[n][kk], acc[mm][n], 0, 0, 0);
    __builtin_amdgcn_s_setprio(0);
    __builtin_amdgcn_s_barrier();
#pragma unroll
    for (int mm = 0; mm < MR / 2; ++mm) {
      int rr = wm * (MR * 16) + (MR / 2 + mm) * 16 + r;
#pragma unroll
      for (int kk = 0; kk < KH; ++kk) {
        int lg = kk * 4 + g;
        af[mm][kk] = *(const s16x8*)&as[rr * BK + ((lg ^ ((rr >> RSH) & SMASK)) << 3)];
      }
    }
    asm volatile("s_waitcnt lgkmcnt(0)" ::: "memory");
    __builtin_amdgcn_sched_barrier(0);
    __builtin_amdgcn_s_setprio(1);
#pragma unroll
    for (int mm = 0; mm < MR / 2; ++mm)
#pragma unroll
      for (int n = 0; n < NR; ++n)
#pragma unroll
        for (int kk = 0; kk < KH; ++kk)
          acc[MR / 2 + mm][n] = __builtin_amdgcn_mfma_f32_16x16x32_bf16(af[mm][kk], bfr[n][kk], acc[MR / 2 + mm][n], 0, 0, 0);
    __builtin_amdgcn_s_setprio(0);
    __syncthreads();
  }

#pragma unroll
  for (int m = 0; m < MR; ++m) {
    int row = bm + wm * (MR * 16) + m * 16 + g * 4;
#pragma unroll
    for (int n = 0; n < NR; ++n) {
      int col = bn + wn * (NR * 16) + n * 16 + r;
      if (col < N) {
#pragma unroll
        for (int j = 0; j < 4; ++j) {
          float v = acc[m][n][j];
          if (BIAS) v += bias[col];
          if (ACT) v = gelu_tanh(v);
          if (RES) v += res[(size_t)(row + j) * N + col];
          if (WF) Cf[(size_t)(row + j) * N + col] = v;
          if (WB) Cb[(size_t)(row + j) * N + col] = f2bf(v);
        }
      }
    }
  }
}

// ---------------- qkv GEMM with fused qk-norm + fused V-transpose --------
// BM=128,BN=128(=DHEAD),BK=64, 2x2 waves. bn<2048: q-head norm -> qb;
// 2048<=bn<2304: k-head norm -> kb; bn>=2304: V tile -> LDS transpose ->
// vt[256][S] directly (replaces the separate vtrans kernel).
__global__ __launch_bounds__(256)
void gemm_qkv(const short* __restrict__ A, const short* __restrict__ BT,
              const float* __restrict__ qg, const float* __restrict__ kg,
              short* __restrict__ qb, short* __restrict__ kb,
              short* __restrict__ vt, int M, int K) {
  __shared__ short As[2][128 * 64];
  __shared__ short Bs[2][128 * 64];
  __shared__ float rsm[2][128], rs2m[2][128];
  const int tid = threadIdx.x;
  const int wave = tid >> 6, lane = tid & 63;
  const int g = lane >> 4, r = lane & 15;
  const int wm = wave >> 1, wn = wave & 1;

  const int GY = gridDim.y;
  int lin = blockIdx.x + blockIdx.y * gridDim.x;
  int nwg = gridDim.x * GY;
  int sw = (lin & 7) * (nwg >> 3) + (lin >> 3);  // 320 % 8 == 0
  const int bm = (sw % GY) * 128;
  const int bn = (sw / GY) * 128;

  const short* gsrc[8];
  short* ldst[2][8];
#pragma unroll
  for (int i = 0; i < 4; ++i) {
    int c = i * 256 + tid;
    int row = c >> 3;
    int slot = c & 7;
    int col = ((slot ^ (row & 7)) << 3);
    gsrc[i] = A + (size_t)(bm + row) * K + col;
    gsrc[4 + i] = BT + (size_t)(bn + row) * K + col;
    int base = (i * 256 + (wave << 6)) << 3;
    ldst[0][i] = &As[0][base]; ldst[0][4 + i] = &Bs[0][base];
    ldst[1][i] = &As[1][base]; ldst[1][4 + i] = &Bs[1][base];
  }

  f32x4 acc[4][4] = {};
  const int NT = K >> 6;

#pragma unroll
  for (int i = 0; i < 8; ++i) glds16(gsrc[i], ldst[0][i]);
  asm volatile("s_waitcnt vmcnt(0)" ::: "memory");
  __syncthreads();

  for (int t = 0; t < NT; ++t) {
    const int cur = t & 1;
    const short* as = As[cur];
    const short* bs = Bs[cur];
    s16x8 bfr[4][2], af[2][2];
#pragma unroll
    for (int n = 0; n < 4; ++n) {
      int rr = wn * 64 + n * 16 + r;
#pragma unroll
      for (int kk = 0; kk < 2; ++kk) {
        int lg = kk * 4 + g;
        bfr[n][kk] = *(const s16x8*)&bs[rr * 64 + ((lg ^ (rr & 7)) << 3)];
      }
    }
#pragma unroll
    for (int mm = 0; mm < 2; ++mm) {
      int rr = wm * 64 + mm * 16 + r;
#pragma unroll
      for (int kk = 0; kk < 2; ++kk) {
        int lg = kk * 4 + g;
        af[mm][kk] = *(const s16x8*)&as[rr * 64 + ((lg ^ (rr & 7)) << 3)];
      }
    }
    if (t + 1 < NT) {
#pragma unroll
      for (int i = 0; i < 8; ++i) glds16(gsrc[i] + (t + 1) * 64, ldst[cur ^ 1][i]);
    }
    asm volatile("s_waitcnt lgkmcnt(0)" ::: "memory");
    __builtin_amdgcn_sched_barrier(0);
    __builtin_amdgcn_s_setprio(1);
#pragma unroll
    for (int mm = 0; mm < 2; ++mm)
#pragma unroll
      for (int n = 0; n < 4; ++n)
#pragma unroll
        for (int kk = 0; kk < 2; ++kk)
          acc[mm][n] = __builtin_amdgcn_mfma_f32_16x16x32_bf16(af[mm][kk], bfr[n][kk], acc[mm][n], 0, 0, 0);
    __builtin_amdgcn_s_setprio(0);
    __builtin_amdgcn_s_barrier();
#pragma unroll
    for (int mm = 0; mm < 2; ++mm) {
      int rr = wm * 64 + (2 + mm) * 16 + r;
#pragma unroll
      for (int kk = 0; kk < 2; ++kk) {
        int lg = kk * 4 + g;
        af[mm][kk] = *(const s16x8*)&as[rr * 64 + ((lg ^ (rr & 7)) << 3)];
      }
    }
    asm volatile("s_waitcnt lgkmcnt(0)" ::: "memory");
    __builtin_amdgcn_sched_barrier(0);
    __builtin_amdgcn_s_setprio(1);
#pragma unroll
    for (int mm = 0; mm < 2; ++mm)
#pragma unroll
      for (int n = 0; n < 4; ++n)
#pragma unroll
        for (int kk = 0; kk < 2; ++kk)
          acc[2 + mm][n] = __builtin_amdgcn_mfma_f32_16x16x32_bf16(af[mm][kk], bfr[n][kk], acc[2 + mm][n], 0, 0, 0);
    __builtin_amdgcn_s_setprio(0);
    __syncthreads();
  }

  if (bn >= 2304) {
    // V tile: write bf16 into LDS [s][d] (reuse As: 128*128 = 16384 shorts),
    // then transposed coalesced-in-s writes to vt[256][S].
    short* ld = &As[0][0];
#pragma unroll
    for (int m = 0; m < 4; ++m) {
      int sl = wm * 64 + m * 16 + g * 4;
#pragma unroll
      for (int n = 0; n < 4; ++n) {
        int dl = wn * 64 + n * 16 + r;
#pragma unroll
        for (int j = 0; j < 4; ++j)
          ld[(sl + j) * 128 + dl] = f2bf(acc[m][n][j]);
      }
    }
    __syncthreads();
    const int dl = tid & 127;
    const int sh = (tid >> 7) * 64;
    short* dst = vt + (size_t)(bn - 2304 + dl) * S_LEN + bm + sh;
#pragma unroll
    for (int v = 0; v < 8; ++v) {
      s16x8 o;
#pragma unroll
      for (int i = 0; i < 8; ++i) o[i] = ld[(sh + v * 8 + i) * 128 + dl];
      *(s16x8*)(dst + v * 8) = o;
    }
  } else {
    // qk-norm over the 128 cols of this head
    float ms[4][4], m2[4][4];
#pragma unroll
    for (int m = 0; m < 4; ++m)
#pragma unroll
      for (int j = 0; j < 4; ++j) {
        float s = 0.f, s2 = 0.f;
#pragma unroll
        for (int n = 0; n < 4; ++n) { float v = acc[m][n][j]; s += v; s2 += v * v; }
#pragma unroll
        for (int off = 1; off < 16; off <<= 1) {
          s += __shfl_xor(s, off); s2 += __shfl_xor(s2, off);
        }
        ms[m][j] = s; m2[m][j] = s2;
      }
    if (r == 0) {
#pragma unroll
      for (int m = 0; m < 4; ++m)
#pragma unroll
        for (int j = 0; j < 4; ++j) {
          int rl = wm * 64 + m * 16 + g * 4 + j;
          rsm[wn][rl] = ms[m][j]; rs2m[wn][rl] = m2[m][j];
        }
    }
    __syncthreads();
    const float* gv = (bn < 2048) ? qg : kg;
#pragma unroll
    for (int m = 0; m < 4; ++m)
#pragma unroll
      for (int j = 0; j < 4; ++j) {
        int rl = wm * 64 + m * 16 + g * 4 + j;
        float s = rsm[0][rl] + rsm[1][rl];
        float s2 = rs2m[0][rl] + rs2m[1][rl];
        float mean = s * (1.f / 128.f);
        float var = s2 * (1.f / 128.f) - mean * mean;
        float rstd = rsqrtf(var + LN_EPS);
        int srow = bm + rl;
#pragma unroll
        for (int n = 0; n < 4; ++n) {
          int cl = wn * 64 + n * 16 + r;
          float v = (acc[m][n][j] - mean) * rstd * gv[cl];
          if (bn < 2048) qb[(size_t)srow * 2048 + bn + cl] = f2bf(v);
          else kb[(size_t)srow * 256 + (bn - 2048) + cl] = f2bf(v);
        }
      }
  }
}

// ---------------- Flash attention v3: split K/V waits (R10, proven) ------
__global__ __launch_bounds__(256)
void attn_fwd3(const short* __restrict__ qbuf, const short* __restrict__ kbuf,
               const short* __restrict__ vtb, short* __restrict__ obuf) {
  __shared__ short Qs[64 * 128];
  __shared__ short Ks[64 * 128];
  __shared__ short Vt[128 * 64];
  __shared__ short Ps[4][16][88];
  const int tid = threadIdx.x;
  int lin = blockIdx.x + blockIdx.y * gridDim.x;
  int sw = (lin & 7) * 32 + (lin >> 3);
  const int pair = sw & 15;
  const int h = sw >> 4;
  const int kh = h >> 3;
  const int wave = tid >> 6, lane = tid & 63;
  const int g = lane >> 4, r = lane & 15;
  const float scale = 0.08838834764831845f;

#pragma unroll
  for (int half = 0; half < 2; ++half) {
    const int qt = half ? (31 - pair) : pair;
    const int qbase = qt * 64;
    __builtin_amdgcn_s_barrier();
#pragma unroll
    for (int i = 0; i < 4; ++i) {
      int c = i * 256 + tid;
      int row = c >> 4;
      int scol = (((c & 15) ^ (row & 7)) << 3);
      glds16(qbuf + (size_t)(qbase + row) * DMODEL + h * DHEAD + scol,
             &Qs[(i * 256 + (wave << 6)) << 3]);
    }
    f32x4 O[8] = {};
    float mst[4], lst[4];
#pragma unroll
    for (int j = 0; j < 4; ++j) { mst[j] = -1e30f; lst[j] = 0.f; }
    s16x8 aq[4];

    for (int jt = 0; jt <= qt; ++jt) {
      const int jb = jt * 64;
      if (jt) __builtin_amdgcn_s_barrier();
#pragma unroll
      for (int i = 0; i < 4; ++i) {
        int c = i * 256 + tid;
        int row = c >> 4;
        int scol = (((c & 15) ^ (row & 7)) << 3);
        glds16(kbuf + (size_t)(jb + row) * 256 + kh * DHEAD + scol,
               &Ks[(i * 256 + (wave << 6)) << 3]);
      }
#pragma unroll
      for (int i = 0; i < 4; ++i) {
        int c = i * 256 + tid;
        int row = c >> 3;
        int scol = (((c & 7) ^ (row & 7)) << 3);
        glds16(vtb + (size_t)(kh * 128 + row) * S_LEN + jb + scol,
               &Vt[(i * 256 + (wave << 6)) << 3]);
      }
      asm volatile("s_waitcnt vmcnt(4)" ::: "memory");
      __builtin_amdgcn_s_barrier();
      if (jt == 0) {
#pragma unroll
        for (int kc = 0; kc < 4; ++kc) {
          int rr = wave * 16 + r;
          aq[kc] = *(const s16x8*)&Qs[rr * 128 + ((((kc << 2) | g) ^ (rr & 7)) << 3)];
        }
      }
      f32x4 sc[4] = {};
      __builtin_amdgcn_s_setprio(1);
#pragma unroll
      for (int n = 0; n < 4; ++n) {
        int rr = n * 16 + r;
#pragma unroll
        for (int kc = 0; kc < 4; ++kc) {
          s16x8 bk = *(const s16x8*)&Ks[rr * 128 + ((((kc << 2) | g) ^ (rr & 7)) << 3)];
          sc[n] = __builtin_amdgcn_mfma_f32_16x16x32_bf16(aq[kc], bk, sc[n], 0, 0, 0);
        }
      }
      __builtin_amdgcn_s_setprio(0);
      if (jt == qt) {
#pragma unroll
        for (int j = 0; j < 4; ++j) {
          int irow = qbase + wave * 16 + g * 4 + j;
#pragma unroll
          for (int n = 0; n < 4; ++n) {
            int jcol = jb + n * 16 + r;
            sc[n][j] = (jcol <= irow) ? sc[n][j] * scale : -1e30f;
          }
        }
      } else {
#pragma unroll
        for (int j = 0; j < 4; ++j)
#pragma unroll
          for (int n = 0; n < 4; ++n) sc[n][j] *= scale;
      }
      float pmax[4], alpha[4], rsum[4];
#pragma unroll
      for (int j = 0; j < 4; ++j)
        pmax[j] = fmaxf(fmaxf(sc[0][j], sc[1][j]), fmaxf(sc[2][j], sc[3][j]));
#pragma unroll
      for (int off = 1; off < 16; off <<= 1)
#pragma unroll
        for (int j = 0; j < 4; ++j) pmax[j] = fmaxf(pmax[j], __shfl_xor(pmax[j], off));
#pragma unroll
      for (int j = 0; j < 4; ++j) {
        float mnew = fmaxf(mst[j], pmax[j]);
        alpha[j] = __expf(mst[j] - mnew);
        mst[j] = mnew;
#pragma unroll
        for (int n = 0; n < 4; ++n) sc[n][j] = __expf(sc[n][j] - mnew);
        rsum[j] = (sc[0][j] + sc[1][j]) + (sc[2][j] + sc[3][j]);
      }
#pragma unroll
      for (int off = 1; off < 16; off <<= 1)
#pragma unroll
        for (int j = 0; j < 4; ++j) rsum[j] += __shfl_xor(rsum[j], off);
#pragma unroll
      for (int j = 0; j < 4; ++j) lst[j] = lst[j] * alpha[j] + rsum[j];
#pragma unroll
      for (int d = 0; d < 8; ++d)
#pragma unroll
        for (int j = 0; j < 4; ++j) O[d][j] *= alpha[j];
      asm volatile("s_waitcnt vmcnt(0)" ::: "memory");
      __builtin_amdgcn_s_barrier();
#pragma unroll
      for (int j = 0; j < 4; ++j)
#pragma unroll
        for (int n = 0; n < 4; ++n)
          Ps[wave][g * 4 + j][n * 16 + r] = f2bf(sc[n][j]);
      s16x8 pa0 = *(const s16x8*)&Ps[wave][r][g * 8];
      s16x8 pa1 = *(const s16x8*)&Ps[wave][r][32 + g * 8];
      __builtin_amdgcn_s_setprio(1);
#pragma unroll
      for (int d = 0; d < 8; ++d) {
        int dd = d * 16 + r;
        s16x8 b0 = *(const s16x8*)&Vt[dd * 64 + ((g ^ (dd & 7)) << 3)];
        s16x8 b1 = *(const s16x8*)&Vt[dd * 64 + (((4 + g) ^ (dd & 7)) << 3)];
        O[d] = __builtin_amdgcn_mfma_f32_16x16x32_bf16(pa0, b0, O[d], 0, 0, 0);
        O[d] = __builtin_amdgcn_mfma_f32_16x16x32_bf16(pa1, b1, O[d], 0, 0, 0);
      }
      __builtin_amdgcn_s_setprio(0);
    }
    float linv[4];
#pragma unroll
    for (int j = 0; j < 4; ++j) linv[j] = 1.f / lst[j];
#pragma unroll
    for (int d = 0; d < 8; ++d)
#pragma unroll
      for (int j = 0; j < 4; ++j)
        obuf[(size_t)(qbase + wave * 16 + g * 4 + j) * DMODEL + h * DHEAD + d * 16 + r] =
            f2bf(O[d][j] * linv[j]);
  }
}

// ---------------- host side ----------------
extern "C" void kernel_launch(void* const* d_in, const int* in_sizes, int n_in,
                              void* d_out, int out_size, void* d_ws, size_t ws_size,
                              hipStream_t stream) {
  const int* text = (const int*)d_in[0];
  const float* embed_w = (const float*)d_in[1];
  const float* model_g = (const float*)d_in[2];
  const float* model_b = (const float*)d_in[3];
  const float* blk_g = (const float*)d_in[4];
  const float* blk_b = (const float*)d_in[5];
  const float* attn_g = (const float*)d_in[6];
  const float* attn_b = (const float*)d_in[7];
  const float* wq = (const float*)d_in[8];
  const float* wk = (const float*)d_in[9];
  const float* wv = (const float*)d_in[10];
  const float* wo = (const float*)d_in[11];
  const float* qn_g = (const float*)d_in[12];
  const float* kn_g = (const float*)d_in[13];
  const float* w1 = (const float*)d_in[14];
  const float* b1 = (const float*)d_in[15];
  const float* w2 = (const float*)d_in[16];
  const float* b2 = (const float*)d_in[17];
  const float* head_g = (const float*)d_in[18];
  const float* head_b = (const float*)d_in[19];
  const float* head_w = (const float*)d_in[20];
  const float* head_bias = (const float*)d_in[21];
  float* out = (float*)d_out;

  const size_t SD = (size_t)S_LEN * DMODEL;
  const size_t SKV = (size_t)S_LEN * KVHEAD * DHEAD;
  const size_t SI = (size_t)S_LEN * INNER_DIM;
  const size_t WD = (size_t)DMODEL * DMODEL;
  const size_t WKV = (size_t)DMODEL * KVHEAD * DHEAD;
  const size_t WI = (size_t)DMODEL * INNER_DIM;

  char* p = (char*)d_ws;
  float* xres  = (float*)p; p += SD * 4;
  float* hb    = (float*)p; p += SD * 4;
  float* h2    = (float*)p; p += SD * 4;
  short* hn16  = (short*)p; p += SD * 2;
  short* h216  = (short*)p; p += SD * 2;
  short* ao16  = (short*)p; p += SD * 2;
  short* ffi16 = (short*)p; p += SI * 2;
  short* qb16  = (short*)p; p += SD * 2;
  short* kb16  = (short*)p; p += SKV * 2;
  short* vt16  = (short*)p; p += SKV * 2;
  short* wqkvT = (short*)p; p += (size_t)QKVN * DMODEL * 2;
  short* woT   = (short*)p; p += WD * 2;
  short* w1T   = (short*)p; p += WI * 2;
  short* w2T   = (short*)p; p += WI * 2;
  short* headT = w1T;  // reused after layers (10240*2048*2 = 42MB < 64MB)

  dim3 blk(256);
  embed_ln3<<<S_LEN, blk, 0, stream>>>(text, embed_w, model_g, model_b,
                                       blk_g, blk_b, attn_g, attn_b, hb, hn16);

  for (int i = 0; i < NLAYER; ++i) {
    wtrans_all<<<10496, blk, 0, stream>>>(
        wq + (size_t)i * WD, wk + (size_t)i * WKV, wv + (size_t)i * WKV,
        wo + (size_t)i * WD, w1 + (size_t)i * WI, w2 + (size_t)i * WI,
        wqkvT, woT, w1T, w2T);

    // qkv GEMM: fused qk-norm + fused V-transpose (320 blocks)
    gemm_qkv<<<dim3(QKVN / 128, S_LEN / 128), blk, 0, stream>>>(
        hn16, wqkvT, qn_g + i * DHEAD, kn_g + i * DHEAD,
        qb16, kb16, vt16, S_LEN, DMODEL);

    attn_fwd3<<<dim3(16, 16), blk, 0, stream>>>(qb16, kb16, vt16, ao16);

    gemm_db<128, 128, 64, 2, 2, 0, false, true, true, true>
        <<<dim3(DMODEL / 128, S_LEN / 128), blk, 0, stream>>>(
        ao16, woT, nullptr, hb, h2, h216, S_LEN, DMODEL, DMODEL);
    // w1: 2-phase 256^2 BK=64 (halved staged bytes, 256 blocks)
    gemm_db<256, 256, 64, 2, 4, 1, true, false, false, true>
        <<<dim3(INNER_DIM / 256, S_LEN / 256), dim3(512), 0, stream>>>(
        h216, w1T, b1 + (size_t)i * INNER_DIM, nullptr, nullptr, ffi16,
        S_LEN, INNER_DIM, DMODEL);
    gemm_db<128, 128, 64, 2, 2, 0, true, true, true, false>
        <<<dim3(DMODEL / 128, S_LEN / 128), blk, 0, stream>>>(
        ffi16, w2T, b2 + (size_t)i * DMODEL, h2, xres, nullptr, S_LEN, DMODEL, INNER_DIM);

    if (i + 1 < NLAYER) {
      ln_triple<<<S_LEN, blk, 0, stream>>>(
          xres, model_g, model_b,
          blk_g + (i + 1) * DMODEL, blk_b + (i + 1) * DMODEL,
          attn_g + (i + 1) * DMODEL, attn_b + (i + 1) * DMODEL, hb, hn16);
    }
  }

  wtrans64<<<dim3(VOCAB_PAD / 64, 32), blk, 0, stream>>>(head_w, headT, DMODEL, VOCAB, VOCAB_PAD);
  ln_dual<<<S_LEN, blk, 0, stream>>>(xres, model_g, model_b, head_g, head_b, hn16);
  // head: 2-phase 256^2 BK=64 (320 blocks)
  gemm_db<256, 256, 64, 2, 4, 0, true, false, true, false>
      <<<dim3(VOCAB_PAD / 256, S_LEN / 256), dim3(512), 0, stream>>>(
      hn16, headT, head_bias, nullptr, out, nullptr, S_LEN, VOCAB, DMODEL);
}

// Round 12
// 1514.462 us; speedup vs baseline: 1.3348x; 1.0838x over previous
//
#include <hip/hip_runtime.h>
#include <math.h>

#define S_LEN 2048
#define DMODEL 2048
#define NHEAD 16
#define KVHEAD 2
#define DHEAD 128
#define NLAYER 4
#define VOCAB 10000
#define INNER_DIM 8192
#define LN_EPS 1e-5f
#define VOCAB_PAD 10240
#define QKVN 2560

typedef __attribute__((ext_vector_type(4))) float f32x4;
typedef __attribute__((ext_vector_type(2))) float f32x2;
typedef __attribute__((ext_vector_type(8))) short s16x8;
typedef __attribute__((ext_vector_type(4))) short s16x4;

__device__ __forceinline__ short f2bf(float f) {
  union { float f; unsigned u; } v; v.f = f;
  unsigned r = v.u + 0x7FFFu + ((v.u >> 16) & 1u);  // RNE
  return (short)(r >> 16);
}
__device__ __forceinline__ float bf2f(short s) {
  union { unsigned u; float f; } v; v.u = ((unsigned)(unsigned short)s) << 16;
  return v.f;
}

__device__ __forceinline__ float gelu_tanh(float x) {
  float z = 0.7978845608028654f * (x + 0.044715f * x * x * x);
  float t = __expf(-2.0f * fabsf(z));
  float th = (1.0f - t) / (1.0f + t);
  th = copysignf(th, z);
  return 0.5f * x * (1.0f + th);
}

__device__ __forceinline__ void glds16(const void* g, void* l) {
  __builtin_amdgcn_global_load_lds(
      (const __attribute__((address_space(1))) unsigned int*)g,
      (__attribute__((address_space(3))) unsigned int*)l, 16, 0, 0);
}

// ---------------- ALL per-layer weight transposes in one launch ----------
__global__ __launch_bounds__(256)
void wtrans_all(const float* __restrict__ wq, const float* __restrict__ wk,
                const float* __restrict__ wv, const float* __restrict__ wo,
                const float* __restrict__ w1, const float* __restrict__ w2,
                short* __restrict__ wqkvT, short* __restrict__ woT,
                short* __restrict__ w1T, short* __restrict__ w2T) {
  __shared__ float ld[64][65];
  int b = blockIdx.x;
  const float* W; short* WT; int gx, K;
  if (b < 1024)      { W = wq; WT = wqkvT; gx = 32; K = 2048; }
  else if (b < 1152) { b -= 1024; W = wk; WT = wqkvT + (size_t)2048 * 2048; gx = 4; K = 2048; }
  else if (b < 1280) { b -= 1152; W = wv; WT = wqkvT + (size_t)2304 * 2048; gx = 4; K = 2048; }
  else if (b < 2304) { b -= 1280; W = wo; WT = woT; gx = 32; K = 2048; }
  else if (b < 6400) { b -= 2304; W = w1; WT = w1T; gx = 128; K = 2048; }
  else               { b -= 6400; W = w2; WT = w2T; gx = 32; K = 8192; }
  const int N = gx * 64;
  const int n0 = (b % gx) * 64, k0 = (b / gx) * 64;
  const int tid = threadIdx.x;
  const int rbase = tid >> 4;
  const int c4 = (tid & 15) * 4;
#pragma unroll
  for (int q = 0; q < 4; ++q) {
    int kk = rbase + q * 16;
    f32x4 v = *(const f32x4*)(W + (size_t)(k0 + kk) * N + n0 + c4);
    ld[kk][c4 + 0] = v[0]; ld[kk][c4 + 1] = v[1];
    ld[kk][c4 + 2] = v[2]; ld[kk][c4 + 3] = v[3];
  }
  __syncthreads();
#pragma unroll
  for (int s = 0; s < 2; ++s) {
    int lin = tid + s * 256;
    int nn = lin >> 3;
    int ks = lin & 7;
    s16x8 o;
#pragma unroll
    for (int j = 0; j < 8; ++j) o[j] = f2bf(ld[ks * 8 + j][nn]);
    *(s16x8*)&WT[(size_t)(n0 + nn) * K + k0 + ks * 8] = o;
  }
}

// ---------------- head weight transpose (edge at N=10000) ----------------
__global__ __launch_bounds__(256)
void wtrans64(const float* __restrict__ W, short* __restrict__ WT,
              int K, int N, int NP) {
  __shared__ float ld[64][65];
  const int n0 = blockIdx.x * 64, k0 = blockIdx.y * 64;
  const int tid = threadIdx.x;
  const int rbase = tid >> 4;
  const int c4 = (tid & 15) * 4;
#pragma unroll
  for (int q = 0; q < 4; ++q) {
    int kk = rbase + q * 16;
    const float* wp = W + (size_t)(k0 + kk) * N + n0 + c4;
    float v0, v1, v2, v3;
    if (n0 + c4 + 3 < N) {
      f32x4 v = *(const f32x4*)wp;
      v0 = v[0]; v1 = v[1]; v2 = v[2]; v3 = v[3];
    } else {
      v0 = (n0 + c4 + 0 < N) ? wp[0] : 0.f;
      v1 = (n0 + c4 + 1 < N) ? wp[1] : 0.f;
      v2 = (n0 + c4 + 2 < N) ? wp[2] : 0.f;
      v3 = (n0 + c4 + 3 < N) ? wp[3] : 0.f;
    }
    ld[kk][c4 + 0] = v0; ld[kk][c4 + 1] = v1;
    ld[kk][c4 + 2] = v2; ld[kk][c4 + 3] = v3;
  }
  __syncthreads();
#pragma unroll
  for (int s = 0; s < 2; ++s) {
    int lin = tid + s * 256;
    int nn = lin >> 3;
    int ks = lin & 7;
    int n = n0 + nn;
    if (n < NP) {
      s16x8 o;
#pragma unroll
      for (int j = 0; j < 8; ++j)
        o[j] = (n < N) ? f2bf(ld[ks * 8 + j][nn]) : (short)0;
      *(s16x8*)&WT[(size_t)n * K + k0 + ks * 8] = o;
    }
  }
}

// ---------------- LN core: 3 rounds ----------------
__device__ __forceinline__ void ln3_core(
    float (&v)[8], int tid, int wave,
    const float* __restrict__ mg, const float* __restrict__ mb,
    const float* __restrict__ bg, const float* __restrict__ bb,
    const float* __restrict__ ag, const float* __restrict__ ab,
    float* __restrict__ hbrow, short* __restrict__ hnrow,
    float rs[3][4], float rs2[3][4]) {
#pragma unroll
  for (int rnd = 0; rnd < 3; ++rnd) {
    float s = 0.f, s2 = 0.f;
#pragma unroll
    for (int i = 0; i < 8; ++i) { s += v[i]; s2 += v[i] * v[i]; }
#pragma unroll
    for (int off = 1; off < 64; off <<= 1) {
      s += __shfl_xor(s, off); s2 += __shfl_xor(s2, off);
    }
    if ((tid & 63) == 0) { rs[rnd][wave] = s; rs2[rnd][wave] = s2; }
    __syncthreads();
    s = rs[rnd][0] + rs[rnd][1] + rs[rnd][2] + rs[rnd][3];
    s2 = rs2[rnd][0] + rs2[rnd][1] + rs2[rnd][2] + rs2[rnd][3];
    const float mean = s * (1.f / DMODEL);
    const float var = s2 * (1.f / DMODEL) - mean * mean;
    const float rstd = rsqrtf(var + LN_EPS);
    const float* gg = (rnd == 0) ? mg : (rnd == 1) ? bg : ag;
    const float* bbv = (rnd == 0) ? mb : (rnd == 1) ? bb : ab;
#pragma unroll
    for (int i = 0; i < 8; ++i) {
      int idx = tid + i * 256;
      v[i] = (v[i] - mean) * rstd * gg[idx] + bbv[idx];
    }
    if (rnd == 1) {
#pragma unroll
      for (int i = 0; i < 8; ++i) hbrow[tid + i * 256] = v[i];
    }
  }
#pragma unroll
  for (int i = 0; i < 8; ++i) hnrow[tid + i * 256] = f2bf(v[i]);
}

// ---------------- embed gather + triple LN (layer 0) ----------------
__global__ __launch_bounds__(256)
void embed_ln3(const int* __restrict__ text, const float* __restrict__ ew,
               const float* __restrict__ mg, const float* __restrict__ mb,
               const float* __restrict__ bg, const float* __restrict__ bb,
               const float* __restrict__ ag, const float* __restrict__ ab,
               float* __restrict__ hb, short* __restrict__ hn16) {
  const int row = blockIdx.x;
  const int tid = threadIdx.x;
  const int wave = tid >> 6;
  __shared__ float rs[3][4], rs2[3][4];
  float v[8];
  const float* x = ew + (size_t)text[row] * DMODEL;
#pragma unroll
  for (int i = 0; i < 8; ++i) v[i] = x[tid + i * 256];
  ln3_core(v, tid, wave, mg, mb, bg, bb, ag, ab,
           hb + (size_t)row * DMODEL, hn16 + (size_t)row * DMODEL, rs, rs2);
}

// ------- fused split-K reduce (p0+p1+b2+h2bf16) + triple LN --------------
__global__ __launch_bounds__(256)
void ln_triple_sum(const float* __restrict__ p0, const float* __restrict__ p1,
                   const short* __restrict__ h216, const float* __restrict__ b2,
                   const float* __restrict__ mg, const float* __restrict__ mb,
                   const float* __restrict__ bg, const float* __restrict__ bb,
                   const float* __restrict__ ag, const float* __restrict__ ab,
                   float* __restrict__ hb, short* __restrict__ hn16) {
  const int row = blockIdx.x;
  const int tid = threadIdx.x;
  const int wave = tid >> 6;
  __shared__ float rs[3][4], rs2[3][4];
  float v[8];
  const size_t base = (size_t)row * DMODEL;
#pragma unroll
  for (int i = 0; i < 8; ++i) {
    int idx = tid + i * 256;
    v[i] = p0[base + idx] + p1[base + idx] + b2[idx] + bf2f(h216[base + idx]);
  }
  ln3_core(v, tid, wave, mg, mb, bg, bb, ag, ab,
           hb + base, hn16 + base, rs, rs2);
}

// ------- fused split-K reduce + dual LN (model -> head), bf16 out --------
__global__ __launch_bounds__(256)
void ln_dual_sum(const float* __restrict__ p0, const float* __restrict__ p1,
                 const short* __restrict__ h216, const float* __restrict__ b2,
                 const float* __restrict__ mg, const float* __restrict__ mb,
                 const float* __restrict__ hg, const float* __restrict__ hbv,
                 short* __restrict__ out16) {
  const int row = blockIdx.x;
  const int tid = threadIdx.x;
  const int wave = tid >> 6;
  __shared__ float rs[2][4], rs2[2][4];
  float v[8];
  const size_t base = (size_t)row * DMODEL;
#pragma unroll
  for (int i = 0; i < 8; ++i) {
    int idx = tid + i * 256;
    v[i] = p0[base + idx] + p1[base + idx] + b2[idx] + bf2f(h216[base + idx]);
  }
#pragma unroll
  for (int rnd = 0; rnd < 2; ++rnd) {
    float s = 0.f, s2 = 0.f;
#pragma unroll
    for (int i = 0; i < 8; ++i) { s += v[i]; s2 += v[i] * v[i]; }
#pragma unroll
    for (int off = 1; off < 64; off <<= 1) {
      s += __shfl_xor(s, off); s2 += __shfl_xor(s2, off);
    }
    if ((tid & 63) == 0) { rs[rnd][wave] = s; rs2[rnd][wave] = s2; }
    __syncthreads();
    s = rs[rnd][0] + rs[rnd][1] + rs[rnd][2] + rs[rnd][3];
    s2 = rs2[rnd][0] + rs2[rnd][1] + rs2[rnd][2] + rs2[rnd][3];
    const float mean = s * (1.f / DMODEL);
    const float var = s2 * (1.f / DMODEL) - mean * mean;
    const float rstd = rsqrtf(var + LN_EPS);
    const float* gg = (rnd == 0) ? mg : hg;
    const float* bbv = (rnd == 0) ? mb : hbv;
#pragma unroll
    for (int i = 0; i < 8; ++i) {
      int idx = tid + i * 256;
      v[i] = (v[i] - mean) * rstd * gg[idx] + bbv[idx];
    }
  }
  short* o = out16 + base;
#pragma unroll
  for (int i = 0; i < 8; ++i) o[tid + i * 256] = f2bf(v[i]);
}

// ---------------- 2-phase double-buffered bf16 GEMM (+optional split-K) --
template<int BM, int BN, int BK, int WM, int WN, int ACT, bool BIAS, bool RES,
         bool WF, bool WB, bool SPLITK>
__global__ __launch_bounds__(WM * WN * 64)
void gemm_db(const short* __restrict__ A, const short* __restrict__ BT,
             const float* __restrict__ bias, const float* __restrict__ res,
             float* __restrict__ Cf, short* __restrict__ Cb,
             int M, int N, int K, int LDA, int LDB) {
  constexpr int THREADS = WM * WN * 64;
  constexpr int MR = BM / WM / 16;
  constexpr int NR = BN / WN / 16;
  constexpr int KH = BK / 32;
  constexpr int SLOTS = BK / 8;
  constexpr int SMASK = SLOTS - 1;
  constexpr int RSH = (SLOTS == 8) ? 0 : 1;
  constexpr int CSH = (SLOTS == 8) ? 3 : 2;
  constexpr int NI = (BM * BK) / (THREADS * 8);
  __shared__ short As[2][BM * BK];
  __shared__ short Bs[2][BN * BK];
  const int tid = threadIdx.x;
  const int wave = tid >> 6, lane = tid & 63;
  const int g = lane >> 4, r = lane & 15;
  const int wm = wave / WN, wn = wave % WN;
  const int zoff = SPLITK ? blockIdx.z * K : 0;
  if (SPLITK && WF) Cf += (size_t)blockIdx.z * M * N;

  const int GY = gridDim.y;
  int lin = blockIdx.x + blockIdx.y * gridDim.x;
  int nwg = gridDim.x * GY;
  int sw = ((nwg & 7) == 0) ? ((lin & 7) * (nwg >> 3) + (lin >> 3)) : lin;
  const int bm = (sw % GY) * BM;
  const int bn = (sw / GY) * BN;

  const short* gsrc[2 * NI];
  short* ldst[2][2 * NI];
#pragma unroll
  for (int i = 0; i < NI; ++i) {
    int c = i * THREADS + tid;
    int row = c >> CSH;
    int slot = c & SMASK;
    int col = ((slot ^ ((row >> RSH) & SMASK)) << 3);
    gsrc[i] = A + (size_t)(bm + row) * LDA + zoff + col;
    gsrc[NI + i] = BT + (size_t)(bn + row) * LDB + zoff + col;
    int base = (i * THREADS + (wave << 6)) << 3;
    ldst[0][i] = &As[0][base]; ldst[0][NI + i] = &Bs[0][base];
    ldst[1][i] = &As[1][base]; ldst[1][NI + i] = &Bs[1][base];
  }

  f32x4 acc[MR][NR] = {};
  const int NT = K / BK;

#pragma unroll
  for (int i = 0; i < 2 * NI; ++i) glds16(gsrc[i], ldst[0][i]);
  asm volatile("s_waitcnt vmcnt(0)" ::: "memory");
  __syncthreads();

  for (int t = 0; t < NT; ++t) {
    const int cur = t & 1;
    const short* as = As[cur];
    const short* bs = Bs[cur];
    s16x8 bfr[NR][KH], af[MR / 2][KH];
#pragma unroll
    for (int n = 0; n < NR; ++n) {
      int rr = wn * (NR * 16) + n * 16 + r;
#pragma unroll
      for (int kk = 0; kk < KH; ++kk) {
        int lg = kk * 4 + g;
        bfr[n][kk] = *(const s16x8*)&bs[rr * BK + ((lg ^ ((rr >> RSH) & SMASK)) << 3)];
      }
    }
#pragma unroll
    for (int mm = 0; mm < MR / 2; ++mm) {
      int rr = wm * (MR * 16) + mm * 16 + r;
#pragma unroll
      for (int kk = 0; kk < KH; ++kk) {
        int lg = kk * 4 + g;
        af[mm][kk] = *(const s16x8*)&as[rr * BK + ((lg ^ ((rr >> RSH) & SMASK)) << 3)];
      }
    }
    if (t + 1 < NT) {
#pragma unroll
      for (int i = 0; i < 2 * NI; ++i) glds16(gsrc[i] + (t + 1) * BK, ldst[cur ^ 1][i]);
    }
    asm volatile("s_waitcnt lgkmcnt(0)" ::: "memory");
    __builtin_amdgcn_sched_barrier(0);
    __builtin_amdgcn_s_setprio(1);
#pragma unroll
    for (int mm = 0; mm < MR / 2; ++mm)
#pragma unroll
      for (int n = 0; n < NR; ++n)
#pragma unroll
        for (int kk = 0; kk < KH; ++kk)
          acc[mm][n] = __builtin_amdgcn_mfma_f32_16x16x32_bf16(af[mm][kk], bfr[n][kk], acc[mm][n], 0, 0, 0);
    __builtin_amdgcn_s_setprio(0);
    __builtin_amdgcn_s_barrier();
#pragma unroll
    for (int mm = 0; mm < MR / 2; ++mm) {
      int rr = wm * (MR * 16) + (MR / 2 + mm) * 16 + r;
#pragma unroll
      for (int kk = 0; kk < KH; ++kk) {
        int lg = kk * 4 + g;
        af[mm][kk] = *(const s16x8*)&as[rr * BK + ((lg ^ ((rr >> RSH) & SMASK)) << 3)];
      }
    }
    asm volatile("s_waitcnt lgkmcnt(0)" ::: "memory");
    __builtin_amdgcn_sched_barrier(0);
    __builtin_amdgcn_s_setprio(1);
#pragma unroll
    for (int mm = 0; mm < MR / 2; ++mm)
#pragma unroll
      for (int n = 0; n < NR; ++n)
#pragma unroll
        for (int kk = 0; kk < KH; ++kk)
          acc[MR / 2 + mm][n] = __builtin_amdgcn_mfma_f32_16x16x32_bf16(af[mm][kk], bfr[n][kk], acc[MR / 2 + mm][n], 0, 0, 0);
    __builtin_amdgcn_s_setprio(0);
    __syncthreads();
  }

#pragma unroll
  for (int m = 0; m < MR; ++m) {
    int row = bm + wm * (MR * 16) + m * 16 + g * 4;
#pragma unroll
    for (int n = 0; n < NR; ++n) {
      int col = bn + wn * (NR * 16) + n * 16 + r;
      if (col < N) {
#pragma unroll
        for (int j = 0; j < 4; ++j) {
          float v = acc[m][n][j];
          if (BIAS) v += bias[col];
          if (ACT) v = gelu_tanh(v);
          if (RES) v += res[(size_t)(row + j) * N + col];
          if (WF) Cf[(size_t)(row + j) * N + col] = v;
          if (WB) Cb[(size_t)(row + j) * N + col] = f2bf(v);
        }
      }
    }
  }
}

// ---------------- qkv GEMM with fused qk-norm + fused V-transpose --------
__global__ __launch_bounds__(256)
void gemm_qkv(const short* __restrict__ A, const short* __restrict__ BT,
              const float* __restrict__ qg, const float* __restrict__ kg,
              short* __restrict__ qb, short* __restrict__ kb,
              short* __restrict__ vt, int M, int K) {
  __shared__ short As[2][128 * 64];
  __shared__ short Bs[2][128 * 64];
  __shared__ float rsm[2][128], rs2m[2][128];
  const int tid = threadIdx.x;
  const int wave = tid >> 6, lane = tid & 63;
  const int g = lane >> 4, r = lane & 15;
  const int wm = wave >> 1, wn = wave & 1;

  const int GY = gridDim.y;
  int lin = blockIdx.x + blockIdx.y * gridDim.x;
  int nwg = gridDim.x * GY;
  int sw = (lin & 7) * (nwg >> 3) + (lin >> 3);
  const int bm = (sw % GY) * 128;
  const int bn = (sw / GY) * 128;

  const short* gsrc[8];
  short* ldst[2][8];
#pragma unroll
  for (int i = 0; i < 4; ++i) {
    int c = i * 256 + tid;
    int row = c >> 3;
    int slot = c & 7;
    int col = ((slot ^ (row & 7)) << 3);
    gsrc[i] = A + (size_t)(bm + row) * K + col;
    gsrc[4 + i] = BT + (size_t)(bn + row) * K + col;
    int base = (i * 256 + (wave << 6)) << 3;
    ldst[0][i] = &As[0][base]; ldst[0][4 + i] = &Bs[0][base];
    ldst[1][i] = &As[1][base]; ldst[1][4 + i] = &Bs[1][base];
  }

  f32x4 acc[4][4] = {};
  const int NT = K >> 6;

#pragma unroll
  for (int i = 0; i < 8; ++i) glds16(gsrc[i], ldst[0][i]);
  asm volatile("s_waitcnt vmcnt(0)" ::: "memory");
  __syncthreads();

  for (int t = 0; t < NT; ++t) {
    const int cur = t & 1;
    const short* as = As[cur];
    const short* bs = Bs[cur];
    s16x8 bfr[4][2], af[2][2];
#pragma unroll
    for (int n = 0; n < 4; ++n) {
      int rr = wn * 64 + n * 16 + r;
#pragma unroll
      for (int kk = 0; kk < 2; ++kk) {
        int lg = kk * 4 + g;
        bfr[n][kk] = *(const s16x8*)&bs[rr * 64 + ((lg ^ (rr & 7)) << 3)];
      }
    }
#pragma unroll
    for (int mm = 0; mm < 2; ++mm) {
      int rr = wm * 64 + mm * 16 + r;
#pragma unroll
      for (int kk = 0; kk < 2; ++kk) {
        int lg = kk * 4 + g;
        af[mm][kk] = *(const s16x8*)&as[rr * 64 + ((lg ^ (rr & 7)) << 3)];
      }
    }
    if (t + 1 < NT) {
#pragma unroll
      for (int i = 0; i < 8; ++i) glds16(gsrc[i] + (t + 1) * 64, ldst[cur ^ 1][i]);
    }
    asm volatile("s_waitcnt lgkmcnt(0)" ::: "memory");
    __builtin_amdgcn_sched_barrier(0);
    __builtin_amdgcn_s_setprio(1);
#pragma unroll
    for (int mm = 0; mm < 2; ++mm)
#pragma unroll
      for (int n = 0; n < 4; ++n)
#pragma unroll
        for (int kk = 0; kk < 2; ++kk)
          acc[mm][n] = __builtin_amdgcn_mfma_f32_16x16x32_bf16(af[mm][kk], bfr[n][kk], acc[mm][n], 0, 0, 0);
    __builtin_amdgcn_s_setprio(0);
    __builtin_amdgcn_s_barrier();
#pragma unroll
    for (int mm = 0; mm < 2; ++mm) {
      int rr = wm * 64 + (2 + mm) * 16 + r;
#pragma unroll
      for (int kk = 0; kk < 2; ++kk) {
        int lg = kk * 4 + g;
        af[mm][kk] = *(const s16x8*)&as[rr * 64 + ((lg ^ (rr & 7)) << 3)];
      }
    }
    asm volatile("s_waitcnt lgkmcnt(0)" ::: "memory");
    __builtin_amdgcn_sched_barrier(0);
    __builtin_amdgcn_s_setprio(1);
#pragma unroll
    for (int mm = 0; mm < 2; ++mm)
#pragma unroll
      for (int n = 0; n < 4; ++n)
#pragma unroll
        for (int kk = 0; kk < 2; ++kk)
          acc[2 + mm][n] = __builtin_amdgcn_mfma_f32_16x16x32_bf16(af[mm][kk], bfr[n][kk], acc[2 + mm][n], 0, 0, 0);
    __builtin_amdgcn_s_setprio(0);
    __syncthreads();
  }

  if (bn >= 2304) {
    short* ld = &As[0][0];
#pragma unroll
    for (int m = 0; m < 4; ++m) {
      int sl = wm * 64 + m * 16 + g * 4;
#pragma unroll
      for (int n = 0; n < 4; ++n) {
        int dl = wn * 64 + n * 16 + r;
#pragma unroll
        for (int j = 0; j < 4; ++j)
          ld[(sl + j) * 128 + dl] = f2bf(acc[m][n][j]);
      }
    }
    __syncthreads();
    const int dl = tid & 127;
    const int sh = (tid >> 7) * 64;
    short* dst = vt + (size_t)(bn - 2304 + dl) * S_LEN + bm + sh;
#pragma unroll
    for (int v = 0; v < 8; ++v) {
      s16x8 o;
#pragma unroll
      for (int i = 0; i < 8; ++i) o[i] = ld[(sh + v * 8 + i) * 128 + dl];
      *(s16x8*)(dst + v * 8) = o;
    }
  } else {
    float ms[4][4], m2[4][4];
#pragma unroll
    for (int m = 0; m < 4; ++m)
#pragma unroll
      for (int j = 0; j < 4; ++j) {
        float s = 0.f, s2 = 0.f;
#pragma unroll
        for (int n = 0; n < 4; ++n) { float v = acc[m][n][j]; s += v; s2 += v * v; }
#pragma unroll
        for (int off = 1; off < 16; off <<= 1) {
          s += __shfl_xor(s, off); s2 += __shfl_xor(s2, off);
        }
        ms[m][j] = s; m2[m][j] = s2;
      }
    if (r == 0) {
#pragma unroll
      for (int m = 0; m < 4; ++m)
#pragma unroll
        for (int j = 0; j < 4; ++j) {
          int rl = wm * 64 + m * 16 + g * 4 + j;
          rsm[wn][rl] = ms[m][j]; rs2m[wn][rl] = m2[m][j];
        }
    }
    __syncthreads();
    const float* gv = (bn < 2048) ? qg : kg;
#pragma unroll
    for (int m = 0; m < 4; ++m)
#pragma unroll
      for (int j = 0; j < 4; ++j) {
        int rl = wm * 64 + m * 16 + g * 4 + j;
        float s = rsm[0][rl] + rsm[1][rl];
        float s2 = rs2m[0][rl] + rs2m[1][rl];
        float mean = s * (1.f / 128.f);
        float var = s2 * (1.f / 128.f) - mean * mean;
        float rstd = rsqrtf(var + LN_EPS);
        int srow = bm + rl;
#pragma unroll
        for (int n = 0; n < 4; ++n) {
          int cl = wn * 64 + n * 16 + r;
          float v = (acc[m][n][j] - mean) * rstd * gv[cl];
          if (bn < 2048) qb[(size_t)srow * 2048 + bn + cl] = f2bf(v);
          else kb[(size_t)srow * 256 + (bn - 2048) + cl] = f2bf(v);
        }
      }
  }
}

// ---------------- Flash attention v3: split K/V waits (proven) -----------
__global__ __launch_bounds__(256)
void attn_fwd3(const short* __restrict__ qbuf, const short* __restrict__ kbuf,
               const short* __restrict__ vtb, short* __restrict__ obuf) {
  __shared__ short Qs[64 * 128];
  __shared__ short Ks[64 * 128];
  __shared__ short Vt[128 * 64];
  __shared__ short Ps[4][16][88];
  const int tid = threadIdx.x;
  int lin = blockIdx.x + blockIdx.y * gridDim.x;
  int sw = (lin & 7) * 32 + (lin >> 3);
  const int pair = sw & 15;
  const int h = sw >> 4;
  const int kh = h >> 3;
  const int wave = tid >> 6, lane = tid & 63;
  const int g = lane >> 4, r = lane & 15;
  const float scale = 0.08838834764831845f;

#pragma unroll
  for (int half = 0; half < 2; ++half) {
    const int qt = half ? (31 - pair) : pair;
    const int qbase = qt * 64;
    __builtin_amdgcn_s_barrier();
#pragma unroll
    for (int i = 0; i < 4; ++i) {
      int c = i * 256 + tid;
      int row = c >> 4;
      int scol = (((c & 15) ^ (row & 7)) << 3);
      glds16(qbuf + (size_t)(qbase + row) * DMODEL + h * DHEAD + scol,
             &Qs[(i * 256 + (wave << 6)) << 3]);
    }
    f32x4 O[8] = {};
    float mst[4], lst[4];
#pragma unroll
    for (int j = 0; j < 4; ++j) { mst[j] = -1e30f; lst[j] = 0.f; }
    s16x8 aq[4];

    for (int jt = 0; jt <= qt; ++jt) {
      const int jb = jt * 64;
      if (jt) __builtin_amdgcn_s_barrier();
#pragma unroll
      for (int i = 0; i < 4; ++i) {
        int c = i * 256 + tid;
        int row = c >> 4;
        int scol = (((c & 15) ^ (row & 7)) << 3);
        glds16(kbuf + (size_t)(jb + row) * 256 + kh * DHEAD + scol,
               &Ks[(i * 256 + (wave << 6)) << 3]);
      }
#pragma unroll
      for (int i = 0; i < 4; ++i) {
        int c = i * 256 + tid;
        int row = c >> 3;
        int scol = (((c & 7) ^ (row & 7)) << 3);
        glds16(vtb + (size_t)(kh * 128 + row) * S_LEN + jb + scol,
               &Vt[(i * 256 + (wave << 6)) << 3]);
      }
      asm volatile("s_waitcnt vmcnt(4)" ::: "memory");
      __builtin_amdgcn_s_barrier();
      if (jt == 0) {
#pragma unroll
        for (int kc = 0; kc < 4; ++kc) {
          int rr = wave * 16 + r;
          aq[kc] = *(const s16x8*)&Qs[rr * 128 + ((((kc << 2) | g) ^ (rr & 7)) << 3)];
        }
      }
      f32x4 sc[4] = {};
      __builtin_amdgcn_s_setprio(1);
#pragma unroll
      for (int n = 0; n < 4; ++n) {
        int rr = n * 16 + r;
#pragma unroll
        for (int kc = 0; kc < 4; ++kc) {
          s16x8 bk = *(const s16x8*)&Ks[rr * 128 + ((((kc << 2) | g) ^ (rr & 7)) << 3)];
          sc[n] = __builtin_amdgcn_mfma_f32_16x16x32_bf16(aq[kc], bk, sc[n], 0, 0, 0);
        }
      }
      __builtin_amdgcn_s_setprio(0);
      if (jt == qt) {
#pragma unroll
        for (int j = 0; j < 4; ++j) {
          int irow = qbase + wave * 16 + g * 4 + j;
#pragma unroll
          for (int n = 0; n < 4; ++n) {
            int jcol = jb + n * 16 + r;
            sc[n][j] = (jcol <= irow) ? sc[n][j] * scale : -1e30f;
          }
        }
      } else {
#pragma unroll
        for (int j = 0; j < 4; ++j)
#pragma unroll
          for (int n = 0; n < 4; ++n) sc[n][j] *= scale;
      }
      float pmax[4], alpha[4], rsum[4];
#pragma unroll
      for (int j = 0; j < 4; ++j)
        pmax[j] = fmaxf(fmaxf(sc[0][j], sc[1][j]), fmaxf(sc[2][j], sc[3][j]));
#pragma unroll
      for (int off = 1; off < 16; off <<= 1)
#pragma unroll
        for (int j = 0; j < 4; ++j) pmax[j] = fmaxf(pmax[j], __shfl_xor(pmax[j], off));
#pragma unroll
      for (int j = 0; j < 4; ++j) {
        float mnew = fmaxf(mst[j], pmax[j]);
        alpha[j] = __expf(mst[j] - mnew);
        mst[j] = mnew;
#pragma unroll
        for (int n = 0; n < 4; ++n) sc[n][j] = __expf(sc[n][j] - mnew);
        rsum[j] = (sc[0][j] + sc[1][j]) + (sc[2][j] + sc[3][j]);
      }
#pragma unroll
      for (int off = 1; off < 16; off <<= 1)
#pragma unroll
        for (int j = 0; j < 4; ++j) rsum[j] += __shfl_xor(rsum[j], off);
#pragma unroll
      for (int j = 0; j < 4; ++j) lst[j] = lst[j] * alpha[j] + rsum[j];
#pragma unroll
      for (int d = 0; d < 8; ++d)
#pragma unroll
        for (int j = 0; j < 4; ++j) O[d][j] *= alpha[j];
      asm volatile("s_waitcnt vmcnt(0)" ::: "memory");
      __builtin_amdgcn_s_barrier();
#pragma unroll
      for (int j = 0; j < 4; ++j)
#pragma unroll
        for (int n = 0; n < 4; ++n)
          Ps[wave][g * 4 + j][n * 16 + r] = f2bf(sc[n][j]);
      s16x8 pa0 = *(const s16x8*)&Ps[wave][r][g * 8];
      s16x8 pa1 = *(const s16x8*)&Ps[wave][r][32 + g * 8];
      __builtin_amdgcn_s_setprio(1);
#pragma unroll
      for (int d = 0; d < 8; ++d) {
        int dd = d * 16 + r;
        s16x8 b0 = *(const s16x8*)&Vt[dd * 64 + ((g ^ (dd & 7)) << 3)];
        s16x8 b1 = *(const s16x8*)&Vt[dd * 64 + (((4 + g) ^ (dd & 7)) << 3)];
        O[d] = __builtin_amdgcn_mfma_f32_16x16x32_bf16(pa0, b0, O[d], 0, 0, 0);
        O[d] = __builtin_amdgcn_mfma_f32_16x16x32_bf16(pa1, b1, O[d], 0, 0, 0);
      }
      __builtin_amdgcn_s_setprio(0);
    }
    float linv[4];
#pragma unroll
    for (int j = 0; j < 4; ++j) linv[j] = 1.f / lst[j];
#pragma unroll
    for (int d = 0; d < 8; ++d)
#pragma unroll
      for (int j = 0; j < 4; ++j)
        obuf[(size_t)(qbase + wave * 16 + g * 4 + j) * DMODEL + h * DHEAD + d * 16 + r] =
            f2bf(O[d][j] * linv[j]);
  }
}

// ---------------- host side ----------------
extern "C" void kernel_launch(void* const* d_in, const int* in_sizes, int n_in,
                              void* d_out, int out_size, void* d_ws, size_t ws_size,
                              hipStream_t stream) {
  const int* text = (const int*)d_in[0];
  const float* embed_w = (const float*)d_in[1];
  const float* model_g = (const float*)d_in[2];
  const float* model_b = (const float*)d_in[3];
  const float* blk_g = (const float*)d_in[4];
  const float* blk_b = (const float*)d_in[5];
  const float* attn_g = (const float*)d_in[6];
  const float* attn_b = (const float*)d_in[7];
  const float* wq = (const float*)d_in[8];
  const float* wk = (const float*)d_in[9];
  const float* wv = (const float*)d_in[10];
  const float* wo = (const float*)d_in[11];
  const float* qn_g = (const float*)d_in[12];
  const float* kn_g = (const float*)d_in[13];
  const float* w1 = (const float*)d_in[14];
  const float* b1 = (const float*)d_in[15];
  const float* w2 = (const float*)d_in[16];
  const float* b2 = (const float*)d_in[17];
  const float* head_g = (const float*)d_in[18];
  const float* head_b = (const float*)d_in[19];
  const float* head_w = (const float*)d_in[20];
  const float* head_bias = (const float*)d_in[21];
  float* out = (float*)d_out;

  const size_t SD = (size_t)S_LEN * DMODEL;
  const size_t SKV = (size_t)S_LEN * KVHEAD * DHEAD;
  const size_t SI = (size_t)S_LEN * INNER_DIM;
  const size_t WD = (size_t)DMODEL * DMODEL;
  const size_t WKV = (size_t)DMODEL * KVHEAD * DHEAD;
  const size_t WI = (size_t)DMODEL * INNER_DIM;

  char* p = (char*)d_ws;
  float* hb    = (float*)p; p += SD * 4;
  float* wpart = (float*)p; p += SD * 4 * 2;   // split-K x2 partials (f32)
  short* hn16  = (short*)p; p += SD * 2;
  short* h216  = (short*)p; p += SD * 2;
  short* ao16  = (short*)p; p += SD * 2;
  short* ffi16 = (short*)p; p += SI * 2;
  short* qb16  = (short*)p; p += SD * 2;
  short* kb16  = (short*)p; p += SKV * 2;
  short* vt16  = (short*)p; p += SKV * 2;
  short* wqkvT = (short*)p; p += (size_t)QKVN * DMODEL * 2;
  short* woT   = (short*)p; p += WD * 2;
  short* w1T   = (short*)p; p += WI * 2;
  short* w2T   = (short*)p; p += WI * 2;
  short* headT = w1T;  // reused after layers

  dim3 blk(256);
  embed_ln3<<<S_LEN, blk, 0, stream>>>(text, embed_w, model_g, model_b,
                                       blk_g, blk_b, attn_g, attn_b, hb, hn16);

  for (int i = 0; i < NLAYER; ++i) {
    wtrans_all<<<10496, blk, 0, stream>>>(
        wq + (size_t)i * WD, wk + (size_t)i * WKV, wv + (size_t)i * WKV,
        wo + (size_t)i * WD, w1 + (size_t)i * WI, w2 + (size_t)i * WI,
        wqkvT, woT, w1T, w2T);

    gemm_qkv<<<dim3(QKVN / 128, S_LEN / 128), blk, 0, stream>>>(
        hn16, wqkvT, qn_g + i * DHEAD, kn_g + i * DHEAD,
        qb16, kb16, vt16, S_LEN, DMODEL);

    attn_fwd3<<<dim3(16, 16), blk, 0, stream>>>(qb16, kb16, vt16, ao16);

    // h2(bf16) = ao @ wo + hb   (no f32 copy; w2 residual folded into LN)
    gemm_db<128, 128, 64, 2, 2, 0, false, true, false, true, false>
        <<<dim3(DMODEL / 128, S_LEN / 128), blk, 0, stream>>>(
        ao16, woT, nullptr, hb, nullptr, h216,
        S_LEN, DMODEL, DMODEL, DMODEL, DMODEL);
    // ffi = gelu(h2 @ w1 + b1): 128^2 -> 1024 blocks (2 blocks/CU)
    gemm_db<128, 128, 64, 2, 2, 1, true, false, false, true, false>
        <<<dim3(INNER_DIM / 128, S_LEN / 128), blk, 0, stream>>>(
        h216, w1T, b1 + (size_t)i * INNER_DIM, nullptr, nullptr, ffi16,
        S_LEN, INNER_DIM, DMODEL, DMODEL, DMODEL);
    // w2: split-K x2 -> 512 blocks (2/CU); partials reduced in fused LN
    gemm_db<128, 128, 64, 2, 2, 0, false, false, true, false, true>
        <<<dim3(DMODEL / 128, S_LEN / 128, 2), blk, 0, stream>>>(
        ffi16, w2T, nullptr, nullptr, wpart, nullptr,
        S_LEN, DMODEL, INNER_DIM / 2, INNER_DIM, INNER_DIM);

    if (i + 1 < NLAYER) {
      ln_triple_sum<<<S_LEN, blk, 0, stream>>>(
          wpart, wpart + SD, h216, b2 + (size_t)i * DMODEL,
          model_g, model_b,
          blk_g + (i + 1) * DMODEL, blk_b + (i + 1) * DMODEL,
          attn_g + (i + 1) * DMODEL, attn_b + (i + 1) * DMODEL, hb, hn16);
    } else {
      ln_dual_sum<<<S_LEN, blk, 0, stream>>>(
          wpart, wpart + SD, h216, b2 + (size_t)i * DMODEL,
          model_g, model_b, head_g, head_b, hn16);
    }
  }

  wtrans64<<<dim3(VOCAB_PAD / 64, 32), blk, 0, stream>>>(head_w, headT, DMODEL, VOCAB, VOCAB_PAD);
  // head: 128^2 -> 1280 blocks (2 blocks/CU)
  gemm_db<128, 128, 64, 2, 2, 0, true, false, true, false, false>
      <<<dim3(VOCAB_PAD / 128, S_LEN / 128), blk, 0, stream>>>(
      hn16, headT, head_bias, nullptr, out, nullptr,
      S_LEN, VOCAB, DMODEL, DMODEL, DMODEL);
}

// Round 13
// 1488.665 us; speedup vs baseline: 1.3580x; 1.0173x over previous
//
#include <hip/hip_runtime.h>
#include <math.h>

#define S_LEN 2048
#define DMODEL 2048
#define NHEAD 16
#define KVHEAD 2
#define DHEAD 128
#define NLAYER 4
#define VOCAB 10000
#define INNER_DIM 8192
#define LN_EPS 1e-5f
#define VOCAB_PAD 10240
#define QKVN 2560

typedef __attribute__((ext_vector_type(4))) float f32x4;
typedef __attribute__((ext_vector_type(2))) float f32x2;
typedef __attribute__((ext_vector_type(8))) short s16x8;
typedef __attribute__((ext_vector_type(4))) short s16x4;

__device__ __forceinline__ short f2bf(float f) {
  union { float f; unsigned u; } v; v.f = f;
  unsigned r = v.u + 0x7FFFu + ((v.u >> 16) & 1u);  // RNE
  return (short)(r >> 16);
}
__device__ __forceinline__ float bf2f(short s) {
  union { unsigned u; float f; } v; v.u = ((unsigned)(unsigned short)s) << 16;
  return v.f;
}

__device__ __forceinline__ float gelu_tanh(float x) {
  float z = 0.7978845608028654f * (x + 0.044715f * x * x * x);
  float t = __expf(-2.0f * fabsf(z));
  float th = (1.0f - t) / (1.0f + t);
  th = copysignf(th, z);
  return 0.5f * x * (1.0f + th);
}

__device__ __forceinline__ void glds16(const void* g, void* l) {
  __builtin_amdgcn_global_load_lds(
      (const __attribute__((address_space(1))) unsigned int*)g,
      (__attribute__((address_space(3))) unsigned int*)l, 16, 0, 0);
}

// ---------------- ALL per-layer weight transposes in one launch ----------
__global__ __launch_bounds__(256)
void wtrans_all(const float* __restrict__ wq, const float* __restrict__ wk,
                const float* __restrict__ wv, const float* __restrict__ wo,
                const float* __restrict__ w1, const float* __restrict__ w2,
                short* __restrict__ wqkvT, short* __restrict__ woT,
                short* __restrict__ w1T, short* __restrict__ w2T) {
  __shared__ float ld[64][65];
  int b = blockIdx.x;
  const float* W; short* WT; int gx, K;
  if (b < 1024)      { W = wq; WT = wqkvT; gx = 32; K = 2048; }
  else if (b < 1152) { b -= 1024; W = wk; WT = wqkvT + (size_t)2048 * 2048; gx = 4; K = 2048; }
  else if (b < 1280) { b -= 1152; W = wv; WT = wqkvT + (size_t)2304 * 2048; gx = 4; K = 2048; }
  else if (b < 2304) { b -= 1280; W = wo; WT = woT; gx = 32; K = 2048; }
  else if (b < 6400) { b -= 2304; W = w1; WT = w1T; gx = 128; K = 2048; }
  else               { b -= 6400; W = w2; WT = w2T; gx = 32; K = 8192; }
  const int N = gx * 64;
  const int n0 = (b % gx) * 64, k0 = (b / gx) * 64;
  const int tid = threadIdx.x;
  const int rbase = tid >> 4;
  const int c4 = (tid & 15) * 4;
#pragma unroll
  for (int q = 0; q < 4; ++q) {
    int kk = rbase + q * 16;
    f32x4 v = *(const f32x4*)(W + (size_t)(k0 + kk) * N + n0 + c4);
    ld[kk][c4 + 0] = v[0]; ld[kk][c4 + 1] = v[1];
    ld[kk][c4 + 2] = v[2]; ld[kk][c4 + 3] = v[3];
  }
  __syncthreads();
#pragma unroll
  for (int s = 0; s < 2; ++s) {
    int lin = tid + s * 256;
    int nn = lin >> 3;
    int ks = lin & 7;
    s16x8 o;
#pragma unroll
    for (int j = 0; j < 8; ++j) o[j] = f2bf(ld[ks * 8 + j][nn]);
    *(s16x8*)&WT[(size_t)(n0 + nn) * K + k0 + ks * 8] = o;
  }
}

// ---------------- head weight transpose (edge at N=10000) ----------------
__global__ __launch_bounds__(256)
void wtrans64(const float* __restrict__ W, short* __restrict__ WT,
              int K, int N, int NP) {
  __shared__ float ld[64][65];
  const int n0 = blockIdx.x * 64, k0 = blockIdx.y * 64;
  const int tid = threadIdx.x;
  const int rbase = tid >> 4;
  const int c4 = (tid & 15) * 4;
#pragma unroll
  for (int q = 0; q < 4; ++q) {
    int kk = rbase + q * 16;
    const float* wp = W + (size_t)(k0 + kk) * N + n0 + c4;
    float v0, v1, v2, v3;
    if (n0 + c4 + 3 < N) {
      f32x4 v = *(const f32x4*)wp;
      v0 = v[0]; v1 = v[1]; v2 = v[2]; v3 = v[3];
    } else {
      v0 = (n0 + c4 + 0 < N) ? wp[0] : 0.f;
      v1 = (n0 + c4 + 1 < N) ? wp[1] : 0.f;
      v2 = (n0 + c4 + 2 < N) ? wp[2] : 0.f;
      v3 = (n0 + c4 + 3 < N) ? wp[3] : 0.f;
    }
    ld[kk][c4 + 0] = v0; ld[kk][c4 + 1] = v1;
    ld[kk][c4 + 2] = v2; ld[kk][c4 + 3] = v3;
  }
  __syncthreads();
#pragma unroll
  for (int s = 0; s < 2; ++s) {
    int lin = tid + s * 256;
    int nn = lin >> 3;
    int ks = lin & 7;
    int n = n0 + nn;
    if (n < NP) {
      s16x8 o;
#pragma unroll
      for (int j = 0; j < 8; ++j)
        o[j] = (n < N) ? f2bf(ld[ks * 8 + j][nn]) : (short)0;
      *(s16x8*)&WT[(size_t)n * K + k0 + ks * 8] = o;
    }
  }
}

// ---------------- LN core: 3 rounds ----------------
__device__ __forceinline__ void ln3_core(
    float (&v)[8], int tid, int wave,
    const float* __restrict__ mg, const float* __restrict__ mb,
    const float* __restrict__ bg, const float* __restrict__ bb,
    const float* __restrict__ ag, const float* __restrict__ ab,
    float* __restrict__ hbrow, short* __restrict__ hnrow,
    float rs[3][4], float rs2[3][4]) {
#pragma unroll
  for (int rnd = 0; rnd < 3; ++rnd) {
    float s = 0.f, s2 = 0.f;
#pragma unroll
    for (int i = 0; i < 8; ++i) { s += v[i]; s2 += v[i] * v[i]; }
#pragma unroll
    for (int off = 1; off < 64; off <<= 1) {
      s += __shfl_xor(s, off); s2 += __shfl_xor(s2, off);
    }
    if ((tid & 63) == 0) { rs[rnd][wave] = s; rs2[rnd][wave] = s2; }
    __syncthreads();
    s = rs[rnd][0] + rs[rnd][1] + rs[rnd][2] + rs[rnd][3];
    s2 = rs2[rnd][0] + rs2[rnd][1] + rs2[rnd][2] + rs2[rnd][3];
    const float mean = s * (1.f / DMODEL);
    const float var = s2 * (1.f / DMODEL) - mean * mean;
    const float rstd = rsqrtf(var + LN_EPS);
    const float* gg = (rnd == 0) ? mg : (rnd == 1) ? bg : ag;
    const float* bbv = (rnd == 0) ? mb : (rnd == 1) ? bb : ab;
#pragma unroll
    for (int i = 0; i < 8; ++i) {
      int idx = tid + i * 256;
      v[i] = (v[i] - mean) * rstd * gg[idx] + bbv[idx];
    }
    if (rnd == 1) {
#pragma unroll
      for (int i = 0; i < 8; ++i) hbrow[tid + i * 256] = v[i];
    }
  }
#pragma unroll
  for (int i = 0; i < 8; ++i) hnrow[tid + i * 256] = f2bf(v[i]);
}

// ---------------- embed gather + triple LN (layer 0) ----------------
__global__ __launch_bounds__(256)
void embed_ln3(const int* __restrict__ text, const float* __restrict__ ew,
               const float* __restrict__ mg, const float* __restrict__ mb,
               const float* __restrict__ bg, const float* __restrict__ bb,
               const float* __restrict__ ag, const float* __restrict__ ab,
               float* __restrict__ hb, short* __restrict__ hn16) {
  const int row = blockIdx.x;
  const int tid = threadIdx.x;
  const int wave = tid >> 6;
  __shared__ float rs[3][4], rs2[3][4];
  float v[8];
  const float* x = ew + (size_t)text[row] * DMODEL;
#pragma unroll
  for (int i = 0; i < 8; ++i) v[i] = x[tid + i * 256];
  ln3_core(v, tid, wave, mg, mb, bg, bb, ag, ab,
           hb + (size_t)row * DMODEL, hn16 + (size_t)row * DMODEL, rs, rs2);
}

// ------- fused split-K reduce (p0+p1+b2+h2bf16) + triple LN --------------
__global__ __launch_bounds__(256)
void ln_triple_sum(const float* __restrict__ p0, const float* __restrict__ p1,
                   const short* __restrict__ h216, const float* __restrict__ b2,
                   const float* __restrict__ mg, const float* __restrict__ mb,
                   const float* __restrict__ bg, const float* __restrict__ bb,
                   const float* __restrict__ ag, const float* __restrict__ ab,
                   float* __restrict__ hb, short* __restrict__ hn16) {
  const int row = blockIdx.x;
  const int tid = threadIdx.x;
  const int wave = tid >> 6;
  __shared__ float rs[3][4], rs2[3][4];
  float v[8];
  const size_t base = (size_t)row * DMODEL;
#pragma unroll
  for (int i = 0; i < 8; ++i) {
    int idx = tid + i * 256;
    v[i] = p0[base + idx] + p1[base + idx] + b2[idx] + bf2f(h216[base + idx]);
  }
  ln3_core(v, tid, wave, mg, mb, bg, bb, ag, ab,
           hb + base, hn16 + base, rs, rs2);
}

// ------- fused split-K reduce + dual LN (model -> head), bf16 out --------
__global__ __launch_bounds__(256)
void ln_dual_sum(const float* __restrict__ p0, const float* __restrict__ p1,
                 const short* __restrict__ h216, const float* __restrict__ b2,
                 const float* __restrict__ mg, const float* __restrict__ mb,
                 const float* __restrict__ hg, const float* __restrict__ hbv,
                 short* __restrict__ out16) {
  const int row = blockIdx.x;
  const int tid = threadIdx.x;
  const int wave = tid >> 6;
  __shared__ float rs[2][4], rs2[2][4];
  float v[8];
  const size_t base = (size_t)row * DMODEL;
#pragma unroll
  for (int i = 0; i < 8; ++i) {
    int idx = tid + i * 256;
    v[i] = p0[base + idx] + p1[base + idx] + b2[idx] + bf2f(h216[base + idx]);
  }
#pragma unroll
  for (int rnd = 0; rnd < 2; ++rnd) {
    float s = 0.f, s2 = 0.f;
#pragma unroll
    for (int i = 0; i < 8; ++i) { s += v[i]; s2 += v[i] * v[i]; }
#pragma unroll
    for (int off = 1; off < 64; off <<= 1) {
      s += __shfl_xor(s, off); s2 += __shfl_xor(s2, off);
    }
    if ((tid & 63) == 0) { rs[rnd][wave] = s; rs2[rnd][wave] = s2; }
    __syncthreads();
    s = rs[rnd][0] + rs[rnd][1] + rs[rnd][2] + rs[rnd][3];
    s2 = rs2[rnd][0] + rs2[rnd][1] + rs2[rnd][2] + rs2[rnd][3];
    const float mean = s * (1.f / DMODEL);
    const float var = s2 * (1.f / DMODEL) - mean * mean;
    const float rstd = rsqrtf(var + LN_EPS);
    const float* gg = (rnd == 0) ? mg : hg;
    const float* bbv = (rnd == 0) ? mb : hbv;
#pragma unroll
    for (int i = 0; i < 8; ++i) {
      int idx = tid + i * 256;
      v[i] = (v[i] - mean) * rstd * gg[idx] + bbv[idx];
    }
  }
  short* o = out16 + base;
#pragma unroll
  for (int i = 0; i < 8; ++i) o[tid + i * 256] = f2bf(v[i]);
}

// ---------------- 2-phase double-buffered bf16 GEMM -----------------------
// Generalized: BM may differ from BN (separate NIA/NIB staging); optional
// split-K via blockIdx.z (A/BT column offset z*K, Cf offset z*M*N).
template<int BM, int BN, int BK, int WM, int WN, int ACT, bool BIAS, bool RES,
         bool WF, bool WB, bool SPLITK>
__global__ __launch_bounds__(WM * WN * 64)
void gemm_db(const short* __restrict__ A, const short* __restrict__ BT,
             const float* __restrict__ bias, const float* __restrict__ res,
             float* __restrict__ Cf, short* __restrict__ Cb,
             int M, int N, int K, int LDA, int LDB) {
  constexpr int THREADS = WM * WN * 64;
  constexpr int MR = BM / WM / 16;
  constexpr int NR = BN / WN / 16;
  constexpr int KH = BK / 32;
  constexpr int SLOTS = BK / 8;
  constexpr int SMASK = SLOTS - 1;
  constexpr int RSH = (SLOTS == 8) ? 0 : 1;
  constexpr int CSH = (SLOTS == 8) ? 3 : 2;
  constexpr int NIA = (BM * BK) / (THREADS * 8);
  constexpr int NIB = (BN * BK) / (THREADS * 8);
  __shared__ short As[2][BM * BK];
  __shared__ short Bs[2][BN * BK];
  const int tid = threadIdx.x;
  const int wave = tid >> 6, lane = tid & 63;
  const int g = lane >> 4, r = lane & 15;
  const int wm = wave / WN, wn = wave % WN;
  const int zoff = SPLITK ? blockIdx.z * K : 0;
  if (SPLITK && WF) Cf += (size_t)blockIdx.z * M * N;

  const int GY = gridDim.y;
  int lin = blockIdx.x + blockIdx.y * gridDim.x;
  int nwg = gridDim.x * GY;
  int sw = ((nwg & 7) == 0) ? ((lin & 7) * (nwg >> 3) + (lin >> 3)) : lin;
  const int bm = (sw % GY) * BM;
  const int bn = (sw / GY) * BN;

  const short* gsrc[NIA + NIB];
  short* ldst[2][NIA + NIB];
#pragma unroll
  for (int i = 0; i < NIA; ++i) {
    int c = i * THREADS + tid;
    int row = c >> CSH;
    int slot = c & SMASK;
    int col = ((slot ^ ((row >> RSH) & SMASK)) << 3);
    gsrc[i] = A + (size_t)(bm + row) * LDA + zoff + col;
    int base = (i * THREADS + (wave << 6)) << 3;
    ldst[0][i] = &As[0][base];
    ldst[1][i] = &As[1][base];
  }
#pragma unroll
  for (int i = 0; i < NIB; ++i) {
    int c = i * THREADS + tid;
    int row = c >> CSH;
    int slot = c & SMASK;
    int col = ((slot ^ ((row >> RSH) & SMASK)) << 3);
    gsrc[NIA + i] = BT + (size_t)(bn + row) * LDB + zoff + col;
    int base = (i * THREADS + (wave << 6)) << 3;
    ldst[0][NIA + i] = &Bs[0][base];
    ldst[1][NIA + i] = &Bs[1][base];
  }

  f32x4 acc[MR][NR] = {};
  const int NT = K / BK;

#pragma unroll
  for (int i = 0; i < NIA + NIB; ++i) glds16(gsrc[i], ldst[0][i]);
  asm volatile("s_waitcnt vmcnt(0)" ::: "memory");
  __syncthreads();

  for (int t = 0; t < NT; ++t) {
    const int cur = t & 1;
    const short* as = As[cur];
    const short* bs = Bs[cur];
    s16x8 bfr[NR][KH], af[(MR > 1) ? MR / 2 : 1][KH];
#pragma unroll
    for (int n = 0; n < NR; ++n) {
      int rr = wn * (NR * 16) + n * 16 + r;
#pragma unroll
      for (int kk = 0; kk < KH; ++kk) {
        int lg = kk * 4 + g;
        bfr[n][kk] = *(const s16x8*)&bs[rr * BK + ((lg ^ ((rr >> RSH) & SMASK)) << 3)];
      }
    }
#pragma unroll
    for (int mm = 0; mm < MR / 2; ++mm) {
      int rr = wm * (MR * 16) + mm * 16 + r;
#pragma unroll
      for (int kk = 0; kk < KH; ++kk) {
        int lg = kk * 4 + g;
        af[mm][kk] = *(const s16x8*)&as[rr * BK + ((lg ^ ((rr >> RSH) & SMASK)) << 3)];
      }
    }
    if (t + 1 < NT) {
#pragma unroll
      for (int i = 0; i < NIA + NIB; ++i) glds16(gsrc[i] + (t + 1) * BK, ldst[cur ^ 1][i]);
    }
    asm volatile("s_waitcnt lgkmcnt(0)" ::: "memory");
    __builtin_amdgcn_sched_barrier(0);
    __builtin_amdgcn_s_setprio(1);
#pragma unroll
    for (int mm = 0; mm < MR / 2; ++mm)
#pragma unroll
      for (int n = 0; n < NR; ++n)
#pragma unroll
        for (int kk = 0; kk < KH; ++kk)
          acc[mm][n] = __builtin_amdgcn_mfma_f32_16x16x32_bf16(af[mm][kk], bfr[n][kk], acc[mm][n], 0, 0, 0);
    __builtin_amdgcn_s_setprio(0);
    __builtin_amdgcn_s_barrier();
#pragma unroll
    for (int mm = 0; mm < MR / 2; ++mm) {
      int rr = wm * (MR * 16) + (MR / 2 + mm) * 16 + r;
#pragma unroll
      for (int kk = 0; kk < KH; ++kk) {
        int lg = kk * 4 + g;
        af[mm][kk] = *(const s16x8*)&as[rr * BK + ((lg ^ ((rr >> RSH) & SMASK)) << 3)];
      }
    }
    asm volatile("s_waitcnt lgkmcnt(0)" ::: "memory");
    __builtin_amdgcn_sched_barrier(0);
    __builtin_amdgcn_s_setprio(1);
#pragma unroll
    for (int mm = 0; mm < MR / 2; ++mm)
#pragma unroll
      for (int n = 0; n < NR; ++n)
#pragma unroll
        for (int kk = 0; kk < KH; ++kk)
          acc[MR / 2 + mm][n] = __builtin_amdgcn_mfma_f32_16x16x32_bf16(af[mm][kk], bfr[n][kk], acc[MR / 2 + mm][n], 0, 0, 0);
    __builtin_amdgcn_s_setprio(0);
    __syncthreads();
  }

#pragma unroll
  for (int m = 0; m < MR; ++m) {
    int row = bm + wm * (MR * 16) + m * 16 + g * 4;
#pragma unroll
    for (int n = 0; n < NR; ++n) {
      int col = bn + wn * (NR * 16) + n * 16 + r;
      if (col < N) {
#pragma unroll
        for (int j = 0; j < 4; ++j) {
          float v = acc[m][n][j];
          if (BIAS) v += bias[col];
          if (ACT) v = gelu_tanh(v);
          if (RES) v += res[(size_t)(row + j) * N + col];
          if (WF) Cf[(size_t)(row + j) * N + col] = v;
          if (WB) Cb[(size_t)(row + j) * N + col] = f2bf(v);
        }
      }
    }
  }
}

// ---------------- qkv GEMM with fused qk-norm + fused V-transpose --------
__global__ __launch_bounds__(256)
void gemm_qkv(const short* __restrict__ A, const short* __restrict__ BT,
              const float* __restrict__ qg, const float* __restrict__ kg,
              short* __restrict__ qb, short* __restrict__ kb,
              short* __restrict__ vt, int M, int K) {
  __shared__ short As[2][128 * 64];
  __shared__ short Bs[2][128 * 64];
  __shared__ float rsm[2][128], rs2m[2][128];
  const int tid = threadIdx.x;
  const int wave = tid >> 6, lane = tid & 63;
  const int g = lane >> 4, r = lane & 15;
  const int wm = wave >> 1, wn = wave & 1;

  const int GY = gridDim.y;
  int lin = blockIdx.x + blockIdx.y * gridDim.x;
  int nwg = gridDim.x * GY;
  int sw = (lin & 7) * (nwg >> 3) + (lin >> 3);
  const int bm = (sw % GY) * 128;
  const int bn = (sw / GY) * 128;

  const short* gsrc[8];
  short* ldst[2][8];
#pragma unroll
  for (int i = 0; i < 4; ++i) {
    int c = i * 256 + tid;
    int row = c >> 3;
    int slot = c & 7;
    int col = ((slot ^ (row & 7)) << 3);
    gsrc[i] = A + (size_t)(bm + row) * K + col;
    gsrc[4 + i] = BT + (size_t)(bn + row) * K + col;
    int base = (i * 256 + (wave << 6)) << 3;
    ldst[0][i] = &As[0][base]; ldst[0][4 + i] = &Bs[0][base];
    ldst[1][i] = &As[1][base]; ldst[1][4 + i] = &Bs[1][base];
  }

  f32x4 acc[4][4] = {};
  const int NT = K >> 6;

#pragma unroll
  for (int i = 0; i < 8; ++i) glds16(gsrc[i], ldst[0][i]);
  asm volatile("s_waitcnt vmcnt(0)" ::: "memory");
  __syncthreads();

  for (int t = 0; t < NT; ++t) {
    const int cur = t & 1;
    const short* as = As[cur];
    const short* bs = Bs[cur];
    s16x8 bfr[4][2], af[2][2];
#pragma unroll
    for (int n = 0; n < 4; ++n) {
      int rr = wn * 64 + n * 16 + r;
#pragma unroll
      for (int kk = 0; kk < 2; ++kk) {
        int lg = kk * 4 + g;
        bfr[n][kk] = *(const s16x8*)&bs[rr * 64 + ((lg ^ (rr & 7)) << 3)];
      }
    }
#pragma unroll
    for (int mm = 0; mm < 2; ++mm) {
      int rr = wm * 64 + mm * 16 + r;
#pragma unroll
      for (int kk = 0; kk < 2; ++kk) {
        int lg = kk * 4 + g;
        af[mm][kk] = *(const s16x8*)&as[rr * 64 + ((lg ^ (rr & 7)) << 3)];
      }
    }
    if (t + 1 < NT) {
#pragma unroll
      for (int i = 0; i < 8; ++i) glds16(gsrc[i] + (t + 1) * 64, ldst[cur ^ 1][i]);
    }
    asm volatile("s_waitcnt lgkmcnt(0)" ::: "memory");
    __builtin_amdgcn_sched_barrier(0);
    __builtin_amdgcn_s_setprio(1);
#pragma unroll
    for (int mm = 0; mm < 2; ++mm)
#pragma unroll
      for (int n = 0; n < 4; ++n)
#pragma unroll
        for (int kk = 0; kk < 2; ++kk)
          acc[mm][n] = __builtin_amdgcn_mfma_f32_16x16x32_bf16(af[mm][kk], bfr[n][kk], acc[mm][n], 0, 0, 0);
    __builtin_amdgcn_s_setprio(0);
    __builtin_amdgcn_s_barrier();
#pragma unroll
    for (int mm = 0; mm < 2; ++mm) {
      int rr = wm * 64 + (2 + mm) * 16 + r;
#pragma unroll
      for (int kk = 0; kk < 2; ++kk) {
        int lg = kk * 4 + g;
        af[mm][kk] = *(const s16x8*)&as[rr * 64 + ((lg ^ (rr & 7)) << 3)];
      }
    }
    asm volatile("s_waitcnt lgkmcnt(0)" ::: "memory");
    __builtin_amdgcn_sched_barrier(0);
    __builtin_amdgcn_s_setprio(1);
#pragma unroll
    for (int mm = 0; mm < 2; ++mm)
#pragma unroll
      for (int n = 0; n < 4; ++n)
#pragma unroll
        for (int kk = 0; kk < 2; ++kk)
          acc[2 + mm][n] = __builtin_amdgcn_mfma_f32_16x16x32_bf16(af[mm][kk], bfr[n][kk], acc[2 + mm][n], 0, 0, 0);
    __builtin_amdgcn_s_setprio(0);
    __syncthreads();
  }

  if (bn >= 2304) {
    short* ld = &As[0][0];
#pragma unroll
    for (int m = 0; m < 4; ++m) {
      int sl = wm * 64 + m * 16 + g * 4;
#pragma unroll
      for (int n = 0; n < 4; ++n) {
        int dl = wn * 64 + n * 16 + r;
#pragma unroll
        for (int j = 0; j < 4; ++j)
          ld[(sl + j) * 128 + dl] = f2bf(acc[m][n][j]);
      }
    }
    __syncthreads();
    const int dl = tid & 127;
    const int sh = (tid >> 7) * 64;
    short* dst = vt + (size_t)(bn - 2304 + dl) * S_LEN + bm + sh;
#pragma unroll
    for (int v = 0; v < 8; ++v) {
      s16x8 o;
#pragma unroll
      for (int i = 0; i < 8; ++i) o[i] = ld[(sh + v * 8 + i) * 128 + dl];
      *(s16x8*)(dst + v * 8) = o;
    }
  } else {
    float ms[4][4], m2[4][4];
#pragma unroll
    for (int m = 0; m < 4; ++m)
#pragma unroll
      for (int j = 0; j < 4; ++j) {
        float s = 0.f, s2 = 0.f;
#pragma unroll
        for (int n = 0; n < 4; ++n) { float v = acc[m][n][j]; s += v; s2 += v * v; }
#pragma unroll
        for (int off = 1; off < 16; off <<= 1) {
          s += __shfl_xor(s, off); s2 += __shfl_xor(s2, off);
        }
        ms[m][j] = s; m2[m][j] = s2;
      }
    if (r == 0) {
#pragma unroll
      for (int m = 0; m < 4; ++m)
#pragma unroll
        for (int j = 0; j < 4; ++j) {
          int rl = wm * 64 + m * 16 + g * 4 + j;
          rsm[wn][rl] = ms[m][j]; rs2m[wn][rl] = m2[m][j];
        }
    }
    __syncthreads();
    const float* gv = (bn < 2048) ? qg : kg;
#pragma unroll
    for (int m = 0; m < 4; ++m)
#pragma unroll
      for (int j = 0; j < 4; ++j) {
        int rl = wm * 64 + m * 16 + g * 4 + j;
        float s = rsm[0][rl] + rsm[1][rl];
        float s2 = rs2m[0][rl] + rs2m[1][rl];
        float mean = s * (1.f / 128.f);
        float var = s2 * (1.f / 128.f) - mean * mean;
        float rstd = rsqrtf(var + LN_EPS);
        int srow = bm + rl;
#pragma unroll
        for (int n = 0; n < 4; ++n) {
          int cl = wn * 64 + n * 16 + r;
          float v = (acc[m][n][j] - mean) * rstd * gv[cl];
          if (bn < 2048) qb[(size_t)srow * 2048 + bn + cl] = f2bf(v);
          else kb[(size_t)srow * 256 + (bn - 2048) + cl] = f2bf(v);
        }
      }
  }
}

// ---------------- Flash attention v3: split K/V waits (proven) -----------
__global__ __launch_bounds__(256)
void attn_fwd3(const short* __restrict__ qbuf, const short* __restrict__ kbuf,
               const short* __restrict__ vtb, short* __restrict__ obuf) {
  __shared__ short Qs[64 * 128];
  __shared__ short Ks[64 * 128];
  __shared__ short Vt[128 * 64];
  __shared__ short Ps[4][16][88];
  const int tid = threadIdx.x;
  int lin = blockIdx.x + blockIdx.y * gridDim.x;
  int sw = (lin & 7) * 32 + (lin >> 3);
  const int pair = sw & 15;
  const int h = sw >> 4;
  const int kh = h >> 3;
  const int wave = tid >> 6, lane = tid & 63;
  const int g = lane >> 4, r = lane & 15;
  const float scale = 0.08838834764831845f;

#pragma unroll
  for (int half = 0; half < 2; ++half) {
    const int qt = half ? (31 - pair) : pair;
    const int qbase = qt * 64;
    __builtin_amdgcn_s_barrier();
#pragma unroll
    for (int i = 0; i < 4; ++i) {
      int c = i * 256 + tid;
      int row = c >> 4;
      int scol = (((c & 15) ^ (row & 7)) << 3);
      glds16(qbuf + (size_t)(qbase + row) * DMODEL + h * DHEAD + scol,
             &Qs[(i * 256 + (wave << 6)) << 3]);
    }
    f32x4 O[8] = {};
    float mst[4], lst[4];
#pragma unroll
    for (int j = 0; j < 4; ++j) { mst[j] = -1e30f; lst[j] = 0.f; }
    s16x8 aq[4];

    for (int jt = 0; jt <= qt; ++jt) {
      const int jb = jt * 64;
      if (jt) __builtin_amdgcn_s_barrier();
#pragma unroll
      for (int i = 0; i < 4; ++i) {
        int c = i * 256 + tid;
        int row = c >> 4;
        int scol = (((c & 15) ^ (row & 7)) << 3);
        glds16(kbuf + (size_t)(jb + row) * 256 + kh * DHEAD + scol,
               &Ks[(i * 256 + (wave << 6)) << 3]);
      }
#pragma unroll
      for (int i = 0; i < 4; ++i) {
        int c = i * 256 + tid;
        int row = c >> 3;
        int scol = (((c & 7) ^ (row & 7)) << 3);
        glds16(vtb + (size_t)(kh * 128 + row) * S_LEN + jb + scol,
               &Vt[(i * 256 + (wave << 6)) << 3]);
      }
      asm volatile("s_waitcnt vmcnt(4)" ::: "memory");
      __builtin_amdgcn_s_barrier();
      if (jt == 0) {
#pragma unroll
        for (int kc = 0; kc < 4; ++kc) {
          int rr = wave * 16 + r;
          aq[kc] = *(const s16x8*)&Qs[rr * 128 + ((((kc << 2) | g) ^ (rr & 7)) << 3)];
        }
      }
      f32x4 sc[4] = {};
      __builtin_amdgcn_s_setprio(1);
#pragma unroll
      for (int n = 0; n < 4; ++n) {
        int rr = n * 16 + r;
#pragma unroll
        for (int kc = 0; kc < 4; ++kc) {
          s16x8 bk = *(const s16x8*)&Ks[rr * 128 + ((((kc << 2) | g) ^ (rr & 7)) << 3)];
          sc[n] = __builtin_amdgcn_mfma_f32_16x16x32_bf16(aq[kc], bk, sc[n], 0, 0, 0);
        }
      }
      __builtin_amdgcn_s_setprio(0);
      if (jt == qt) {
#pragma unroll
        for (int j = 0; j < 4; ++j) {
          int irow = qbase + wave * 16 + g * 4 + j;
#pragma unroll
          for (int n = 0; n < 4; ++n) {
            int jcol = jb + n * 16 + r;
            sc[n][j] = (jcol <= irow) ? sc[n][j] * scale : -1e30f;
          }
        }
      } else {
#pragma unroll
        for (int j = 0; j < 4; ++j)
#pragma unroll
          for (int n = 0; n < 4; ++n) sc[n][j] *= scale;
      }
      float pmax[4], alpha[4], rsum[4];
#pragma unroll
      for (int j = 0; j < 4; ++j)
        pmax[j] = fmaxf(fmaxf(sc[0][j], sc[1][j]), fmaxf(sc[2][j], sc[3][j]));
#pragma unroll
      for (int off = 1; off < 16; off <<= 1)
#pragma unroll
        for (int j = 0; j < 4; ++j) pmax[j] = fmaxf(pmax[j], __shfl_xor(pmax[j], off));
#pragma unroll
      for (int j = 0; j < 4; ++j) {
        float mnew = fmaxf(mst[j], pmax[j]);
        alpha[j] = __expf(mst[j] - mnew);
        mst[j] = mnew;
#pragma unroll
        for (int n = 0; n < 4; ++n) sc[n][j] = __expf(sc[n][j] - mnew);
        rsum[j] = (sc[0][j] + sc[1][j]) + (sc[2][j] + sc[3][j]);
      }
#pragma unroll
      for (int off = 1; off < 16; off <<= 1)
#pragma unroll
        for (int j = 0; j < 4; ++j) rsum[j] += __shfl_xor(rsum[j], off);
#pragma unroll
      for (int j = 0; j < 4; ++j) lst[j] = lst[j] * alpha[j] + rsum[j];
#pragma unroll
      for (int d = 0; d < 8; ++d)
#pragma unroll
        for (int j = 0; j < 4; ++j) O[d][j] *= alpha[j];
      asm volatile("s_waitcnt vmcnt(0)" ::: "memory");
      __builtin_amdgcn_s_barrier();
#pragma unroll
      for (int j = 0; j < 4; ++j)
#pragma unroll
        for (int n = 0; n < 4; ++n)
          Ps[wave][g * 4 + j][n * 16 + r] = f2bf(sc[n][j]);
      s16x8 pa0 = *(const s16x8*)&Ps[wave][r][g * 8];
      s16x8 pa1 = *(const s16x8*)&Ps[wave][r][32 + g * 8];
      __builtin_amdgcn_s_setprio(1);
#pragma unroll
      for (int d = 0; d < 8; ++d) {
        int dd = d * 16 + r;
        s16x8 b0 = *(const s16x8*)&Vt[dd * 64 + ((g ^ (dd & 7)) << 3)];
        s16x8 b1 = *(const s16x8*)&Vt[dd * 64 + (((4 + g) ^ (dd & 7)) << 3)];
        O[d] = __builtin_amdgcn_mfma_f32_16x16x32_bf16(pa0, b0, O[d], 0, 0, 0);
        O[d] = __builtin_amdgcn_mfma_f32_16x16x32_bf16(pa1, b1, O[d], 0, 0, 0);
      }
      __builtin_amdgcn_s_setprio(0);
    }
    float linv[4];
#pragma unroll
    for (int j = 0; j < 4; ++j) linv[j] = 1.f / lst[j];
#pragma unroll
    for (int d = 0; d < 8; ++d)
#pragma unroll
      for (int j = 0; j < 4; ++j)
        obuf[(size_t)(qbase + wave * 16 + g * 4 + j) * DMODEL + h * DHEAD + d * 16 + r] =
            f2bf(O[d][j] * linv[j]);
  }
}

// ---------------- host side ----------------
extern "C" void kernel_launch(void* const* d_in, const int* in_sizes, int n_in,
                              void* d_out, int out_size, void* d_ws, size_t ws_size,
                              hipStream_t stream) {
  const int* text = (const int*)d_in[0];
  const float* embed_w = (const float*)d_in[1];
  const float* model_g = (const float*)d_in[2];
  const float* model_b = (const float*)d_in[3];
  const float* blk_g = (const float*)d_in[4];
  const float* blk_b = (const float*)d_in[5];
  const float* attn_g = (const float*)d_in[6];
  const float* attn_b = (const float*)d_in[7];
  const float* wq = (const float*)d_in[8];
  const float* wk = (const float*)d_in[9];
  const float* wv = (const float*)d_in[10];
  const float* wo = (const float*)d_in[11];
  const float* qn_g = (const float*)d_in[12];
  const float* kn_g = (const float*)d_in[13];
  const float* w1 = (const float*)d_in[14];
  const float* b1 = (const float*)d_in[15];
  const float* w2 = (const float*)d_in[16];
  const float* b2 = (const float*)d_in[17];
  const float* head_g = (const float*)d_in[18];
  const float* head_b = (const float*)d_in[19];
  const float* head_w = (const float*)d_in[20];
  const float* head_bias = (const float*)d_in[21];
  float* out = (float*)d_out;

  const size_t SD = (size_t)S_LEN * DMODEL;
  const size_t SKV = (size_t)S_LEN * KVHEAD * DHEAD;
  const size_t SI = (size_t)S_LEN * INNER_DIM;
  const size_t WD = (size_t)DMODEL * DMODEL;
  const size_t WKV = (size_t)DMODEL * KVHEAD * DHEAD;
  const size_t WI = (size_t)DMODEL * INNER_DIM;

  char* p = (char*)d_ws;
  float* hb    = (float*)p; p += SD * 4;
  float* wpart = (float*)p; p += SD * 4 * 2;
  short* hn16  = (short*)p; p += SD * 2;
  short* h216  = (short*)p; p += SD * 2;
  short* ao16  = (short*)p; p += SD * 2;
  short* ffi16 = (short*)p; p += SI * 2;
  short* qb16  = (short*)p; p += SD * 2;
  short* kb16  = (short*)p; p += SKV * 2;
  short* vt16  = (short*)p; p += SKV * 2;
  short* wqkvT = (short*)p; p += (size_t)QKVN * DMODEL * 2;
  short* woT   = (short*)p; p += WD * 2;
  short* w1T   = (short*)p; p += WI * 2;
  short* w2T   = (short*)p; p += WI * 2;
  short* headT = w1T;

  dim3 blk(256);
  embed_ln3<<<S_LEN, blk, 0, stream>>>(text, embed_w, model_g, model_b,
                                       blk_g, blk_b, attn_g, attn_b, hb, hn16);

  for (int i = 0; i < NLAYER; ++i) {
    wtrans_all<<<10496, blk, 0, stream>>>(
        wq + (size_t)i * WD, wk + (size_t)i * WKV, wv + (size_t)i * WKV,
        wo + (size_t)i * WD, w1 + (size_t)i * WI, w2 + (size_t)i * WI,
        wqkvT, woT, w1T, w2T);

    gemm_qkv<<<dim3(QKVN / 128, S_LEN / 128), blk, 0, stream>>>(
        hn16, wqkvT, qn_g + i * DHEAD, kn_g + i * DHEAD,
        qb16, kb16, vt16, S_LEN, DMODEL);

    attn_fwd3<<<dim3(16, 16), blk, 0, stream>>>(qb16, kb16, vt16, ao16);

    // h2(bf16) = ao @ wo + hb : 64x128 tiles -> 512 blocks (2-3 resident/CU)
    gemm_db<64, 128, 64, 2, 2, 0, false, true, false, true, false>
        <<<dim3(DMODEL / 128, S_LEN / 64), blk, 0, stream>>>(
        ao16, woT, nullptr, hb, nullptr, h216,
        S_LEN, DMODEL, DMODEL, DMODEL, DMODEL);
    // ffi = gelu(h2 @ w1 + b1): 128^2 -> 1024 blocks (2/CU)
    gemm_db<128, 128, 64, 2, 2, 1, true, false, false, true, false>
        <<<dim3(INNER_DIM / 128, S_LEN / 128), blk, 0, stream>>>(
        h216, w1T, b1 + (size_t)i * INNER_DIM, nullptr, nullptr, ffi16,
        S_LEN, INNER_DIM, DMODEL, DMODEL, DMODEL);
    // w2: split-K x2 -> 512 blocks (2/CU); partials reduced in fused LN
    gemm_db<128, 128, 64, 2, 2, 0, false, false, true, false, true>
        <<<dim3(DMODEL / 128, S_LEN / 128, 2), blk, 0, stream>>>(
        ffi16, w2T, nullptr, nullptr, wpart, nullptr,
        S_LEN, DMODEL, INNER_DIM / 2, INNER_DIM, INNER_DIM);

    if (i + 1 < NLAYER) {
      ln_triple_sum<<<S_LEN, blk, 0, stream>>>(
          wpart, wpart + SD, h216, b2 + (size_t)i * DMODEL,
          model_g, model_b,
          blk_g + (i + 1) * DMODEL, blk_b + (i + 1) * DMODEL,
          attn_g + (i + 1) * DMODEL, attn_b + (i + 1) * DMODEL, hb, hn16);
    } else {
      ln_dual_sum<<<S_LEN, blk, 0, stream>>>(
          wpart, wpart + SD, h216, b2 + (size_t)i * DMODEL,
          model_g, model_b, head_g, head_b, hn16);
    }
  }

  wtrans64<<<dim3(VOCAB_PAD / 64, 32), blk, 0, stream>>>(head_w, headT, DMODEL, VOCAB, VOCAB_PAD);
  // head: 128^2 -> 1280 blocks (2/CU)
  gemm_db<128, 128, 64, 2, 2, 0, true, false, true, false, false>
      <<<dim3(VOCAB_PAD / 128, S_LEN / 128), blk, 0, stream>>>(
      hn16, headT, head_bias, nullptr, out, nullptr,
      S_LEN, VOCAB, DMODEL, DMODEL, DMODEL);
}

// Round 14
// 1478.205 us; speedup vs baseline: 1.3676x; 1.0071x over previous
//
#include <hip/hip_runtime.h>
#include <math.h>

#define S_LEN 2048
#define DMODEL 2048
#define NHEAD 16
#define KVHEAD 2
#define DHEAD 128
#define NLAYER 4
#define VOCAB 10000
#define INNER_DIM 8192
#define LN_EPS 1e-5f
#define VOCAB_PAD 10240
#define QKVN 2560

typedef __attribute__((ext_vector_type(4))) float f32x4;
typedef __attribute__((ext_vector_type(2))) float f32x2;
typedef __attribute__((ext_vector_type(8))) short s16x8;
typedef __attribute__((ext_vector_type(4))) short s16x4;

__device__ __forceinline__ short f2bf(float f) {
  union { float f; unsigned u; } v; v.f = f;
  unsigned r = v.u + 0x7FFFu + ((v.u >> 16) & 1u);  // RNE
  return (short)(r >> 16);
}
__device__ __forceinline__ float bf2f(short s) {
  union { unsigned u; float f; } v; v.u = ((unsigned)(unsigned short)s) << 16;
  return v.f;
}

__device__ __forceinline__ float gelu_tanh(float x) {
  float z = 0.7978845608028654f * (x + 0.044715f * x * x * x);
  float t = __expf(-2.0f * fabsf(z));
  float th = (1.0f - t) / (1.0f + t);
  th = copysignf(th, z);
  return 0.5f * x * (1.0f + th);
}

__device__ __forceinline__ void glds16(const void* g, void* l) {
  __builtin_amdgcn_global_load_lds(
      (const __attribute__((address_space(1))) unsigned int*)g,
      (__attribute__((address_space(3))) unsigned int*)l, 16, 0, 0);
}

// ---------------- ALL per-layer weight transposes in one launch ----------
__global__ __launch_bounds__(256)
void wtrans_all(const float* __restrict__ wq, const float* __restrict__ wk,
                const float* __restrict__ wv, const float* __restrict__ wo,
                const float* __restrict__ w1, const float* __restrict__ w2,
                short* __restrict__ wqkvT, short* __restrict__ woT,
                short* __restrict__ w1T, short* __restrict__ w2T) {
  __shared__ float ld[64][65];
  int b = blockIdx.x;
  const float* W; short* WT; int gx, K;
  if (b < 1024)      { W = wq; WT = wqkvT; gx = 32; K = 2048; }
  else if (b < 1152) { b -= 1024; W = wk; WT = wqkvT + (size_t)2048 * 2048; gx = 4; K = 2048; }
  else if (b < 1280) { b -= 1152; W = wv; WT = wqkvT + (size_t)2304 * 2048; gx = 4; K = 2048; }
  else if (b < 2304) { b -= 1280; W = wo; WT = woT; gx = 32; K = 2048; }
  else if (b < 6400) { b -= 2304; W = w1; WT = w1T; gx = 128; K = 2048; }
  else               { b -= 6400; W = w2; WT = w2T; gx = 32; K = 8192; }
  const int N = gx * 64;
  const int n0 = (b % gx) * 64, k0 = (b / gx) * 64;
  const int tid = threadIdx.x;
  const int rbase = tid >> 4;
  const int c4 = (tid & 15) * 4;
#pragma unroll
  for (int q = 0; q < 4; ++q) {
    int kk = rbase + q * 16;
    f32x4 v = *(const f32x4*)(W + (size_t)(k0 + kk) * N + n0 + c4);
    ld[kk][c4 + 0] = v[0]; ld[kk][c4 + 1] = v[1];
    ld[kk][c4 + 2] = v[2]; ld[kk][c4 + 3] = v[3];
  }
  __syncthreads();
#pragma unroll
  for (int s = 0; s < 2; ++s) {
    int lin = tid + s * 256;
    int nn = lin >> 3;
    int ks = lin & 7;
    s16x8 o;
#pragma unroll
    for (int j = 0; j < 8; ++j) o[j] = f2bf(ld[ks * 8 + j][nn]);
    *(s16x8*)&WT[(size_t)(n0 + nn) * K + k0 + ks * 8] = o;
  }
}

// ---------------- head weight transpose (edge at N=10000) ----------------
__global__ __launch_bounds__(256)
void wtrans64(const float* __restrict__ W, short* __restrict__ WT,
              int K, int N, int NP) {
  __shared__ float ld[64][65];
  const int n0 = blockIdx.x * 64, k0 = blockIdx.y * 64;
  const int tid = threadIdx.x;
  const int rbase = tid >> 4;
  const int c4 = (tid & 15) * 4;
#pragma unroll
  for (int q = 0; q < 4; ++q) {
    int kk = rbase + q * 16;
    const float* wp = W + (size_t)(k0 + kk) * N + n0 + c4;
    float v0, v1, v2, v3;
    if (n0 + c4 + 3 < N) {
      f32x4 v = *(const f32x4*)wp;
      v0 = v[0]; v1 = v[1]; v2 = v[2]; v3 = v[3];
    } else {
      v0 = (n0 + c4 + 0 < N) ? wp[0] : 0.f;
      v1 = (n0 + c4 + 1 < N) ? wp[1] : 0.f;
      v2 = (n0 + c4 + 2 < N) ? wp[2] : 0.f;
      v3 = (n0 + c4 + 3 < N) ? wp[3] : 0.f;
    }
    ld[kk][c4 + 0] = v0; ld[kk][c4 + 1] = v1;
    ld[kk][c4 + 2] = v2; ld[kk][c4 + 3] = v3;
  }
  __syncthreads();
#pragma unroll
  for (int s = 0; s < 2; ++s) {
    int lin = tid + s * 256;
    int nn = lin >> 3;
    int ks = lin & 7;
    int n = n0 + nn;
    if (n < NP) {
      s16x8 o;
#pragma unroll
      for (int j = 0; j < 8; ++j)
        o[j] = (n < N) ? f2bf(ld[ks * 8 + j][nn]) : (short)0;
      *(s16x8*)&WT[(size_t)n * K + k0 + ks * 8] = o;
    }
  }
}

// ---------------- LN core: 3 rounds (hb now bf16) ----------------
__device__ __forceinline__ void ln3_core(
    float (&v)[8], int tid, int wave,
    const float* __restrict__ mg, const float* __restrict__ mb,
    const float* __restrict__ bg, const float* __restrict__ bb,
    const float* __restrict__ ag, const float* __restrict__ ab,
    short* __restrict__ hbrow, short* __restrict__ hnrow,
    float rs[3][4], float rs2[3][4]) {
#pragma unroll
  for (int rnd = 0; rnd < 3; ++rnd) {
    float s = 0.f, s2 = 0.f;
#pragma unroll
    for (int i = 0; i < 8; ++i) { s += v[i]; s2 += v[i] * v[i]; }
#pragma unroll
    for (int off = 1; off < 64; off <<= 1) {
      s += __shfl_xor(s, off); s2 += __shfl_xor(s2, off);
    }
    if ((tid & 63) == 0) { rs[rnd][wave] = s; rs2[rnd][wave] = s2; }
    __syncthreads();
    s = rs[rnd][0] + rs[rnd][1] + rs[rnd][2] + rs[rnd][3];
    s2 = rs2[rnd][0] + rs2[rnd][1] + rs2[rnd][2] + rs2[rnd][3];
    const float mean = s * (1.f / DMODEL);
    const float var = s2 * (1.f / DMODEL) - mean * mean;
    const float rstd = rsqrtf(var + LN_EPS);
    const float* gg = (rnd == 0) ? mg : (rnd == 1) ? bg : ag;
    const float* bbv = (rnd == 0) ? mb : (rnd == 1) ? bb : ab;
#pragma unroll
    for (int i = 0; i < 8; ++i) {
      int idx = tid + i * 256;
      v[i] = (v[i] - mean) * rstd * gg[idx] + bbv[idx];
    }
    if (rnd == 1) {
#pragma unroll
      for (int i = 0; i < 8; ++i) hbrow[tid + i * 256] = f2bf(v[i]);
    }
  }
#pragma unroll
  for (int i = 0; i < 8; ++i) hnrow[tid + i * 256] = f2bf(v[i]);
}

// ---------------- embed gather + triple LN (layer 0) ----------------
__global__ __launch_bounds__(256)
void embed_ln3(const int* __restrict__ text, const float* __restrict__ ew,
               const float* __restrict__ mg, const float* __restrict__ mb,
               const float* __restrict__ bg, const float* __restrict__ bb,
               const float* __restrict__ ag, const float* __restrict__ ab,
               short* __restrict__ hb16, short* __restrict__ hn16) {
  const int row = blockIdx.x;
  const int tid = threadIdx.x;
  const int wave = tid >> 6;
  __shared__ float rs[3][4], rs2[3][4];
  float v[8];
  const float* x = ew + (size_t)text[row] * DMODEL;
#pragma unroll
  for (int i = 0; i < 8; ++i) v[i] = x[tid + i * 256];
  ln3_core(v, tid, wave, mg, mb, bg, bb, ag, ab,
           hb16 + (size_t)row * DMODEL, hn16 + (size_t)row * DMODEL, rs, rs2);
}

// ------- fused split-K reduce (p0+p1+b2+h2bf16) + triple LN --------------
__global__ __launch_bounds__(256)
void ln_triple_sum(const float* __restrict__ p0, const float* __restrict__ p1,
                   const short* __restrict__ h216, const float* __restrict__ b2,
                   const float* __restrict__ mg, const float* __restrict__ mb,
                   const float* __restrict__ bg, const float* __restrict__ bb,
                   const float* __restrict__ ag, const float* __restrict__ ab,
                   short* __restrict__ hb16, short* __restrict__ hn16) {
  const int row = blockIdx.x;
  const int tid = threadIdx.x;
  const int wave = tid >> 6;
  __shared__ float rs[3][4], rs2[3][4];
  float v[8];
  const size_t base = (size_t)row * DMODEL;
#pragma unroll
  for (int i = 0; i < 8; ++i) {
    int idx = tid + i * 256;
    v[i] = p0[base + idx] + p1[base + idx] + b2[idx] + bf2f(h216[base + idx]);
  }
  ln3_core(v, tid, wave, mg, mb, bg, bb, ag, ab,
           hb16 + base, hn16 + base, rs, rs2);
}

// ------- fused split-K reduce + dual LN (model -> head), bf16 out --------
__global__ __launch_bounds__(256)
void ln_dual_sum(const float* __restrict__ p0, const float* __restrict__ p1,
                 const short* __restrict__ h216, const float* __restrict__ b2,
                 const float* __restrict__ mg, const float* __restrict__ mb,
                 const float* __restrict__ hg, const float* __restrict__ hbv,
                 short* __restrict__ out16) {
  const int row = blockIdx.x;
  const int tid = threadIdx.x;
  const int wave = tid >> 6;
  __shared__ float rs[2][4], rs2[2][4];
  float v[8];
  const size_t base = (size_t)row * DMODEL;
#pragma unroll
  for (int i = 0; i < 8; ++i) {
    int idx = tid + i * 256;
    v[i] = p0[base + idx] + p1[base + idx] + b2[idx] + bf2f(h216[base + idx]);
  }
#pragma unroll
  for (int rnd = 0; rnd < 2; ++rnd) {
    float s = 0.f, s2 = 0.f;
#pragma unroll
    for (int i = 0; i < 8; ++i) { s += v[i]; s2 += v[i] * v[i]; }
#pragma unroll
    for (int off = 1; off < 64; off <<= 1) {
      s += __shfl_xor(s, off); s2 += __shfl_xor(s2, off);
    }
    if ((tid & 63) == 0) { rs[rnd][wave] = s; rs2[rnd][wave] = s2; }
    __syncthreads();
    s = rs[rnd][0] + rs[rnd][1] + rs[rnd][2] + rs[rnd][3];
    s2 = rs2[rnd][0] + rs2[rnd][1] + rs2[rnd][2] + rs2[rnd][3];
    const float mean = s * (1.f / DMODEL);
    const float var = s2 * (1.f / DMODEL) - mean * mean;
    const float rstd = rsqrtf(var + LN_EPS);
    const float* gg = (rnd == 0) ? mg : hg;
    const float* bbv = (rnd == 0) ? mb : hbv;
#pragma unroll
    for (int i = 0; i < 8; ++i) {
      int idx = tid + i * 256;
      v[i] = (v[i] - mean) * rstd * gg[idx] + bbv[idx];
    }
  }
  short* o = out16 + base;
#pragma unroll
  for (int i = 0; i < 8; ++i) o[tid + i * 256] = f2bf(v[i]);
}

// ---------------- 2-phase double-buffered bf16 GEMM -----------------------
// BM may differ from BN; optional split-K via blockIdx.z; residual may be
// bf16 (RESB) or absent.
template<int BM, int BN, int BK, int WM, int WN, int ACT, bool BIAS, bool RESB,
         bool WF, bool WB, bool SPLITK>
__global__ __launch_bounds__(WM * WN * 64)
void gemm_db(const short* __restrict__ A, const short* __restrict__ BT,
             const float* __restrict__ bias, const short* __restrict__ res16,
             float* __restrict__ Cf, short* __restrict__ Cb,
             int M, int N, int K, int LDA, int LDB) {
  constexpr int THREADS = WM * WN * 64;
  constexpr int MR = BM / WM / 16;
  constexpr int NR = BN / WN / 16;
  constexpr int KH = BK / 32;
  constexpr int SLOTS = BK / 8;
  constexpr int SMASK = SLOTS - 1;
  constexpr int RSH = (SLOTS == 8) ? 0 : 1;
  constexpr int CSH = (SLOTS == 8) ? 3 : 2;
  constexpr int NIA = (BM * BK) / (THREADS * 8);
  constexpr int NIB = (BN * BK) / (THREADS * 8);
  __shared__ short As[2][BM * BK];
  __shared__ short Bs[2][BN * BK];
  const int tid = threadIdx.x;
  const int wave = tid >> 6, lane = tid & 63;
  const int g = lane >> 4, r = lane & 15;
  const int wm = wave / WN, wn = wave % WN;
  const int zoff = SPLITK ? blockIdx.z * K : 0;
  if (SPLITK && WF) Cf += (size_t)blockIdx.z * M * N;

  const int GY = gridDim.y;
  int lin = blockIdx.x + blockIdx.y * gridDim.x;
  int nwg = gridDim.x * GY;
  int sw = ((nwg & 7) == 0) ? ((lin & 7) * (nwg >> 3) + (lin >> 3)) : lin;
  const int bm = (sw % GY) * BM;
  const int bn = (sw / GY) * BN;

  const short* gsrc[NIA + NIB];
  short* ldst[2][NIA + NIB];
#pragma unroll
  for (int i = 0; i < NIA; ++i) {
    int c = i * THREADS + tid;
    int row = c >> CSH;
    int slot = c & SMASK;
    int col = ((slot ^ ((row >> RSH) & SMASK)) << 3);
    gsrc[i] = A + (size_t)(bm + row) * LDA + zoff + col;
    int base = (i * THREADS + (wave << 6)) << 3;
    ldst[0][i] = &As[0][base];
    ldst[1][i] = &As[1][base];
  }
#pragma unroll
  for (int i = 0; i < NIB; ++i) {
    int c = i * THREADS + tid;
    int row = c >> CSH;
    int slot = c & SMASK;
    int col = ((slot ^ ((row >> RSH) & SMASK)) << 3);
    gsrc[NIA + i] = BT + (size_t)(bn + row) * LDB + zoff + col;
    int base = (i * THREADS + (wave << 6)) << 3;
    ldst[0][NIA + i] = &Bs[0][base];
    ldst[1][NIA + i] = &Bs[1][base];
  }

  f32x4 acc[MR][NR] = {};
  const int NT = K / BK;

#pragma unroll
  for (int i = 0; i < NIA + NIB; ++i) glds16(gsrc[i], ldst[0][i]);
  asm volatile("s_waitcnt vmcnt(0)" ::: "memory");
  __syncthreads();

  for (int t = 0; t < NT; ++t) {
    const int cur = t & 1;
    const short* as = As[cur];
    const short* bs = Bs[cur];
    s16x8 bfr[NR][KH], af[(MR > 1) ? MR / 2 : 1][KH];
#pragma unroll
    for (int n = 0; n < NR; ++n) {
      int rr = wn * (NR * 16) + n * 16 + r;
#pragma unroll
      for (int kk = 0; kk < KH; ++kk) {
        int lg = kk * 4 + g;
        bfr[n][kk] = *(const s16x8*)&bs[rr * BK + ((lg ^ ((rr >> RSH) & SMASK)) << 3)];
      }
    }
#pragma unroll
    for (int mm = 0; mm < MR / 2; ++mm) {
      int rr = wm * (MR * 16) + mm * 16 + r;
#pragma unroll
      for (int kk = 0; kk < KH; ++kk) {
        int lg = kk * 4 + g;
        af[mm][kk] = *(const s16x8*)&as[rr * BK + ((lg ^ ((rr >> RSH) & SMASK)) << 3)];
      }
    }
    if (t + 1 < NT) {
#pragma unroll
      for (int i = 0; i < NIA + NIB; ++i) glds16(gsrc[i] + (t + 1) * BK, ldst[cur ^ 1][i]);
    }
    asm volatile("s_waitcnt lgkmcnt(0)" ::: "memory");
    __builtin_amdgcn_sched_barrier(0);
    __builtin_amdgcn_s_setprio(1);
#pragma unroll
    for (int mm = 0; mm < MR / 2; ++mm)
#pragma unroll
      for (int n = 0; n < NR; ++n)
#pragma unroll
        for (int kk = 0; kk < KH; ++kk)
          acc[mm][n] = __builtin_amdgcn_mfma_f32_16x16x32_bf16(af[mm][kk], bfr[n][kk], acc[mm][n], 0, 0, 0);
    __builtin_amdgcn_s_setprio(0);
    __builtin_amdgcn_s_barrier();
#pragma unroll
    for (int mm = 0; mm < MR / 2; ++mm) {
      int rr = wm * (MR * 16) + (MR / 2 + mm) * 16 + r;
#pragma unroll
      for (int kk = 0; kk < KH; ++kk) {
        int lg = kk * 4 + g;
        af[mm][kk] = *(const s16x8*)&as[rr * BK + ((lg ^ ((rr >> RSH) & SMASK)) << 3)];
      }
    }
    asm volatile("s_waitcnt lgkmcnt(0)" ::: "memory");
    __builtin_amdgcn_sched_barrier(0);
    __builtin_amdgcn_s_setprio(1);
#pragma unroll
    for (int mm = 0; mm < MR / 2; ++mm)
#pragma unroll
      for (int n = 0; n < NR; ++n)
#pragma unroll
        for (int kk = 0; kk < KH; ++kk)
          acc[MR / 2 + mm][n] = __builtin_amdgcn_mfma_f32_16x16x32_bf16(af[mm][kk], bfr[n][kk], acc[MR / 2 + mm][n], 0, 0, 0);
    __builtin_amdgcn_s_setprio(0);
    __syncthreads();
  }

#pragma unroll
  for (int m = 0; m < MR; ++m) {
    int row = bm + wm * (MR * 16) + m * 16 + g * 4;
#pragma unroll
    for (int n = 0; n < NR; ++n) {
      int col = bn + wn * (NR * 16) + n * 16 + r;
      if (col < N) {
#pragma unroll
        for (int j = 0; j < 4; ++j) {
          float v = acc[m][n][j];
          if (BIAS) v += bias[col];
          if (ACT) v = gelu_tanh(v);
          if (RESB) v += bf2f(res16[(size_t)(row + j) * N + col]);
          if (WF) Cf[(size_t)(row + j) * N + col] = v;
          if (WB) Cb[(size_t)(row + j) * N + col] = f2bf(v);
        }
      }
    }
  }
}

// ---------------- qkv GEMM: 64x128 tiles, fused qk-norm + V-transpose ----
// grid (20,32) = 640 blocks (2-3 resident/CU). Each col-tile is one head.
__global__ __launch_bounds__(256)
void gemm_qkv(const short* __restrict__ A, const short* __restrict__ BT,
              const float* __restrict__ qg, const float* __restrict__ kg,
              short* __restrict__ qb, short* __restrict__ kb,
              short* __restrict__ vt, int M, int K) {
  __shared__ short As[2][64 * 64];    // A tile 64x64(k)
  __shared__ short Bs[2][128 * 64];   // B tile 128x64(k)
  __shared__ float rsm[2][64], rs2m[2][64];
  const int tid = threadIdx.x;
  const int wave = tid >> 6, lane = tid & 63;
  const int g = lane >> 4, r = lane & 15;
  const int wm = wave >> 1, wn = wave & 1;   // 2x2 waves: 32-row x 64-col each

  const int GY = gridDim.y;  // 32
  int lin = blockIdx.x + blockIdx.y * gridDim.x;
  int nwg = gridDim.x * GY;  // 640 % 8 == 0
  int sw = (lin & 7) * (nwg >> 3) + (lin >> 3);
  const int bm = (sw % GY) * 64;
  const int bn = (sw / GY) * 128;

  const short* gsrc[6];
  short* ldst[2][6];
#pragma unroll
  for (int i = 0; i < 2; ++i) {   // A: 512 chunks / 256 thr = 2
    int c = i * 256 + tid;
    int row = c >> 3, slot = c & 7;
    int col = ((slot ^ (row & 7)) << 3);
    gsrc[i] = A + (size_t)(bm + row) * K + col;
    int base = (i * 256 + (wave << 6)) << 3;
    ldst[0][i] = &As[0][base];
    ldst[1][i] = &As[1][base];
  }
#pragma unroll
  for (int i = 0; i < 4; ++i) {   // B: 1024 chunks / 256 thr = 4
    int c = i * 256 + tid;
    int row = c >> 3, slot = c & 7;
    int col = ((slot ^ (row & 7)) << 3);
    gsrc[2 + i] = BT + (size_t)(bn + row) * K + col;
    int base = (i * 256 + (wave << 6)) << 3;
    ldst[0][2 + i] = &Bs[0][base];
    ldst[1][2 + i] = &Bs[1][base];
  }

  f32x4 acc[2][4] = {};
  const int NT = K >> 6;

#pragma unroll
  for (int i = 0; i < 6; ++i) glds16(gsrc[i], ldst[0][i]);
  asm volatile("s_waitcnt vmcnt(0)" ::: "memory");
  __syncthreads();

  for (int t = 0; t < NT; ++t) {
    const int cur = t & 1;
    const short* as = As[cur];
    const short* bs = Bs[cur];
    s16x8 bfr[4][2], af[1][2];
#pragma unroll
    for (int n = 0; n < 4; ++n) {
      int rr = wn * 64 + n * 16 + r;
#pragma unroll
      for (int kk = 0; kk < 2; ++kk) {
        int lg = kk * 4 + g;
        bfr[n][kk] = *(const s16x8*)&bs[rr * 64 + ((lg ^ (rr & 7)) << 3)];
      }
    }
    {
      int rr = wm * 32 + r;
#pragma unroll
      for (int kk = 0; kk < 2; ++kk) {
        int lg = kk * 4 + g;
        af[0][kk] = *(const s16x8*)&as[rr * 64 + ((lg ^ (rr & 7)) << 3)];
      }
    }
    if (t + 1 < NT) {
#pragma unroll
      for (int i = 0; i < 6; ++i) glds16(gsrc[i] + (t + 1) * 64, ldst[cur ^ 1][i]);
    }
    asm volatile("s_waitcnt lgkmcnt(0)" ::: "memory");
    __builtin_amdgcn_sched_barrier(0);
    __builtin_amdgcn_s_setprio(1);
#pragma unroll
    for (int n = 0; n < 4; ++n)
#pragma unroll
      for (int kk = 0; kk < 2; ++kk)
        acc[0][n] = __builtin_amdgcn_mfma_f32_16x16x32_bf16(af[0][kk], bfr[n][kk], acc[0][n], 0, 0, 0);
    __builtin_amdgcn_s_setprio(0);
    __builtin_amdgcn_s_barrier();
    {
      int rr = wm * 32 + 16 + r;
#pragma unroll
      for (int kk = 0; kk < 2; ++kk) {
        int lg = kk * 4 + g;
        af[0][kk] = *(const s16x8*)&as[rr * 64 + ((lg ^ (rr & 7)) << 3)];
      }
    }
    asm volatile("s_waitcnt lgkmcnt(0)" ::: "memory");
    __builtin_amdgcn_sched_barrier(0);
    __builtin_amdgcn_s_setprio(1);
#pragma unroll
    for (int n = 0; n < 4; ++n)
#pragma unroll
      for (int kk = 0; kk < 2; ++kk)
        acc[1][n] = __builtin_amdgcn_mfma_f32_16x16x32_bf16(af[0][kk], bfr[n][kk], acc[1][n], 0, 0, 0);
    __builtin_amdgcn_s_setprio(0);
    __syncthreads();
  }

  if (bn >= 2304) {
    // V tile 64x128: LDS transpose via As (2*4096 = 8192 shorts = 64*128)
    short* ld = &As[0][0];
#pragma unroll
    for (int m = 0; m < 2; ++m) {
      int sl = wm * 32 + m * 16 + g * 4;
#pragma unroll
      for (int n = 0; n < 4; ++n) {
        int dl = wn * 64 + n * 16 + r;
#pragma unroll
        for (int j = 0; j < 4; ++j)
          ld[(sl + j) * 128 + dl] = f2bf(acc[m][n][j]);
      }
    }
    __syncthreads();
    const int dl = tid & 127;
    const int sh = (tid >> 7) * 32;
    short* dst = vt + (size_t)(bn - 2304 + dl) * S_LEN + bm + sh;
#pragma unroll
    for (int v = 0; v < 4; ++v) {
      s16x8 o;
#pragma unroll
      for (int i = 0; i < 8; ++i) o[i] = ld[(sh + v * 8 + i) * 128 + dl];
      *(s16x8*)(dst + v * 8) = o;
    }
  } else {
    // qk-norm over 128 cols of this head (2 wn-waves combine via LDS)
    float ms[2][4], m2[2][4];
#pragma unroll
    for (int m = 0; m < 2; ++m)
#pragma unroll
      for (int j = 0; j < 4; ++j) {
        float s = 0.f, s2 = 0.f;
#pragma unroll
        for (int n = 0; n < 4; ++n) { float v = acc[m][n][j]; s += v; s2 += v * v; }
#pragma unroll
        for (int off = 1; off < 16; off <<= 1) {
          s += __shfl_xor(s, off); s2 += __shfl_xor(s2, off);
        }
        ms[m][j] = s; m2[m][j] = s2;
      }
    if (r == 0) {
#pragma unroll
      for (int m = 0; m < 2; ++m)
#pragma unroll
        for (int j = 0; j < 4; ++j) {
          int rl = wm * 32 + m * 16 + g * 4 + j;
          rsm[wn][rl] = ms[m][j]; rs2m[wn][rl] = m2[m][j];
        }
    }
    __syncthreads();
    const float* gv = (bn < 2048) ? qg : kg;
#pragma unroll
    for (int m = 0; m < 2; ++m)
#pragma unroll
      for (int j = 0; j < 4; ++j) {
        int rl = wm * 32 + m * 16 + g * 4 + j;
        float s = rsm[0][rl] + rsm[1][rl];
        float s2 = rs2m[0][rl] + rs2m[1][rl];
        float mean = s * (1.f / 128.f);
        float var = s2 * (1.f / 128.f) - mean * mean;
        float rstd = rsqrtf(var + LN_EPS);
        int srow = bm + rl;
#pragma unroll
        for (int n = 0; n < 4; ++n) {
          int cl = wn * 64 + n * 16 + r;
          float v = (acc[m][n][j] - mean) * rstd * gv[cl];
          if (bn < 2048) qb[(size_t)srow * 2048 + bn + cl] = f2bf(v);
          else kb[(size_t)srow * 256 + (bn - 2048) + cl] = f2bf(v);
        }
      }
  }
}

// ---------------- Flash attention v3: split K/V waits (proven) -----------
__global__ __launch_bounds__(256)
void attn_fwd3(const short* __restrict__ qbuf, const short* __restrict__ kbuf,
               const short* __restrict__ vtb, short* __restrict__ obuf) {
  __shared__ short Qs[64 * 128];
  __shared__ short Ks[64 * 128];
  __shared__ short Vt[128 * 64];
  __shared__ short Ps[4][16][88];
  const int tid = threadIdx.x;
  int lin = blockIdx.x + blockIdx.y * gridDim.x;
  int sw = (lin & 7) * 32 + (lin >> 3);
  const int pair = sw & 15;
  const int h = sw >> 4;
  const int kh = h >> 3;
  const int wave = tid >> 6, lane = tid & 63;
  const int g = lane >> 4, r = lane & 15;
  const float scale = 0.08838834764831845f;

#pragma unroll
  for (int half = 0; half < 2; ++half) {
    const int qt = half ? (31 - pair) : pair;
    const int qbase = qt * 64;
    __builtin_amdgcn_s_barrier();
#pragma unroll
    for (int i = 0; i < 4; ++i) {
      int c = i * 256 + tid;
      int row = c >> 4;
      int scol = (((c & 15) ^ (row & 7)) << 3);
      glds16(qbuf + (size_t)(qbase + row) * DMODEL + h * DHEAD + scol,
             &Qs[(i * 256 + (wave << 6)) << 3]);
    }
    f32x4 O[8] = {};
    float mst[4], lst[4];
#pragma unroll
    for (int j = 0; j < 4; ++j) { mst[j] = -1e30f; lst[j] = 0.f; }
    s16x8 aq[4];

    for (int jt = 0; jt <= qt; ++jt) {
      const int jb = jt * 64;
      if (jt) __builtin_amdgcn_s_barrier();
#pragma unroll
      for (int i = 0; i < 4; ++i) {
        int c = i * 256 + tid;
        int row = c >> 4;
        int scol = (((c & 15) ^ (row & 7)) << 3);
        glds16(kbuf + (size_t)(jb + row) * 256 + kh * DHEAD + scol,
               &Ks[(i * 256 + (wave << 6)) << 3]);
      }
#pragma unroll
      for (int i = 0; i < 4; ++i) {
        int c = i * 256 + tid;
        int row = c >> 3;
        int scol = (((c & 7) ^ (row & 7)) << 3);
        glds16(vtb + (size_t)(kh * 128 + row) * S_LEN + jb + scol,
               &Vt[(i * 256 + (wave << 6)) << 3]);
      }
      asm volatile("s_waitcnt vmcnt(4)" ::: "memory");
      __builtin_amdgcn_s_barrier();
      if (jt == 0) {
#pragma unroll
        for (int kc = 0; kc < 4; ++kc) {
          int rr = wave * 16 + r;
          aq[kc] = *(const s16x8*)&Qs[rr * 128 + ((((kc << 2) | g) ^ (rr & 7)) << 3)];
        }
      }
      f32x4 sc[4] = {};
      __builtin_amdgcn_s_setprio(1);
#pragma unroll
      for (int n = 0; n < 4; ++n) {
        int rr = n * 16 + r;
#pragma unroll
        for (int kc = 0; kc < 4; ++kc) {
          s16x8 bk = *(const s16x8*)&Ks[rr * 128 + ((((kc << 2) | g) ^ (rr & 7)) << 3)];
          sc[n] = __builtin_amdgcn_mfma_f32_16x16x32_bf16(aq[kc], bk, sc[n], 0, 0, 0);
        }
      }
      __builtin_amdgcn_s_setprio(0);
      if (jt == qt) {
#pragma unroll
        for (int j = 0; j < 4; ++j) {
          int irow = qbase + wave * 16 + g * 4 + j;
#pragma unroll
          for (int n = 0; n < 4; ++n) {
            int jcol = jb + n * 16 + r;
            sc[n][j] = (jcol <= irow) ? sc[n][j] * scale : -1e30f;
          }
        }
      } else {
#pragma unroll
        for (int j = 0; j < 4; ++j)
#pragma unroll
          for (int n = 0; n < 4; ++n) sc[n][j] *= scale;
      }
      float pmax[4], alpha[4], rsum[4];
#pragma unroll
      for (int j = 0; j < 4; ++j)
        pmax[j] = fmaxf(fmaxf(sc[0][j], sc[1][j]), fmaxf(sc[2][j], sc[3][j]));
#pragma unroll
      for (int off = 1; off < 16; off <<= 1)
#pragma unroll
        for (int j = 0; j < 4; ++j) pmax[j] = fmaxf(pmax[j], __shfl_xor(pmax[j], off));
#pragma unroll
      for (int j = 0; j < 4; ++j) {
        float mnew = fmaxf(mst[j], pmax[j]);
        alpha[j] = __expf(mst[j] - mnew);
        mst[j] = mnew;
#pragma unroll
        for (int n = 0; n < 4; ++n) sc[n][j] = __expf(sc[n][j] - mnew);
        rsum[j] = (sc[0][j] + sc[1][j]) + (sc[2][j] + sc[3][j]);
      }
#pragma unroll
      for (int off = 1; off < 16; off <<= 1)
#pragma unroll
        for (int j = 0; j < 4; ++j) rsum[j] += __shfl_xor(rsum[j], off);
#pragma unroll
      for (int j = 0; j < 4; ++j) lst[j] = lst[j] * alpha[j] + rsum[j];
#pragma unroll
      for (int d = 0; d < 8; ++d)
#pragma unroll
        for (int j = 0; j < 4; ++j) O[d][j] *= alpha[j];
      asm volatile("s_waitcnt vmcnt(0)" ::: "memory");
      __builtin_amdgcn_s_barrier();
#pragma unroll
      for (int j = 0; j < 4; ++j)
#pragma unroll
        for (int n = 0; n < 4; ++n)
          Ps[wave][g * 4 + j][n * 16 + r] = f2bf(sc[n][j]);
      s16x8 pa0 = *(const s16x8*)&Ps[wave][r][g * 8];
      s16x8 pa1 = *(const s16x8*)&Ps[wave][r][32 + g * 8];
      __builtin_amdgcn_s_setprio(1);
#pragma unroll
      for (int d = 0; d < 8; ++d) {
        int dd = d * 16 + r;
        s16x8 b0 = *(const s16x8*)&Vt[dd * 64 + ((g ^ (dd & 7)) << 3)];
        s16x8 b1 = *(const s16x8*)&Vt[dd * 64 + (((4 + g) ^ (dd & 7)) << 3)];
        O[d] = __builtin_amdgcn_mfma_f32_16x16x32_bf16(pa0, b0, O[d], 0, 0, 0);
        O[d] = __builtin_amdgcn_mfma_f32_16x16x32_bf16(pa1, b1, O[d], 0, 0, 0);
      }
      __builtin_amdgcn_s_setprio(0);
    }
    float linv[4];
#pragma unroll
    for (int j = 0; j < 4; ++j) linv[j] = 1.f / lst[j];
#pragma unroll
    for (int d = 0; d < 8; ++d)
#pragma unroll
      for (int j = 0; j < 4; ++j)
        obuf[(size_t)(qbase + wave * 16 + g * 4 + j) * DMODEL + h * DHEAD + d * 16 + r] =
            f2bf(O[d][j] * linv[j]);
  }
}

// ---------------- host side ----------------
extern "C" void kernel_launch(void* const* d_in, const int* in_sizes, int n_in,
                              void* d_out, int out_size, void* d_ws, size_t ws_size,
                              hipStream_t stream) {
  const int* text = (const int*)d_in[0];
  const float* embed_w = (const float*)d_in[1];
  const float* model_g = (const float*)d_in[2];
  const float* model_b = (const float*)d_in[3];
  const float* blk_g = (const float*)d_in[4];
  const float* blk_b = (const float*)d_in[5];
  const float* attn_g = (const float*)d_in[6];
  const float* attn_b = (const float*)d_in[7];
  const float* wq = (const float*)d_in[8];
  const float* wk = (const float*)d_in[9];
  const float* wv = (const float*)d_in[10];
  const float* wo = (const float*)d_in[11];
  const float* qn_g = (const float*)d_in[12];
  const float* kn_g = (const float*)d_in[13];
  const float* w1 = (const float*)d_in[14];
  const float* b1 = (const float*)d_in[15];
  const float* w2 = (const float*)d_in[16];
  const float* b2 = (const float*)d_in[17];
  const float* head_g = (const float*)d_in[18];
  const float* head_b = (const float*)d_in[19];
  const float* head_w = (const float*)d_in[20];
  const float* head_bias = (const float*)d_in[21];
  float* out = (float*)d_out;

  const size_t SD = (size_t)S_LEN * DMODEL;
  const size_t SKV = (size_t)S_LEN * KVHEAD * DHEAD;
  const size_t SI = (size_t)S_LEN * INNER_DIM;
  const size_t WD = (size_t)DMODEL * DMODEL;
  const size_t WKV = (size_t)DMODEL * KVHEAD * DHEAD;
  const size_t WI = (size_t)DMODEL * INNER_DIM;

  char* p = (char*)d_ws;
  float* wpart = (float*)p; p += SD * 4 * 2;
  short* hb16  = (short*)p; p += SD * 2;
  short* hn16  = (short*)p; p += SD * 2;
  short* h216  = (short*)p; p += SD * 2;
  short* ao16  = (short*)p; p += SD * 2;
  short* ffi16 = (short*)p; p += SI * 2;
  short* qb16  = (short*)p; p += SD * 2;
  short* kb16  = (short*)p; p += SKV * 2;
  short* vt16  = (short*)p; p += SKV * 2;
  short* wqkvT = (short*)p; p += (size_t)QKVN * DMODEL * 2;
  short* woT   = (short*)p; p += WD * 2;
  short* w1T   = (short*)p; p += WI * 2;
  short* w2T   = (short*)p; p += WI * 2;
  short* headT = w1T;

  dim3 blk(256);
  embed_ln3<<<S_LEN, blk, 0, stream>>>(text, embed_w, model_g, model_b,
                                       blk_g, blk_b, attn_g, attn_b, hb16, hn16);

  for (int i = 0; i < NLAYER; ++i) {
    wtrans_all<<<10496, blk, 0, stream>>>(
        wq + (size_t)i * WD, wk + (size_t)i * WKV, wv + (size_t)i * WKV,
        wo + (size_t)i * WD, w1 + (size_t)i * WI, w2 + (size_t)i * WI,
        wqkvT, woT, w1T, w2T);

    // qkv: 64x128 tiles -> 640 blocks (2-3 resident/CU)
    gemm_qkv<<<dim3(QKVN / 128, S_LEN / 64), blk, 0, stream>>>(
        hn16, wqkvT, qn_g + i * DHEAD, kn_g + i * DHEAD,
        qb16, kb16, vt16, S_LEN, DMODEL);

    attn_fwd3<<<dim3(16, 16), blk, 0, stream>>>(qb16, kb16, vt16, ao16);

    // h2(bf16) = ao @ wo + hb16 : 64x128 tiles -> 512 blocks
    gemm_db<64, 128, 64, 2, 2, 0, false, true, false, true, false>
        <<<dim3(DMODEL / 128, S_LEN / 64), blk, 0, stream>>>(
        ao16, woT, nullptr, hb16, nullptr, h216,
        S_LEN, DMODEL, DMODEL, DMODEL, DMODEL);
    // ffi = gelu(h2 @ w1 + b1): 128^2 -> 1024 blocks
    gemm_db<128, 128, 64, 2, 2, 1, true, false, false, true, false>
        <<<dim3(INNER_DIM / 128, S_LEN / 128), blk, 0, stream>>>(
        h216, w1T, b1 + (size_t)i * INNER_DIM, nullptr, nullptr, ffi16,
        S_LEN, INNER_DIM, DMODEL, DMODEL, DMODEL);
    // w2: split-K x2 -> 512 blocks; partials reduced in fused LN
    gemm_db<128, 128, 64, 2, 2, 0, false, false, true, false, true>
        <<<dim3(DMODEL / 128, S_LEN / 128, 2), blk, 0, stream>>>(
        ffi16, w2T, nullptr, nullptr, wpart, nullptr,
        S_LEN, DMODEL, INNER_DIM / 2, INNER_DIM, INNER_DIM);

    if (i + 1 < NLAYER) {
      ln_triple_sum<<<S_LEN, blk, 0, stream>>>(
          wpart, wpart + SD, h216, b2 + (size_t)i * DMODEL,
          model_g, model_b,
          blk_g + (i + 1) * DMODEL, blk_b + (i + 1) * DMODEL,
          attn_g + (i + 1) * DMODEL, attn_b + (i + 1) * DMODEL, hb16, hn16);
    } else {
      ln_dual_sum<<<S_LEN, blk, 0, stream>>>(
          wpart, wpart + SD, h216, b2 + (size_t)i * DMODEL,
          model_g, model_b, head_g, head_b, hn16);
    }
  }

  wtrans64<<<dim3(VOCAB_PAD / 64, 32), blk, 0, stream>>>(head_w, headT, DMODEL, VOCAB, VOCAB_PAD);
  // head: 128^2 -> 1280 blocks
  gemm_db<128, 128, 64, 2, 2, 0, true, false, true, false, false>
      <<<dim3(VOCAB_PAD / 128, S_LEN / 128), blk, 0, stream>>>(
      hn16, headT, head_bias, nullptr, out, nullptr,
      S_LEN, VOCAB, DMODEL, DMODEL, DMODEL);
}